// Round 3
// baseline (3529.750 us; speedup 1.0000x reference)
//
#include <hip/hip_runtime.h>
#include <hip/hip_bf16.h>

#define B_    8
#define C_    64
#define N_    1024
#define HID   384
#define OUTD  128
#define L_    3
#define KNN   16
#define NHEADS 3
#define DH    128

// ---------------------------------------------------------------- encode
// h[b,n,:] = x[b,:,n] @ W_enc + b_enc      (x is [B,C,H,W], n = h*W+w)
__global__ void k_encode(const float* __restrict__ x, const float* __restrict__ Wenc,
                         const float* __restrict__ benc, float* __restrict__ h) {
    int bn = blockIdx.x;                 // b*N + n
    int b = bn >> 10, n = bn & 1023;
    const float* xb = x + (long)b * C_ * N_ + n;
    for (int c0 = threadIdx.x; c0 < HID; c0 += blockDim.x) {
        float acc = benc[c0];
        for (int c = 0; c < C_; ++c)
            acc += xb[c * N_] * Wenc[c * HID + c0];
        h[(long)bn * HID + c0] = acc;
    }
}

// ---------------------------------------------------------------- row normalize
__global__ void k_normalize(const float* __restrict__ h, float* __restrict__ nh) {
    int bn = blockIdx.x;
    __shared__ float red[128];
    int tid = threadIdx.x;
    float ss = 0.f;
    for (int c = tid; c < HID; c += 128) { float v = h[(long)bn*HID+c]; ss += v*v; }
    red[tid] = ss; __syncthreads();
    for (int s = 64; s > 0; s >>= 1) { if (tid < s) red[tid] += red[tid+s]; __syncthreads(); }
    float inv = 1.0f / sqrtf(red[0]);
    for (int c = tid; c < HID; c += 128) nh[(long)bn*HID+c] = h[(long)bn*HID+c] * inv;
}

// ---------------------------------------------------------------- tiled f32 GEMM
// C[M,N] = A[M,K] @ B + bias + resid, optional relu.  BT: B stored [N,K] (NT gemm)
template<bool BT, bool RELU>
__global__ __launch_bounds__(256) void k_gemm(
        const float* __restrict__ A, const float* __restrict__ Bm,
        const float* __restrict__ bias, const float* __restrict__ resid,
        float* __restrict__ C, int M, int N, int K,
        long strideA, long strideB, long strideC) {
    __shared__ float As[16][68];
    __shared__ float Bs[16][68];
    int bz = blockIdx.z;
    A  += (long)bz * strideA;
    Bm += (long)bz * strideB;
    C  += (long)bz * strideC;
    int bm = blockIdx.y * 64, bn = blockIdx.x * 64;
    int tid = threadIdx.x;
    int ty = tid >> 4, tx = tid & 15;
    int lm = tid >> 2, lq = tid & 3;
    float acc[4][4] = {};
    for (int k0 = 0; k0 < K; k0 += 16) {
        {   // A tile: As[k][m]
            float4 av = *(const float4*)&A[(long)(bm + lm) * K + k0 + lq * 4];
            As[lq*4+0][lm] = av.x; As[lq*4+1][lm] = av.y;
            As[lq*4+2][lm] = av.z; As[lq*4+3][lm] = av.w;
        }
        if (BT) {
            float4 bv = *(const float4*)&Bm[(long)(bn + lm) * K + k0 + lq * 4];
            Bs[lq*4+0][lm] = bv.x; Bs[lq*4+1][lm] = bv.y;
            Bs[lq*4+2][lm] = bv.z; Bs[lq*4+3][lm] = bv.w;
        } else {
            int kk = tid >> 4, nq = tid & 15;
            float4 bv = *(const float4*)&Bm[(long)(k0 + kk) * N + bn + nq * 4];
            Bs[kk][nq*4+0] = bv.x; Bs[kk][nq*4+1] = bv.y;
            Bs[kk][nq*4+2] = bv.z; Bs[kk][nq*4+3] = bv.w;
        }
        __syncthreads();
        #pragma unroll
        for (int kk = 0; kk < 16; ++kk) {
            float4 a = *(const float4*)&As[kk][ty * 4];
            float4 b = *(const float4*)&Bs[kk][tx * 4];
            acc[0][0] += a.x*b.x; acc[0][1] += a.x*b.y; acc[0][2] += a.x*b.z; acc[0][3] += a.x*b.w;
            acc[1][0] += a.y*b.x; acc[1][1] += a.y*b.y; acc[1][2] += a.y*b.z; acc[1][3] += a.y*b.w;
            acc[2][0] += a.z*b.x; acc[2][1] += a.z*b.y; acc[2][2] += a.z*b.z; acc[2][3] += a.z*b.w;
            acc[3][0] += a.w*b.x; acc[3][1] += a.w*b.y; acc[3][2] += a.w*b.z; acc[3][3] += a.w*b.w;
        }
        __syncthreads();
    }
    #pragma unroll
    for (int i = 0; i < 4; ++i) {
        int row = bm + ty * 4 + i;
        #pragma unroll
        for (int j = 0; j < 4; ++j) {
            int col = bn + tx * 4 + j;
            float c = acc[i][j];
            if (bias)  c += bias[col];
            if (resid) c += resid[(long)row * N + col];
            if (RELU)  c = fmaxf(c, 0.f);
            C[(long)row * N + col] = c;
        }
    }
}

// ---------------------------------------------------------------- top-k (k=16) per row
__global__ __launch_bounds__(256) void k_topk(const float* __restrict__ sim, int* __restrict__ knn) {
    int bn = blockIdx.x; int b = bn >> 10, n = bn & 1023;
    __shared__ float sv[1024];
    __shared__ float rv[256];
    __shared__ int   ri[256];
    int tid = threadIdx.x;
    const float* row = sim + (long)b * N_ * N_ + (long)n * N_;
    for (int m = tid; m < N_; m += 256)
        sv[m] = row[m] - (m == n ? 2.0f : 0.0f);
    __syncthreads();
    for (int j = 0; j < KNN; ++j) {
        float best = -1e30f; int bi = 0;
        for (int m = tid; m < N_; m += 256) {
            float v = sv[m];
            if (v > best) { best = v; bi = m; }
        }
        rv[tid] = best; ri[tid] = bi; __syncthreads();
        for (int s = 128; s > 0; s >>= 1) {
            if (tid < s) {
                if (rv[tid+s] > rv[tid] || (rv[tid+s] == rv[tid] && ri[tid+s] < ri[tid])) {
                    rv[tid] = rv[tid+s]; ri[tid] = ri[tid+s];
                }
            }
            __syncthreads();
        }
        if (tid == 0) { knn[(long)bn * KNN + j] = ri[0]; sv[ri[0]] = -1e30f; }
        __syncthreads();
    }
}

// ---------------------------------------------------------------- GCN gather + residual + LN
// hlocal = LN(h + (xw[self] + sum_j xw[knn_j]) / 17)
__global__ void k_gcn_ln(const float* __restrict__ h, const float* __restrict__ xw,
                         const int* __restrict__ knn,
                         const float* __restrict__ lns, const float* __restrict__ lnb,
                         float* __restrict__ hlocal) {
    int bn = blockIdx.x; int b = bn >> 10;
    __shared__ int nb[KNN];
    __shared__ float red[128];
    int tid = threadIdx.x;
    if (tid < KNN) nb[tid] = knn[(long)bn * KNN + tid];
    __syncthreads();
    float val[3]; float sum = 0.f, ssq = 0.f;
    #pragma unroll
    for (int i = 0; i < 3; ++i) {
        int c = tid + i * 128;
        float acc = xw[(long)bn * HID + c];
        #pragma unroll
        for (int j = 0; j < KNN; ++j)
            acc += xw[((long)(b << 10) + nb[j]) * HID + c];
        float v = h[(long)bn * HID + c] + acc * (1.0f / 17.0f);
        val[i] = v; sum += v; ssq += v * v;
    }
    red[tid] = sum; __syncthreads();
    for (int s = 64; s > 0; s >>= 1) { if (tid < s) red[tid] += red[tid+s]; __syncthreads(); }
    sum = red[0]; __syncthreads();
    red[tid] = ssq; __syncthreads();
    for (int s = 64; s > 0; s >>= 1) { if (tid < s) red[tid] += red[tid+s]; __syncthreads(); }
    ssq = red[0];
    float mu = sum / HID;
    float var = ssq / HID - mu * mu;
    float inv = rsqrtf(var + 1e-5f);
    #pragma unroll
    for (int i = 0; i < 3; ++i) {
        int c = tid + i * 128;
        hlocal[(long)bn * HID + c] = (val[i] - mu) * inv * lns[c] + lnb[c];
    }
}

// ---------------------------------------------------------------- generic (a[+badd]) -> LN -> (+post)
__global__ void k_addln(const float* __restrict__ a, const float* __restrict__ badd,
                        const float* __restrict__ post,
                        const float* __restrict__ lns, const float* __restrict__ lnb,
                        float* __restrict__ outp) {
    int bn = blockIdx.x;
    __shared__ float red[128];
    int tid = threadIdx.x;
    float val[3]; float sum = 0.f, ssq = 0.f;
    #pragma unroll
    for (int i = 0; i < 3; ++i) {
        int c = tid + i * 128;
        float v = a[(long)bn * HID + c];
        if (badd) v += badd[(long)bn * HID + c];
        val[i] = v; sum += v; ssq += v * v;
    }
    red[tid] = sum; __syncthreads();
    for (int s = 64; s > 0; s >>= 1) { if (tid < s) red[tid] += red[tid+s]; __syncthreads(); }
    sum = red[0]; __syncthreads();
    red[tid] = ssq; __syncthreads();
    for (int s = 64; s > 0; s >>= 1) { if (tid < s) red[tid] += red[tid+s]; __syncthreads(); }
    ssq = red[0];
    float mu = sum / HID;
    float var = ssq / HID - mu * mu;
    float inv = rsqrtf(var + 1e-5f);
    #pragma unroll
    for (int i = 0; i < 3; ++i) {
        int c = tid + i * 128;
        float o = (val[i] - mu) * inv * lns[c] + lnb[c];
        if (post) o += post[(long)bn * HID + c];
        outp[(long)bn * HID + c] = o;
    }
}

// ---------------------------------------------------------------- attention (flash-style, 8 rows/block)
__global__ __launch_bounds__(256) void k_attn(const float* __restrict__ q,
                                              const float* __restrict__ kbuf,
                                              const float* __restrict__ v,
                                              float* __restrict__ o) {
    int b = blockIdx.z, hh = blockIdx.y, r0 = blockIdx.x * 8;
    __shared__ float qs[8][DH];
    __shared__ float sc[8][N_];
    __shared__ float rsum[8];
    __shared__ float red[256];
    int tid = threadIdx.x;
    {   // load Q tile (8 x 128)
        int r = tid >> 5, d4 = (tid & 31) * 4;
        *(float4*)&qs[r][d4] =
            *(const float4*)&q[((long)(b * N_ + r0 + r)) * HID + hh * DH + d4];
    }
    __syncthreads();
    const float scale = 0.08838834764831845f;   // 1/sqrt(128)
    // scores: each thread handles 4 key rows
    for (int mi = 0; mi < 4; ++mi) {
        int m = tid + mi * 256;
        const float* kr = &kbuf[((long)(b * N_ + m)) * HID + hh * DH];
        float acc[8] = {};
        for (int d = 0; d < DH; d += 4) {
            float4 kv = *(const float4*)&kr[d];
            #pragma unroll
            for (int r = 0; r < 8; ++r) {
                float4 qv = *(const float4*)&qs[r][d];
                acc[r] += qv.x*kv.x + qv.y*kv.y + qv.z*kv.z + qv.w*kv.w;
            }
        }
        #pragma unroll
        for (int r = 0; r < 8; ++r) sc[r][m] = acc[r] * scale;
    }
    __syncthreads();
    // softmax per row
    for (int r = 0; r < 8; ++r) {
        float mx = -1e30f;
        for (int m = tid; m < N_; m += 256) mx = fmaxf(mx, sc[r][m]);
        red[tid] = mx; __syncthreads();
        for (int s = 128; s > 0; s >>= 1) { if (tid < s) red[tid] = fmaxf(red[tid], red[tid+s]); __syncthreads(); }
        mx = red[0]; __syncthreads();
        float sm = 0.f;
        for (int m = tid; m < N_; m += 256) { float e = __expf(sc[r][m] - mx); sc[r][m] = e; sm += e; }
        red[tid] = sm; __syncthreads();
        for (int s = 128; s > 0; s >>= 1) { if (tid < s) red[tid] += red[tid+s]; __syncthreads(); }
        if (tid == 0) rsum[r] = red[0];
        __syncthreads();
    }
    // attn @ V
    int r = tid >> 5, c4 = (tid & 31) * 4;
    float4 accv = {0.f, 0.f, 0.f, 0.f};
    for (int m = 0; m < N_; ++m) {
        float p = sc[r][m];
        float4 vv = *(const float4*)&v[((long)(b * N_ + m)) * HID + hh * DH + c4];
        accv.x += p * vv.x; accv.y += p * vv.y; accv.z += p * vv.z; accv.w += p * vv.w;
    }
    float is = 1.0f / rsum[r];
    accv.x *= is; accv.y *= is; accv.z *= is; accv.w *= is;
    *(float4*)&o[((long)(b * N_ + r0 + r)) * HID + hh * DH + c4] = accv;
}

// ---------------------------------------------------------------- mean pool over N
__global__ void k_pool(const float* __restrict__ h, float* __restrict__ pooled) {
    int b = blockIdx.x; int tid = threadIdx.x;   // 128 threads
    #pragma unroll
    for (int i = 0; i < 3; ++i) {
        int c = tid + i * 128;
        float s = 0.f;
        for (int n = 0; n < N_; ++n) s += h[((long)(b * N_ + n)) * HID + c];
        pooled[b * HID + c] = s * (1.0f / N_);
    }
}

// ---------------------------------------------------------------- head: relu(p@W1+b1)@W2+b2 -> f32
__global__ void k_head(const float* __restrict__ pooled,
                       const float* __restrict__ w1, const float* __restrict__ b1,
                       const float* __restrict__ w2, const float* __restrict__ b2,
                       float* __restrict__ out) {
    int b = blockIdx.x; int tid = threadIdx.x;   // 384 threads
    __shared__ float z[HID];
    float acc = b1[tid];
    for (int c = 0; c < HID; ++c) acc += pooled[b * HID + c] * w1[c * HID + tid];
    z[tid] = fmaxf(acc, 0.f);
    __syncthreads();
    if (tid < OUTD) {
        float a2 = b2[tid];
        for (int j = 0; j < HID; ++j) a2 += z[j] * w2[j * OUTD + tid];
        out[b * OUTD + tid] = a2;            // OUTPUT IS F32 (reference dtype)
    }
}

// ================================================================ launch
extern "C" void kernel_launch(void* const* d_in, const int* in_sizes, int n_in,
                              void* d_out, int out_size, void* d_ws, size_t ws_size,
                              hipStream_t stream) {
    const float* x       = (const float*)d_in[0];
    const float* W_enc   = (const float*)d_in[1];
    const float* b_enc   = (const float*)d_in[2];
    const float* gcn_W   = (const float*)d_in[3];
    const float* gcn_b   = (const float*)d_in[4];
    const float* Wq      = (const float*)d_in[5];
    const float* bq      = (const float*)d_in[6];
    const float* Wk      = (const float*)d_in[7];
    const float* bk      = (const float*)d_in[8];
    const float* Wv      = (const float*)d_in[9];
    const float* bv      = (const float*)d_in[10];
    const float* Wo      = (const float*)d_in[11];
    const float* bo      = (const float*)d_in[12];
    const float* ln_s    = (const float*)d_in[13];
    const float* ln_b    = (const float*)d_in[14];
    const float* mlp_W1  = (const float*)d_in[15];
    const float* mlp_b1  = (const float*)d_in[16];
    const float* mlp_W2  = (const float*)d_in[17];
    const float* mlp_b2  = (const float*)d_in[18];
    const float* lin1_W  = (const float*)d_in[19];
    const float* lin1_b  = (const float*)d_in[20];
    const float* lin2_W  = (const float*)d_in[21];
    const float* lin2_b  = (const float*)d_in[22];

    float* ws = (float*)d_ws;
    const long S = (long)B_ * N_ * HID;          // 3,145,728 floats
    float* h      = ws;                           // [0, S)
    float* tmp1   = ws + S;                       // nh / xw / o_pre / u
    float* hlocal = ws + 2 * S;
    float* qb     = ws + 3 * S;                   // q / "out" buffer
    float* kb     = ws + 4 * S;                   // k / mlp-hidden t (2S: kb..vb)
    float* vb     = ws + 5 * S;
    float* proj   = ws + 6 * S;
    float* sim    = ws + 2 * S;                   // phase-1 overlay [2S, 2S+8M)
    int*   knn    = (int*)(ws + 7 * S);           // 131072 ints
    float* pooled = ws + 7 * S + 131072;          // 3072 floats
    // total ws use: (7*S + 131072 + 3072)*4 bytes ~= 88.6 MB

    // ---- encode + normalize + sim + topk
    k_encode<<<B_ * N_, 128, 0, stream>>>(x, W_enc, b_enc, h);
    k_normalize<<<B_ * N_, 128, 0, stream>>>(h, tmp1);
    k_gemm<true, false><<<dim3(16, 16, B_), 256, 0, stream>>>(
        tmp1, tmp1, nullptr, nullptr, sim, N_, N_, HID,
        (long)N_ * HID, (long)N_ * HID, (long)N_ * N_);
    k_topk<<<B_ * N_, 256, 0, stream>>>(sim, knn);

    const int M = B_ * N_;   // 8192
    for (int l = 0; l < L_; ++l) {
        const float* gW  = gcn_W + (long)l * HID * HID;
        const float* gB  = gcn_b + (long)l * HID;
        const float* wq  = Wq + (long)l * HID * HID;  const float* bql = bq + (long)l * HID;
        const float* wk  = Wk + (long)l * HID * HID;  const float* bkl = bk + (long)l * HID;
        const float* wv  = Wv + (long)l * HID * HID;  const float* bvl = bv + (long)l * HID;
        const float* wo  = Wo + (long)l * HID * HID;  const float* bol = bo + (long)l * HID;
        const float* w1  = mlp_W1 + (long)l * HID * 2 * HID;
        const float* b1l = mlp_b1 + (long)l * 2 * HID;
        const float* w2  = mlp_W2 + (long)l * 2 * HID * HID;
        const float* b2l = mlp_b2 + (long)l * HID;
        const float* ls0 = ln_s + (long)(l * 3 + 0) * HID; const float* lb0 = ln_b + (long)(l * 3 + 0) * HID;
        const float* ls1 = ln_s + (long)(l * 3 + 1) * HID; const float* lb1 = ln_b + (long)(l * 3 + 1) * HID;
        const float* ls2 = ln_s + (long)(l * 3 + 2) * HID; const float* lb2 = ln_b + (long)(l * 3 + 2) * HID;

        // xw = h @ gcn_W + gcn_b
        k_gemm<false, false><<<dim3(HID / 64, M / 64, 1), 256, 0, stream>>>(
            h, gW, gB, nullptr, tmp1, M, HID, HID, 0, 0, 0);
        // h_local = LN(h + gather(xw)/17)
        k_gcn_ln<<<B_ * N_, 128, 0, stream>>>(h, tmp1, knn, ls0, lb0, hlocal);
        // q, k, v
        k_gemm<false, false><<<dim3(HID / 64, M / 64, 1), 256, 0, stream>>>(
            h, wq, bql, nullptr, qb, M, HID, HID, 0, 0, 0);
        k_gemm<false, false><<<dim3(HID / 64, M / 64, 1), 256, 0, stream>>>(
            h, wk, bkl, nullptr, kb, M, HID, HID, 0, 0, 0);
        k_gemm<false, false><<<dim3(HID / 64, M / 64, 1), 256, 0, stream>>>(
            h, wv, bvl, nullptr, vb, M, HID, HID, 0, 0, 0);
        // attention -> o_pre (tmp1)
        k_attn<<<dim3(N_ / 8, NHEADS, B_), 256, 0, stream>>>(qb, kb, vb, tmp1);
        // proj = o_pre @ Wo + bo
        k_gemm<false, false><<<dim3(HID / 64, M / 64, 1), 256, 0, stream>>>(
            tmp1, wo, bol, nullptr, proj, M, HID, HID, 0, 0, 0);
        // out = hlocal + LN(h + proj)   -> qb
        k_addln<<<B_ * N_, 128, 0, stream>>>(h, proj, hlocal, ls1, lb1, qb);
        // t = relu(out @ W1 + b1)  -> kb (2S wide)
        k_gemm<false, true><<<dim3(2 * HID / 64, M / 64, 1), 256, 0, stream>>>(
            qb, w1, b1l, nullptr, kb, M, 2 * HID, HID, 0, 0, 0);
        // u = out + t @ W2 + b2   -> tmp1
        k_gemm<false, false><<<dim3(HID / 64, M / 64, 1), 256, 0, stream>>>(
            kb, w2, b2l, qb, tmp1, M, HID, 2 * HID, 0, 0, 0);
        // h = LN(u)
        k_addln<<<B_ * N_, 128, 0, stream>>>(tmp1, nullptr, nullptr, ls2, lb2, h);
    }

    k_pool<<<B_, 128, 0, stream>>>(h, pooled);
    k_head<<<B_, HID, 0, stream>>>(pooled, lin1_W, lin1_b, lin2_W, lin2_b,
                                   (float*)d_out);
}

// Round 4
// 3382.029 us; speedup vs baseline: 1.0437x; 1.0437x over previous
//
#include <hip/hip_runtime.h>
#include <hip/hip_bf16.h>

#define B_    8
#define C_    64
#define N_    1024
#define HID   384
#define OUTD  128
#define L_    3
#define KNN   16
#define NHEADS 3
#define DH    128

// ---------------------------------------------------------------- encode
// h[b,n,:] = x[b,:,n] @ W_enc + b_enc      (x is [B,C,H,W], n = h*W+w)
__global__ void k_encode(const float* __restrict__ x, const float* __restrict__ Wenc,
                         const float* __restrict__ benc, float* __restrict__ h) {
    int bn = blockIdx.x;                 // b*N + n
    int b = bn >> 10, n = bn & 1023;
    const float* xb = x + (long)b * C_ * N_ + n;
    for (int c0 = threadIdx.x; c0 < HID; c0 += blockDim.x) {
        float acc = benc[c0];
        for (int c = 0; c < C_; ++c)
            acc += xb[c * N_] * Wenc[c * HID + c0];
        h[(long)bn * HID + c0] = acc;
    }
}

// ---------------------------------------------------------------- row normalize
__global__ void k_normalize(const float* __restrict__ h, float* __restrict__ nh) {
    int bn = blockIdx.x;
    __shared__ float red[128];
    int tid = threadIdx.x;
    float ss = 0.f;
    for (int c = tid; c < HID; c += 128) { float v = h[(long)bn*HID+c]; ss += v*v; }
    red[tid] = ss; __syncthreads();
    for (int s = 64; s > 0; s >>= 1) { if (tid < s) red[tid] += red[tid+s]; __syncthreads(); }
    float inv = 1.0f / sqrtf(red[0]);
    for (int c = tid; c < HID; c += 128) nh[(long)bn*HID+c] = h[(long)bn*HID+c] * inv;
}

// ---------------------------------------------------------------- tiled f32 GEMM
// C[M,N] = A[M,K] @ B + bias + resid, optional relu.  BT: B stored [N,K] (NT gemm)
template<bool BT, bool RELU>
__global__ __launch_bounds__(256) void k_gemm(
        const float* __restrict__ A, const float* __restrict__ Bm,
        const float* __restrict__ bias, const float* __restrict__ resid,
        float* __restrict__ C, int M, int N, int K,
        long strideA, long strideB, long strideC) {
    __shared__ float As[16][68];
    __shared__ float Bs[16][68];
    int bz = blockIdx.z;
    A  += (long)bz * strideA;
    Bm += (long)bz * strideB;
    C  += (long)bz * strideC;
    int bm = blockIdx.y * 64, bn = blockIdx.x * 64;
    int tid = threadIdx.x;
    int ty = tid >> 4, tx = tid & 15;
    int lm = tid >> 2, lq = tid & 3;
    float acc[4][4] = {};
    for (int k0 = 0; k0 < K; k0 += 16) {
        {   // A tile: As[k][m]
            float4 av = *(const float4*)&A[(long)(bm + lm) * K + k0 + lq * 4];
            As[lq*4+0][lm] = av.x; As[lq*4+1][lm] = av.y;
            As[lq*4+2][lm] = av.z; As[lq*4+3][lm] = av.w;
        }
        if (BT) {
            float4 bv = *(const float4*)&Bm[(long)(bn + lm) * K + k0 + lq * 4];
            Bs[lq*4+0][lm] = bv.x; Bs[lq*4+1][lm] = bv.y;
            Bs[lq*4+2][lm] = bv.z; Bs[lq*4+3][lm] = bv.w;
        } else {
            int kk = tid >> 4, nq = tid & 15;
            float4 bv = *(const float4*)&Bm[(long)(k0 + kk) * N + bn + nq * 4];
            Bs[kk][nq*4+0] = bv.x; Bs[kk][nq*4+1] = bv.y;
            Bs[kk][nq*4+2] = bv.z; Bs[kk][nq*4+3] = bv.w;
        }
        __syncthreads();
        #pragma unroll
        for (int kk = 0; kk < 16; ++kk) {
            float4 a = *(const float4*)&As[kk][ty * 4];
            float4 b = *(const float4*)&Bs[kk][tx * 4];
            acc[0][0] += a.x*b.x; acc[0][1] += a.x*b.y; acc[0][2] += a.x*b.z; acc[0][3] += a.x*b.w;
            acc[1][0] += a.y*b.x; acc[1][1] += a.y*b.y; acc[1][2] += a.y*b.z; acc[1][3] += a.y*b.w;
            acc[2][0] += a.z*b.x; acc[2][1] += a.z*b.y; acc[2][2] += a.z*b.z; acc[2][3] += a.z*b.w;
            acc[3][0] += a.w*b.x; acc[3][1] += a.w*b.y; acc[3][2] += a.w*b.z; acc[3][3] += a.w*b.w;
        }
        __syncthreads();
    }
    #pragma unroll
    for (int i = 0; i < 4; ++i) {
        int row = bm + ty * 4 + i;
        #pragma unroll
        for (int j = 0; j < 4; ++j) {
            int col = bn + tx * 4 + j;
            float c = acc[i][j];
            if (bias)  c += bias[col];
            if (resid) c += resid[(long)row * N + col];
            if (RELU)  c = fmaxf(c, 0.f);
            C[(long)row * N + col] = c;
        }
    }
}

// ---------------------------------------------------------------- top-k (k=16) per row
__global__ __launch_bounds__(256) void k_topk(const float* __restrict__ sim, int* __restrict__ knn) {
    int bn = blockIdx.x; int b = bn >> 10, n = bn & 1023;
    __shared__ float sv[1024];
    __shared__ float rv[256];
    __shared__ int   ri[256];
    int tid = threadIdx.x;
    const float* row = sim + (long)b * N_ * N_ + (long)n * N_;
    for (int m = tid; m < N_; m += 256)
        sv[m] = row[m] - (m == n ? 2.0f : 0.0f);
    __syncthreads();
    for (int j = 0; j < KNN; ++j) {
        float best = -1e30f; int bi = 0;
        for (int m = tid; m < N_; m += 256) {
            float v = sv[m];
            if (v > best) { best = v; bi = m; }
        }
        rv[tid] = best; ri[tid] = bi; __syncthreads();
        for (int s = 128; s > 0; s >>= 1) {
            if (tid < s) {
                if (rv[tid+s] > rv[tid] || (rv[tid+s] == rv[tid] && ri[tid+s] < ri[tid])) {
                    rv[tid] = rv[tid+s]; ri[tid] = ri[tid+s];
                }
            }
            __syncthreads();
        }
        if (tid == 0) { knn[(long)bn * KNN + j] = ri[0]; sv[ri[0]] = -1e30f; }
        __syncthreads();
    }
}

// ---------------------------------------------------------------- GCN gather + residual + LN
// hlocal = LN(h + (xw[self] + sum_j xw[knn_j]) / 17)
__global__ void k_gcn_ln(const float* __restrict__ h, const float* __restrict__ xw,
                         const int* __restrict__ knn,
                         const float* __restrict__ lns, const float* __restrict__ lnb,
                         float* __restrict__ hlocal) {
    int bn = blockIdx.x; int b = bn >> 10;
    __shared__ int nb[KNN];
    __shared__ float red[128];
    int tid = threadIdx.x;
    if (tid < KNN) nb[tid] = knn[(long)bn * KNN + tid];
    __syncthreads();
    float val[3]; float sum = 0.f, ssq = 0.f;
    #pragma unroll
    for (int i = 0; i < 3; ++i) {
        int c = tid + i * 128;
        float acc = xw[(long)bn * HID + c];
        #pragma unroll
        for (int j = 0; j < KNN; ++j)
            acc += xw[((long)(b << 10) + nb[j]) * HID + c];
        float v = h[(long)bn * HID + c] + acc * (1.0f / 17.0f);
        val[i] = v; sum += v; ssq += v * v;
    }
    red[tid] = sum; __syncthreads();
    for (int s = 64; s > 0; s >>= 1) { if (tid < s) red[tid] += red[tid+s]; __syncthreads(); }
    sum = red[0]; __syncthreads();
    red[tid] = ssq; __syncthreads();
    for (int s = 64; s > 0; s >>= 1) { if (tid < s) red[tid] += red[tid+s]; __syncthreads(); }
    ssq = red[0];
    float mu = sum / HID;
    float var = ssq / HID - mu * mu;
    float inv = rsqrtf(var + 1e-5f);
    #pragma unroll
    for (int i = 0; i < 3; ++i) {
        int c = tid + i * 128;
        hlocal[(long)bn * HID + c] = (val[i] - mu) * inv * lns[c] + lnb[c];
    }
}

// ---------------------------------------------------------------- generic (a[+badd]) -> LN -> (+post)
__global__ void k_addln(const float* __restrict__ a, const float* __restrict__ badd,
                        const float* __restrict__ post,
                        const float* __restrict__ lns, const float* __restrict__ lnb,
                        float* __restrict__ outp) {
    int bn = blockIdx.x;
    __shared__ float red[128];
    int tid = threadIdx.x;
    float val[3]; float sum = 0.f, ssq = 0.f;
    #pragma unroll
    for (int i = 0; i < 3; ++i) {
        int c = tid + i * 128;
        float v = a[(long)bn * HID + c];
        if (badd) v += badd[(long)bn * HID + c];
        val[i] = v; sum += v; ssq += v * v;
    }
    red[tid] = sum; __syncthreads();
    for (int s = 64; s > 0; s >>= 1) { if (tid < s) red[tid] += red[tid+s]; __syncthreads(); }
    sum = red[0]; __syncthreads();
    red[tid] = ssq; __syncthreads();
    for (int s = 64; s > 0; s >>= 1) { if (tid < s) red[tid] += red[tid+s]; __syncthreads(); }
    ssq = red[0];
    float mu = sum / HID;
    float var = ssq / HID - mu * mu;
    float inv = rsqrtf(var + 1e-5f);
    #pragma unroll
    for (int i = 0; i < 3; ++i) {
        int c = tid + i * 128;
        float o = (val[i] - mu) * inv * lns[c] + lnb[c];
        if (post) o += post[(long)bn * HID + c];
        outp[(long)bn * HID + c] = o;
    }
}

// ---------------------------------------------------------------- attention (8 rows/block)
// QK^T into LDS, wave-parallel softmax (one 32-lane group per row, shfl
// butterfly, zero barriers in the reduction), PV with 4 independent
// accumulator chains (breaks FMA dependence, 4 loads in flight).
__global__ __launch_bounds__(256) void k_attn(const float* __restrict__ q,
                                              const float* __restrict__ kbuf,
                                              const float* __restrict__ v,
                                              float* __restrict__ o) {
    int b = blockIdx.z, hh = blockIdx.y, r0 = blockIdx.x * 8;
    __shared__ float qs[8][DH];
    __shared__ float sc[8][N_];
    int tid = threadIdx.x;
    {   // load Q tile (8 x 128)
        int r = tid >> 5, d4 = (tid & 31) * 4;
        *(float4*)&qs[r][d4] =
            *(const float4*)&q[((long)(b * N_ + r0 + r)) * HID + hh * DH + d4];
    }
    __syncthreads();
    const float scale = 0.08838834764831845f;   // 1/sqrt(128)
    // scores: each thread handles 4 key rows
    for (int mi = 0; mi < 4; ++mi) {
        int m = tid + mi * 256;
        const float* kr = &kbuf[((long)(b * N_ + m)) * HID + hh * DH];
        float acc[8] = {};
        for (int d = 0; d < DH; d += 4) {
            float4 kv = *(const float4*)&kr[d];
            #pragma unroll
            for (int r = 0; r < 8; ++r) {
                float4 qv = *(const float4*)&qs[r][d];
                acc[r] += qv.x*kv.x + qv.y*kv.y + qv.z*kv.z + qv.w*kv.w;
            }
        }
        #pragma unroll
        for (int r = 0; r < 8; ++r) sc[r][m] = acc[r] * scale;
    }
    __syncthreads();
    // wave-parallel softmax: 32-lane group per row, all in registers
    int r = tid >> 5, lane = tid & 31;
    float vals[32];
    float mx = -1e30f;
    #pragma unroll
    for (int i = 0; i < 32; ++i) {
        vals[i] = sc[r][lane + 32 * i];
        mx = fmaxf(mx, vals[i]);
    }
    #pragma unroll
    for (int mask = 16; mask >= 1; mask >>= 1)
        mx = fmaxf(mx, __shfl_xor(mx, mask));
    float sm = 0.f;
    #pragma unroll
    for (int i = 0; i < 32; ++i) {
        float e = __expf(vals[i] - mx);
        sc[r][lane + 32 * i] = e;
        sm += e;
    }
    #pragma unroll
    for (int mask = 16; mask >= 1; mask >>= 1)
        sm += __shfl_xor(sm, mask);
    float is = 1.0f / sm;
    __syncthreads();
    // attn @ V — 4 independent chains
    int c4 = lane * 4;
    const float* vbase = &v[((long)(b * N_)) * HID + hh * DH + c4];
    float4 a0 = {0,0,0,0}, a1 = {0,0,0,0}, a2 = {0,0,0,0}, a3 = {0,0,0,0};
    for (int m = 0; m < N_; m += 4) {
        float p0 = sc[r][m + 0], p1 = sc[r][m + 1];
        float p2 = sc[r][m + 2], p3 = sc[r][m + 3];
        float4 v0 = *(const float4*)&vbase[(long)(m + 0) * HID];
        float4 v1 = *(const float4*)&vbase[(long)(m + 1) * HID];
        float4 v2 = *(const float4*)&vbase[(long)(m + 2) * HID];
        float4 v3 = *(const float4*)&vbase[(long)(m + 3) * HID];
        a0.x += p0*v0.x; a0.y += p0*v0.y; a0.z += p0*v0.z; a0.w += p0*v0.w;
        a1.x += p1*v1.x; a1.y += p1*v1.y; a1.z += p1*v1.z; a1.w += p1*v1.w;
        a2.x += p2*v2.x; a2.y += p2*v2.y; a2.z += p2*v2.z; a2.w += p2*v2.w;
        a3.x += p3*v3.x; a3.y += p3*v3.y; a3.z += p3*v3.z; a3.w += p3*v3.w;
    }
    float4 accv;
    accv.x = ((a0.x + a1.x) + (a2.x + a3.x)) * is;
    accv.y = ((a0.y + a1.y) + (a2.y + a3.y)) * is;
    accv.z = ((a0.z + a1.z) + (a2.z + a3.z)) * is;
    accv.w = ((a0.w + a1.w) + (a2.w + a3.w)) * is;
    *(float4*)&o[((long)(b * N_ + r0 + r)) * HID + hh * DH + c4] = accv;
}

// ---------------------------------------------------------------- mean pool over N
__global__ void k_pool(const float* __restrict__ h, float* __restrict__ pooled) {
    int b = blockIdx.x; int tid = threadIdx.x;   // 128 threads
    #pragma unroll
    for (int i = 0; i < 3; ++i) {
        int c = tid + i * 128;
        float s = 0.f;
        for (int n = 0; n < N_; ++n) s += h[((long)(b * N_ + n)) * HID + c];
        pooled[b * HID + c] = s * (1.0f / N_);
    }
}

// ---------------------------------------------------------------- head: relu(p@W1+b1)@W2+b2 -> f32
__global__ void k_head(const float* __restrict__ pooled,
                       const float* __restrict__ w1, const float* __restrict__ b1,
                       const float* __restrict__ w2, const float* __restrict__ b2,
                       float* __restrict__ out) {
    int b = blockIdx.x; int tid = threadIdx.x;   // 384 threads
    __shared__ float z[HID];
    float acc = b1[tid];
    for (int c = 0; c < HID; ++c) acc += pooled[b * HID + c] * w1[c * HID + tid];
    z[tid] = fmaxf(acc, 0.f);
    __syncthreads();
    if (tid < OUTD) {
        float a2 = b2[tid];
        for (int j = 0; j < HID; ++j) a2 += z[j] * w2[j * OUTD + tid];
        out[b * OUTD + tid] = a2;            // OUTPUT IS F32 (reference dtype)
    }
}

// ================================================================ launch
extern "C" void kernel_launch(void* const* d_in, const int* in_sizes, int n_in,
                              void* d_out, int out_size, void* d_ws, size_t ws_size,
                              hipStream_t stream) {
    const float* x       = (const float*)d_in[0];
    const float* W_enc   = (const float*)d_in[1];
    const float* b_enc   = (const float*)d_in[2];
    const float* gcn_W   = (const float*)d_in[3];
    const float* gcn_b   = (const float*)d_in[4];
    const float* Wq      = (const float*)d_in[5];
    const float* bq      = (const float*)d_in[6];
    const float* Wk      = (const float*)d_in[7];
    const float* bk      = (const float*)d_in[8];
    const float* Wv      = (const float*)d_in[9];
    const float* bv      = (const float*)d_in[10];
    const float* Wo      = (const float*)d_in[11];
    const float* bo      = (const float*)d_in[12];
    const float* ln_s    = (const float*)d_in[13];
    const float* ln_b    = (const float*)d_in[14];
    const float* mlp_W1  = (const float*)d_in[15];
    const float* mlp_b1  = (const float*)d_in[16];
    const float* mlp_W2  = (const float*)d_in[17];
    const float* mlp_b2  = (const float*)d_in[18];
    const float* lin1_W  = (const float*)d_in[19];
    const float* lin1_b  = (const float*)d_in[20];
    const float* lin2_W  = (const float*)d_in[21];
    const float* lin2_b  = (const float*)d_in[22];

    float* ws = (float*)d_ws;
    const long S = (long)B_ * N_ * HID;          // 3,145,728 floats
    float* h      = ws;                           // [0, S)
    float* tmp1   = ws + S;                       // nh / xw / o_pre / u
    float* hlocal = ws + 2 * S;
    float* qb     = ws + 3 * S;                   // q / "out" buffer
    float* kb     = ws + 4 * S;                   // k / mlp-hidden t (2S: kb..vb)
    float* vb     = ws + 5 * S;
    float* proj   = ws + 6 * S;
    float* sim    = ws + 2 * S;                   // phase-1 overlay [2S, 2S+8M)
    int*   knn    = (int*)(ws + 7 * S);           // 131072 ints
    float* pooled = ws + 7 * S + 131072;          // 3072 floats
    // total ws use: (7*S + 131072 + 3072)*4 bytes ~= 88.6 MB

    // ---- encode + normalize + sim + topk
    k_encode<<<B_ * N_, 128, 0, stream>>>(x, W_enc, b_enc, h);
    k_normalize<<<B_ * N_, 128, 0, stream>>>(h, tmp1);
    k_gemm<true, false><<<dim3(16, 16, B_), 256, 0, stream>>>(
        tmp1, tmp1, nullptr, nullptr, sim, N_, N_, HID,
        (long)N_ * HID, (long)N_ * HID, (long)N_ * N_);
    k_topk<<<B_ * N_, 256, 0, stream>>>(sim, knn);

    const int M = B_ * N_;   // 8192
    for (int l = 0; l < L_; ++l) {
        const float* gW  = gcn_W + (long)l * HID * HID;
        const float* gB  = gcn_b + (long)l * HID;
        const float* wq  = Wq + (long)l * HID * HID;  const float* bql = bq + (long)l * HID;
        const float* wk  = Wk + (long)l * HID * HID;  const float* bkl = bk + (long)l * HID;
        const float* wv  = Wv + (long)l * HID * HID;  const float* bvl = bv + (long)l * HID;
        const float* wo  = Wo + (long)l * HID * HID;  const float* bol = bo + (long)l * HID;
        const float* w1  = mlp_W1 + (long)l * HID * 2 * HID;
        const float* b1l = mlp_b1 + (long)l * 2 * HID;
        const float* w2  = mlp_W2 + (long)l * 2 * HID * HID;
        const float* b2l = mlp_b2 + (long)l * HID;
        const float* ls0 = ln_s + (long)(l * 3 + 0) * HID; const float* lb0 = ln_b + (long)(l * 3 + 0) * HID;
        const float* ls1 = ln_s + (long)(l * 3 + 1) * HID; const float* lb1 = ln_b + (long)(l * 3 + 1) * HID;
        const float* ls2 = ln_s + (long)(l * 3 + 2) * HID; const float* lb2 = ln_b + (long)(l * 3 + 2) * HID;

        // xw = h @ gcn_W + gcn_b
        k_gemm<false, false><<<dim3(HID / 64, M / 64, 1), 256, 0, stream>>>(
            h, gW, gB, nullptr, tmp1, M, HID, HID, 0, 0, 0);
        // h_local = LN(h + gather(xw)/17)
        k_gcn_ln<<<B_ * N_, 128, 0, stream>>>(h, tmp1, knn, ls0, lb0, hlocal);
        // q, k, v
        k_gemm<false, false><<<dim3(HID / 64, M / 64, 1), 256, 0, stream>>>(
            h, wq, bql, nullptr, qb, M, HID, HID, 0, 0, 0);
        k_gemm<false, false><<<dim3(HID / 64, M / 64, 1), 256, 0, stream>>>(
            h, wk, bkl, nullptr, kb, M, HID, HID, 0, 0, 0);
        k_gemm<false, false><<<dim3(HID / 64, M / 64, 1), 256, 0, stream>>>(
            h, wv, bvl, nullptr, vb, M, HID, HID, 0, 0, 0);
        // attention -> o_pre (tmp1)
        k_attn<<<dim3(N_ / 8, NHEADS, B_), 256, 0, stream>>>(qb, kb, vb, tmp1);
        // proj = o_pre @ Wo + bo
        k_gemm<false, false><<<dim3(HID / 64, M / 64, 1), 256, 0, stream>>>(
            tmp1, wo, bol, nullptr, proj, M, HID, HID, 0, 0, 0);
        // out = hlocal + LN(h + proj)   -> qb
        k_addln<<<B_ * N_, 128, 0, stream>>>(h, proj, hlocal, ls1, lb1, qb);
        // t = relu(out @ W1 + b1)  -> kb (2S wide)
        k_gemm<false, true><<<dim3(2 * HID / 64, M / 64, 1), 256, 0, stream>>>(
            qb, w1, b1l, nullptr, kb, M, 2 * HID, HID, 0, 0, 0);
        // u = out + t @ W2 + b2   -> tmp1
        k_gemm<false, false><<<dim3(HID / 64, M / 64, 1), 256, 0, stream>>>(
            kb, w2, b2l, qb, tmp1, M, HID, 2 * HID, 0, 0, 0);
        // h = LN(u)
        k_addln<<<B_ * N_, 128, 0, stream>>>(tmp1, nullptr, nullptr, ls2, lb2, h);
    }

    k_pool<<<B_, 128, 0, stream>>>(h, pooled);
    k_head<<<B_, HID, 0, stream>>>(pooled, lin1_W, lin1_b, lin2_W, lin2_b,
                                   (float*)d_out);
}

// Round 5
// 1318.336 us; speedup vs baseline: 2.6774x; 2.5654x over previous
//
#include <hip/hip_runtime.h>
#include <hip/hip_bf16.h>

#define B_    8
#define C_    64
#define N_    1024
#define HID   384
#define OUTD  128
#define L_    3
#define KNN   16
#define NHEADS 3
#define DH    128

typedef __attribute__((ext_vector_type(8))) short    s16x8;   // MFMA A/B frag: 8 bf16
typedef __attribute__((ext_vector_type(4))) float    f32x4;   // MFMA C/D frag
typedef __attribute__((ext_vector_type(8))) unsigned short u16x8;
typedef __attribute__((ext_vector_type(4))) unsigned short u16x4;

// RNE f32 -> bf16 (finite inputs)
__device__ __forceinline__ ushort f2b(float f) {
    uint x = __float_as_uint(f);
    return (ushort)((x + 0x7fff + ((x >> 16) & 1)) >> 16);
}
__device__ __forceinline__ float b2f(uint u) {
    return __uint_as_float(u << 16);
}

// ---------------------------------------------------------------- encode (f32)
__global__ void k_encode(const float* __restrict__ x, const float* __restrict__ Wenc,
                         const float* __restrict__ benc, float* __restrict__ h) {
    int bn = blockIdx.x;
    int b = bn >> 10;
    const float* xb = x + (long)b * C_ * N_ + (bn & 1023);
    for (int c0 = threadIdx.x; c0 < HID; c0 += blockDim.x) {
        float acc = benc[c0];
        for (int c = 0; c < C_; ++c)
            acc += xb[c * N_] * Wenc[c * HID + c0];
        h[(long)bn * HID + c0] = acc;
    }
}

// ---------------------------------------------------------------- row normalize (f32)
__global__ void k_normalize(const float* __restrict__ h, float* __restrict__ nh) {
    int bn = blockIdx.x;
    __shared__ float red[128];
    int tid = threadIdx.x;
    float ss = 0.f;
    for (int c = tid; c < HID; c += 128) { float v = h[(long)bn*HID+c]; ss += v*v; }
    red[tid] = ss; __syncthreads();
    for (int s = 64; s > 0; s >>= 1) { if (tid < s) red[tid] += red[tid+s]; __syncthreads(); }
    float inv = 1.0f / sqrtf(red[0]);
    for (int c = tid; c < HID; c += 128) nh[(long)bn*HID+c] = h[(long)bn*HID+c] * inv;
}

// ---------------------------------------------------------------- f32 GEMM (sim only, NT)
template<bool BT, bool RELU>
__global__ __launch_bounds__(256) void k_gemm(
        const float* __restrict__ A, const float* __restrict__ Bm,
        const float* __restrict__ bias, const float* __restrict__ resid,
        float* __restrict__ C, int M, int N, int K,
        long strideA, long strideB, long strideC) {
    __shared__ float As[16][68];
    __shared__ float Bs[16][68];
    int bz = blockIdx.z;
    A  += (long)bz * strideA;
    Bm += (long)bz * strideB;
    C  += (long)bz * strideC;
    int bm = blockIdx.y * 64, bn = blockIdx.x * 64;
    int tid = threadIdx.x;
    int ty = tid >> 4, tx = tid & 15;
    int lm = tid >> 2, lq = tid & 3;
    float acc[4][4] = {};
    for (int k0 = 0; k0 < K; k0 += 16) {
        {
            float4 av = *(const float4*)&A[(long)(bm + lm) * K + k0 + lq * 4];
            As[lq*4+0][lm] = av.x; As[lq*4+1][lm] = av.y;
            As[lq*4+2][lm] = av.z; As[lq*4+3][lm] = av.w;
        }
        if (BT) {
            float4 bv = *(const float4*)&Bm[(long)(bn + lm) * K + k0 + lq * 4];
            Bs[lq*4+0][lm] = bv.x; Bs[lq*4+1][lm] = bv.y;
            Bs[lq*4+2][lm] = bv.z; Bs[lq*4+3][lm] = bv.w;
        } else {
            int kk = tid >> 4, nq = tid & 15;
            float4 bv = *(const float4*)&Bm[(long)(k0 + kk) * N + bn + nq * 4];
            Bs[kk][nq*4+0] = bv.x; Bs[kk][nq*4+1] = bv.y;
            Bs[kk][nq*4+2] = bv.z; Bs[kk][nq*4+3] = bv.w;
        }
        __syncthreads();
        #pragma unroll
        for (int kk = 0; kk < 16; ++kk) {
            float4 a = *(const float4*)&As[kk][ty * 4];
            float4 b = *(const float4*)&Bs[kk][tx * 4];
            acc[0][0] += a.x*b.x; acc[0][1] += a.x*b.y; acc[0][2] += a.x*b.z; acc[0][3] += a.x*b.w;
            acc[1][0] += a.y*b.x; acc[1][1] += a.y*b.y; acc[1][2] += a.y*b.z; acc[1][3] += a.y*b.w;
            acc[2][0] += a.z*b.x; acc[2][1] += a.z*b.y; acc[2][2] += a.z*b.z; acc[2][3] += a.z*b.w;
            acc[3][0] += a.w*b.x; acc[3][1] += a.w*b.y; acc[3][2] += a.w*b.z; acc[3][3] += a.w*b.w;
        }
        __syncthreads();
    }
    #pragma unroll
    for (int i = 0; i < 4; ++i) {
        int row = bm + ty * 4 + i;
        #pragma unroll
        for (int j = 0; j < 4; ++j) {
            int col = bn + tx * 4 + j;
            float c = acc[i][j];
            if (bias)  c += bias[col];
            if (resid) c += resid[(long)row * N + col];
            if (RELU)  c = fmaxf(c, 0.f);
            C[(long)row * N + col] = c;
        }
    }
}

// ---------------------------------------------------------------- top-k (k=16) per row (f32, exact)
__global__ __launch_bounds__(256) void k_topk(const float* __restrict__ sim, int* __restrict__ knn) {
    int bn = blockIdx.x; int b = bn >> 10, n = bn & 1023;
    __shared__ float sv[1024];
    __shared__ float rv[256];
    __shared__ int   ri[256];
    int tid = threadIdx.x;
    const float* row = sim + (long)b * N_ * N_ + (long)n * N_;
    for (int m = tid; m < N_; m += 256)
        sv[m] = row[m] - (m == n ? 2.0f : 0.0f);
    __syncthreads();
    for (int j = 0; j < KNN; ++j) {
        float best = -1e30f; int bi = 0;
        for (int m = tid; m < N_; m += 256) {
            float v = sv[m];
            if (v > best) { best = v; bi = m; }
        }
        rv[tid] = best; ri[tid] = bi; __syncthreads();
        for (int s = 128; s > 0; s >>= 1) {
            if (tid < s) {
                if (rv[tid+s] > rv[tid] || (rv[tid+s] == rv[tid] && ri[tid+s] < ri[tid])) {
                    rv[tid] = rv[tid+s]; ri[tid] = ri[tid+s];
                }
            }
            __syncthreads();
        }
        if (tid == 0) { knn[(long)bn * KNN + j] = ri[0]; sv[ri[0]] = -1e30f; }
        __syncthreads();
    }
}

// ---------------------------------------------------------------- weight cast+transpose
// 15 square weights [384][384] f32 -> bf16 [384][384] transposed
__global__ void k_cast15(const float* __restrict__ g, const float* __restrict__ q,
                         const float* __restrict__ k, const float* __restrict__ v,
                         const float* __restrict__ o, ushort* __restrict__ out) {
    int z = blockIdx.z; int type = z / 3, l = z % 3;
    const float* in = (type == 0 ? g : type == 1 ? q : type == 2 ? k : type == 3 ? v : o)
                      + (long)l * HID * HID;
    ushort* op = out + (long)z * HID * HID;
    __shared__ float t[32][33];
    int c0 = blockIdx.x * 32, r0 = blockIdx.y * 32;
    int tid = threadIdx.x; int i = tid & 31, j4 = tid >> 5;
    #pragma unroll
    for (int rr = 0; rr < 4; ++rr) {
        int r = j4 * 4 + rr;
        t[r][i] = in[(long)(r0 + r) * HID + c0 + i];
    }
    __syncthreads();
    #pragma unroll
    for (int rr = 0; rr < 4; ++rr) {
        int c = j4 * 4 + rr;
        op[(long)(c0 + c) * HID + r0 + i] = f2b(t[i][c]);
    }
}

// generic: in f32 [R][C] -> out bf16 [C][R]; z batches whole matrices
__global__ void k_castT(const float* __restrict__ in_, ushort* __restrict__ out_,
                        int R, int C) {
    long mz = (long)blockIdx.z * R * C;
    const float* in = in_ + mz;
    ushort* op = out_ + mz;
    __shared__ float t[32][33];
    int c0 = blockIdx.x * 32, r0 = blockIdx.y * 32;
    int tid = threadIdx.x; int i = tid & 31, j4 = tid >> 5;
    #pragma unroll
    for (int rr = 0; rr < 4; ++rr) {
        int r = j4 * 4 + rr;
        t[r][i] = in[(long)(r0 + r) * C + c0 + i];
    }
    __syncthreads();
    #pragma unroll
    for (int rr = 0; rr < 4; ++rr) {
        int c = j4 * 4 + rr;
        op[(long)(c0 + c) * R + r0 + i] = f2b(t[i][c]);
    }
}

// ---------------------------------------------------------------- MFMA GEMM
// C[M,N] = A[M,K] @ Wt[N,K]^T + bias (+resid) (+relu)
// OUTMODE: 0 = f32 [M][N], 1 = bf16 [M][N], 2 = bf16 transposed [N][ldcT]
// Tile 64x64, BK=32, 4 waves; wave w -> rows [w*16,w*16+16), 4 col-frags.
template<int OUTMODE, bool RELU, bool ABF16>
__global__ __launch_bounds__(256) void k_mgemm(
        const void* __restrict__ Ap, const ushort* __restrict__ Wt,
        const float* __restrict__ bias, const float* __restrict__ resid,
        void* __restrict__ Cout, int M, int N, int K, long ldcT) {
    __shared__ ushort Al[64][40];   // stride 80B (odd multiple of 16B)
    __shared__ ushort Bl[64][40];
    int bm = blockIdx.y * 64, bnn = blockIdx.x * 64;
    int tid = threadIdx.x;
    int w = tid >> 6, l = tid & 63;
    int sr = tid >> 2, skq = (tid & 3) * 8;     // staging: row 0..63, k-offset {0,8,16,24}
    f32x4 zero = {0.f, 0.f, 0.f, 0.f};
    f32x4 acc[4] = {zero, zero, zero, zero};
    for (int k0 = 0; k0 < K; k0 += 32) {
        // stage A (cast f32->bf16 unless ABF16)
        if (ABF16) {
            const ushort* As = (const ushort*)Ap + (long)(bm + sr) * K + k0 + skq;
            *(u16x8*)&Al[sr][skq] = *(const u16x8*)As;
        } else {
            const float* As = (const float*)Ap + (long)(bm + sr) * K + k0 + skq;
            float4 a0 = *(const float4*)As;
            float4 a1 = *(const float4*)(As + 4);
            u16x8 v;
            v[0]=f2b(a0.x); v[1]=f2b(a0.y); v[2]=f2b(a0.z); v[3]=f2b(a0.w);
            v[4]=f2b(a1.x); v[5]=f2b(a1.y); v[6]=f2b(a1.z); v[7]=f2b(a1.w);
            *(u16x8*)&Al[sr][skq] = v;
        }
        // stage Wt (bf16 copy)
        {
            const ushort* Ws = Wt + (long)(bnn + sr) * K + k0 + skq;
            *(u16x8*)&Bl[sr][skq] = *(const u16x8*)Ws;
        }
        __syncthreads();
        s16x8 af = *(const s16x8*)&Al[w * 16 + (l & 15)][(l >> 4) * 8];
        #pragma unroll
        for (int cb = 0; cb < 4; ++cb) {
            s16x8 bf = *(const s16x8*)&Bl[cb * 16 + (l & 15)][(l >> 4) * 8];
            acc[cb] = __builtin_amdgcn_mfma_f32_16x16x32_bf16(af, bf, acc[cb], 0, 0, 0);
        }
        __syncthreads();
    }
    // epilogue
    #pragma unroll
    for (int cb = 0; cb < 4; ++cb) {
        int coln = bnn + cb * 16 + (l & 15);
        float bv = bias[coln];
        if (OUTMODE == 2) {
            int tok0 = bm + w * 16 + (l >> 4) * 4;
            u16x4 pk;
            #pragma unroll
            for (int reg = 0; reg < 4; ++reg)
                pk[reg] = f2b(acc[cb][reg] + bv);
            *(u16x4*)((ushort*)Cout + (long)coln * ldcT + tok0) = pk;
        } else {
            #pragma unroll
            for (int reg = 0; reg < 4; ++reg) {
                int rowg = bm + w * 16 + (l >> 4) * 4 + reg;
                float v = acc[cb][reg] + bv;
                if (resid) v += resid[(long)rowg * N + coln];
                if (RELU)  v = fmaxf(v, 0.f);
                if (OUTMODE == 0) ((float*)Cout)[(long)rowg * N + coln] = v;
                else              ((ushort*)Cout)[(long)rowg * N + coln] = f2b(v);
            }
        }
    }
}

// ---------------------------------------------------------------- GCN gather + residual + LN (f32)
__global__ void k_gcn_ln(const float* __restrict__ h, const float* __restrict__ xw,
                         const int* __restrict__ knn,
                         const float* __restrict__ lns, const float* __restrict__ lnb,
                         float* __restrict__ hlocal) {
    int bn = blockIdx.x; int b = bn >> 10;
    __shared__ int nb[KNN];
    __shared__ float red[128];
    int tid = threadIdx.x;
    if (tid < KNN) nb[tid] = knn[(long)bn * KNN + tid];
    __syncthreads();
    float val[3]; float sum = 0.f, ssq = 0.f;
    #pragma unroll
    for (int i = 0; i < 3; ++i) {
        int c = tid + i * 128;
        float acc = xw[(long)bn * HID + c];
        #pragma unroll
        for (int j = 0; j < KNN; ++j)
            acc += xw[((long)(b << 10) + nb[j]) * HID + c];
        float v = h[(long)bn * HID + c] + acc * (1.0f / 17.0f);
        val[i] = v; sum += v; ssq += v * v;
    }
    red[tid] = sum; __syncthreads();
    for (int s = 64; s > 0; s >>= 1) { if (tid < s) red[tid] += red[tid+s]; __syncthreads(); }
    sum = red[0]; __syncthreads();
    red[tid] = ssq; __syncthreads();
    for (int s = 64; s > 0; s >>= 1) { if (tid < s) red[tid] += red[tid+s]; __syncthreads(); }
    ssq = red[0];
    float mu = sum / HID;
    float var = ssq / HID - mu * mu;
    float inv = rsqrtf(var + 1e-5f);
    #pragma unroll
    for (int i = 0; i < 3; ++i) {
        int c = tid + i * 128;
        hlocal[(long)bn * HID + c] = (val[i] - mu) * inv * lns[c] + lnb[c];
    }
}

// ---------------------------------------------------------------- (a[+badd]) -> LN -> (+post) (f32)
__global__ void k_addln(const float* __restrict__ a, const float* __restrict__ badd,
                        const float* __restrict__ post,
                        const float* __restrict__ lns, const float* __restrict__ lnb,
                        float* __restrict__ outp) {
    int bn = blockIdx.x;
    __shared__ float red[128];
    int tid = threadIdx.x;
    float val[3]; float sum = 0.f, ssq = 0.f;
    #pragma unroll
    for (int i = 0; i < 3; ++i) {
        int c = tid + i * 128;
        float v = a[(long)bn * HID + c];
        if (badd) v += badd[(long)bn * HID + c];
        val[i] = v; sum += v; ssq += v * v;
    }
    red[tid] = sum; __syncthreads();
    for (int s = 64; s > 0; s >>= 1) { if (tid < s) red[tid] += red[tid+s]; __syncthreads(); }
    sum = red[0]; __syncthreads();
    red[tid] = ssq; __syncthreads();
    for (int s = 64; s > 0; s >>= 1) { if (tid < s) red[tid] += red[tid+s]; __syncthreads(); }
    ssq = red[0];
    float mu = sum / HID;
    float var = ssq / HID - mu * mu;
    float inv = rsqrtf(var + 1e-5f);
    #pragma unroll
    for (int i = 0; i < 3; ++i) {
        int c = tid + i * 128;
        float o = (val[i] - mu) * inv * lns[c] + lnb[c];
        if (post) o += post[(long)bn * HID + c];
        outp[(long)bn * HID + c] = o;
    }
}

// ---------------------------------------------------------------- MFMA attention
// 16 rows/block, 4 waves. q,k bf16 [token][384]; v bf16 TRANSPOSED [dim384][token8192].
// S tiles of 64 keys -> sc bf16 (full row in LDS), wave-parallel softmax, MFMA PV.
__global__ __launch_bounds__(256) void k_attn(const ushort* __restrict__ qb,
                                              const ushort* __restrict__ kb,
                                              const ushort* __restrict__ vt,
                                              float* __restrict__ o) {
    int b = blockIdx.z, hh = blockIdx.y, r0 = blockIdx.x * 16;
    __shared__ ushort sc[16][1032];     // bf16 scores/probs; stride 2064B (odd x 16B)
    __shared__ ushort kvt[9216];        // union: Kt[64][136] | VtT[128][72]
    __shared__ float rowinv[16];
    int tid = threadIdx.x;
    int w = tid >> 6, l = tid & 63;
    // preload Q frags (row = l&15, dh-contiguous)
    s16x8 aq[4];
    const ushort* qrow = qb + ((long)(b * N_) + r0 + (l & 15)) * HID + hh * DH + (l >> 4) * 8;
    #pragma unroll
    for (int ks = 0; ks < 4; ++ks) aq[ks] = *(const s16x8*)(qrow + ks * 32);
    const float scale = 0.08838834764831845f;   // 1/sqrt(128)
    // ---------- S = Q K^T
    for (int m0 = 0; m0 < N_; m0 += 64) {
        {   // stage K tile [64 keys][128 dh] -> Kt[key][136]
            int key = tid >> 2, seg = tid & 3;
            const ushort* src = kb + ((long)(b * N_) + m0 + key) * HID + hh * DH + seg * 32;
            ushort* dst = &kvt[key * 136 + seg * 32];
            #pragma unroll
            for (int i = 0; i < 4; ++i)
                *(u16x8*)(dst + i * 8) = *(const u16x8*)(src + i * 8);
        }
        __syncthreads();
        f32x4 acc = {0.f, 0.f, 0.f, 0.f};
        #pragma unroll
        for (int ks = 0; ks < 4; ++ks) {
            s16x8 bk = *(const s16x8*)&kvt[(w * 16 + (l & 15)) * 136 + ks * 32 + (l >> 4) * 8];
            acc = __builtin_amdgcn_mfma_f32_16x16x32_bf16(aq[ks], bk, acc, 0, 0, 0);
        }
        int key = m0 + w * 16 + (l & 15);
        #pragma unroll
        for (int reg = 0; reg < 4; ++reg)
            sc[(l >> 4) * 4 + reg][key] = f2b(acc[reg] * scale);
        __syncthreads();
    }
    // ---------- softmax (group of 32 lanes per row; rows g and g+8)
    {
        int g = tid >> 5, l2 = tid & 31;
        #pragma unroll
        for (int rr = 0; rr < 2; ++rr) {
            int row = g + rr * 8;
            float v[32];
            #pragma unroll
            for (int i = 0; i < 16; ++i) {
                uint u = *(const uint*)&sc[row][l2 * 2 + i * 64];
                v[2*i]   = b2f(u & 0xffffu);
                v[2*i+1] = b2f(u >> 16);
            }
            float mx = v[0];
            #pragma unroll
            for (int i = 1; i < 32; ++i) mx = fmaxf(mx, v[i]);
            #pragma unroll
            for (int m = 16; m >= 1; m >>= 1) mx = fmaxf(mx, __shfl_xor(mx, m));
            float sm = 0.f;
            #pragma unroll
            for (int i = 0; i < 16; ++i) {
                float e0 = __expf(v[2*i]   - mx);
                float e1 = __expf(v[2*i+1] - mx);
                sm += e0 + e1;
                *(uint*)&sc[row][l2 * 2 + i * 64] = (uint)f2b(e0) | ((uint)f2b(e1) << 16);
            }
            #pragma unroll
            for (int m = 16; m >= 1; m >>= 1) sm += __shfl_xor(sm, m);
            if (l2 == 0) rowinv[row] = 1.0f / sm;
        }
    }
    __syncthreads();
    // ---------- O = P V
    f32x4 zero = {0.f, 0.f, 0.f, 0.f};
    f32x4 oacc[2] = {zero, zero};
    for (int m0 = 0; m0 < N_; m0 += 64) {
        {   // stage V^T tile [128 dims][64 keys] -> VtT[dim][72]
            int dim = tid >> 1, half = tid & 1;
            const ushort* src = vt + ((long)(hh * DH + dim)) * (B_ * N_) + b * N_ + m0 + half * 32;
            ushort* dst = &kvt[dim * 72 + half * 32];
            #pragma unroll
            for (int i = 0; i < 4; ++i)
                *(u16x8*)(dst + i * 8) = *(const u16x8*)(src + i * 8);
        }
        __syncthreads();
        #pragma unroll
        for (int ks = 0; ks < 2; ++ks) {
            s16x8 pf = *(const s16x8*)&sc[l & 15][m0 + ks * 32 + (l >> 4) * 8];
            #pragma unroll
            for (int d = 0; d < 2; ++d) {
                s16x8 vf = *(const s16x8*)&kvt[((w * 2 + d) * 16 + (l & 15)) * 72 + ks * 32 + (l >> 4) * 8];
                oacc[d] = __builtin_amdgcn_mfma_f32_16x16x32_bf16(pf, vf, oacc[d], 0, 0, 0);
            }
        }
        __syncthreads();
    }
    // epilogue: scale by 1/rowsum, write f32
    #pragma unroll
    for (int d = 0; d < 2; ++d) {
        int dim = (w * 2 + d) * 16 + (l & 15);
        #pragma unroll
        for (int reg = 0; reg < 4; ++reg) {
            int row = (l >> 4) * 4 + reg;
            o[((long)(b * N_) + r0 + row) * HID + hh * DH + dim] = oacc[d][reg] * rowinv[row];
        }
    }
}

// ---------------------------------------------------------------- mean pool over N (f32)
__global__ void k_pool(const float* __restrict__ h, float* __restrict__ pooled) {
    int b = blockIdx.x; int tid = threadIdx.x;   // 128 threads
    #pragma unroll
    for (int i = 0; i < 3; ++i) {
        int c = tid + i * 128;
        float s = 0.f;
        for (int n = 0; n < N_; ++n) s += h[((long)(b * N_ + n)) * HID + c];
        pooled[b * HID + c] = s * (1.0f / N_);
    }
}

// ---------------------------------------------------------------- head (f32)
__global__ void k_head(const float* __restrict__ pooled,
                       const float* __restrict__ w1, const float* __restrict__ b1,
                       const float* __restrict__ w2, const float* __restrict__ b2,
                       float* __restrict__ out) {
    int b = blockIdx.x; int tid = threadIdx.x;   // 384 threads
    __shared__ float z[HID];
    float acc = b1[tid];
    for (int c = 0; c < HID; ++c) acc += pooled[b * HID + c] * w1[c * HID + tid];
    z[tid] = fmaxf(acc, 0.f);
    __syncthreads();
    if (tid < OUTD) {
        float a2 = b2[tid];
        for (int j = 0; j < HID; ++j) a2 += z[j] * w2[j * OUTD + tid];
        out[b * OUTD + tid] = a2;
    }
}

// ================================================================ launch
extern "C" void kernel_launch(void* const* d_in, const int* in_sizes, int n_in,
                              void* d_out, int out_size, void* d_ws, size_t ws_size,
                              hipStream_t stream) {
    const float* x       = (const float*)d_in[0];
    const float* W_enc   = (const float*)d_in[1];
    const float* b_enc   = (const float*)d_in[2];
    const float* gcn_W   = (const float*)d_in[3];
    const float* gcn_b   = (const float*)d_in[4];
    const float* Wq      = (const float*)d_in[5];
    const float* bq      = (const float*)d_in[6];
    const float* Wk      = (const float*)d_in[7];
    const float* bk      = (const float*)d_in[8];
    const float* Wv      = (const float*)d_in[9];
    const float* bv      = (const float*)d_in[10];
    const float* Wo      = (const float*)d_in[11];
    const float* bo      = (const float*)d_in[12];
    const float* ln_s    = (const float*)d_in[13];
    const float* ln_b    = (const float*)d_in[14];
    const float* mlp_W1  = (const float*)d_in[15];
    const float* mlp_b1  = (const float*)d_in[16];
    const float* mlp_W2  = (const float*)d_in[17];
    const float* mlp_b2  = (const float*)d_in[18];
    const float* lin1_W  = (const float*)d_in[19];
    const float* lin1_b  = (const float*)d_in[20];
    const float* lin2_W  = (const float*)d_in[21];
    const float* lin2_b  = (const float*)d_in[22];

    const long S = (long)B_ * N_ * HID;            // 3,145,728
    char* base = (char*)d_ws;
    float* h      = (float*)(base);
    float* tmp1   = (float*)(base + (size_t)S * 4);       // xw / o / u
    float* hlocal = (float*)(base + (size_t)S * 8);
    float* outb   = (float*)(base + (size_t)S * 12);
    char*  tzone  = base + (size_t)S * 16;                // 2S f32 region (multi-use)
    float* proj   = (float*)(base + (size_t)S * 24);
    // overlays of tzone (disjoint in time):
    float*  sim = (float*)tzone;                          // phase-1 (33.5MB <= tzone+proj)
    ushort* qbf = (ushort*)tzone;                         // steps 3-6
    ushort* kbf = (ushort*)(tzone + (size_t)S * 2);
    ushort* vbT = (ushort*)(tzone + (size_t)S * 4);
    ushort* tb  = (ushort*)tzone;                         // steps 9-10 (q/k/v dead)
    int*    knn    = (int*)(base + (size_t)S * 28);
    float*  pooled = (float*)(base + (size_t)S * 28 + 524288);
    ushort* wts    = (ushort*)(base + (size_t)S * 28 + 524288 + 16384);
    const long SQ = (long)HID * HID;                      // 147456
    ushort* w1T = wts + 15 * SQ;
    ushort* w2T = w1T + 3 * (long)HID * 2 * HID;

    // ---- weight cast+transpose (bf16 [N][K])
    k_cast15<<<dim3(12, 12, 15), 256, 0, stream>>>(gcn_W, Wq, Wk, Wv, Wo, wts);
    k_castT<<<dim3(24, 12, 3), 256, 0, stream>>>(mlp_W1, w1T, HID, 2 * HID);   // [384][768]->[768][384]
    k_castT<<<dim3(12, 24, 3), 256, 0, stream>>>(mlp_W2, w2T, 2 * HID, HID);   // [768][384]->[384][768]

    // ---- encode + normalize + sim (f32 exact) + topk
    k_encode<<<B_ * N_, 128, 0, stream>>>(x, W_enc, b_enc, h);
    k_normalize<<<B_ * N_, 128, 0, stream>>>(h, tmp1);
    k_gemm<true, false><<<dim3(16, 16, B_), 256, 0, stream>>>(
        tmp1, tmp1, nullptr, nullptr, sim, N_, N_, HID,
        (long)N_ * HID, (long)N_ * HID, (long)N_ * N_);
    k_topk<<<B_ * N_, 256, 0, stream>>>(sim, knn);

    const int M = B_ * N_;   // 8192
    for (int l = 0; l < L_; ++l) {
        const ushort* gWt = wts + (long)(0 + l) * SQ;
        const ushort* wqT = wts + (long)(3 + l) * SQ;
        const ushort* wkT = wts + (long)(6 + l) * SQ;
        const ushort* wvT = wts + (long)(9 + l) * SQ;
        const ushort* woT = wts + (long)(12 + l) * SQ;
        const ushort* w1Tl = w1T + (long)l * HID * 2 * HID;
        const ushort* w2Tl = w2T + (long)l * HID * 2 * HID;
        const float* gB  = gcn_b + (long)l * HID;
        const float* bql = bq + (long)l * HID;
        const float* bkl = bk + (long)l * HID;
        const float* bvl = bv + (long)l * HID;
        const float* bol = bo + (long)l * HID;
        const float* b1l = mlp_b1 + (long)l * 2 * HID;
        const float* b2l = mlp_b2 + (long)l * HID;
        const float* ls0 = ln_s + (long)(l * 3 + 0) * HID; const float* lb0 = ln_b + (long)(l * 3 + 0) * HID;
        const float* ls1 = ln_s + (long)(l * 3 + 1) * HID; const float* lb1 = ln_b + (long)(l * 3 + 1) * HID;
        const float* ls2 = ln_s + (long)(l * 3 + 2) * HID; const float* lb2 = ln_b + (long)(l * 3 + 2) * HID;

        // xw = h @ gcn_W + gcn_b  (f32 out)
        k_mgemm<0, false, false><<<dim3(HID / 64, M / 64), 256, 0, stream>>>(
            h, gWt, gB, nullptr, tmp1, M, HID, HID, 0);
        k_gcn_ln<<<B_ * N_, 128, 0, stream>>>(h, tmp1, knn, ls0, lb0, hlocal);
        // q, k (bf16), v (bf16 transposed)
        k_mgemm<1, false, false><<<dim3(HID / 64, M / 64), 256, 0, stream>>>(
            h, wqT, bql, nullptr, qbf, M, HID, HID, 0);
        k_mgemm<1, false, false><<<dim3(HID / 64, M / 64), 256, 0, stream>>>(
            h, wkT, bkl, nullptr, kbf, M, HID, HID, 0);
        k_mgemm<2, false, false><<<dim3(HID / 64, M / 64), 256, 0, stream>>>(
            h, wvT, bvl, nullptr, vbT, M, HID, HID, (long)M);
        // attention -> o (tmp1, f32)
        k_attn<<<dim3(N_ / 16, NHEADS, B_), 256, 0, stream>>>(qbf, kbf, vbT, tmp1);
        // proj = o @ Wo + bo (f32)
        k_mgemm<0, false, false><<<dim3(HID / 64, M / 64), 256, 0, stream>>>(
            tmp1, woT, bol, nullptr, proj, M, HID, HID, 0);
        // out = hlocal + LN(h + proj) -> outb
        k_addln<<<B_ * N_, 128, 0, stream>>>(h, proj, hlocal, ls1, lb1, outb);
        // t = relu(out @ W1 + b1) -> bf16 tb
        k_mgemm<1, true, false><<<dim3(2 * HID / 64, M / 64), 256, 0, stream>>>(
            outb, w1Tl, b1l, nullptr, tb, M, 2 * HID, HID, 0);
        // u = out + t @ W2 + b2 -> tmp1 (f32)
        k_mgemm<0, false, true><<<dim3(HID / 64, M / 64), 256, 0, stream>>>(
            tb, w2Tl, b2l, outb, tmp1, M, HID, 2 * HID, 0);
        // h = LN(u)
        k_addln<<<B_ * N_, 128, 0, stream>>>(tmp1, nullptr, nullptr, ls2, lb2, h);
    }

    k_pool<<<B_, 128, 0, stream>>>(h, pooled);
    k_head<<<B_, HID, 0, stream>>>(pooled, lin1_W, lin1_b, lin2_W, lin2_b,
                                   (float*)d_out);
}

// Round 6
// 1114.278 us; speedup vs baseline: 3.1677x; 1.1831x over previous
//
#include <hip/hip_runtime.h>
#include <hip/hip_bf16.h>

#define B_    8
#define C_    64
#define N_    1024
#define HID   384
#define OUTD  128
#define L_    3
#define KNN   16
#define NHEADS 3
#define DH    128

typedef __attribute__((ext_vector_type(8))) short    s16x8;   // MFMA A/B frag: 8 bf16
typedef __attribute__((ext_vector_type(4))) float    f32x4;   // MFMA C/D frag
typedef __attribute__((ext_vector_type(8))) unsigned short u16x8;
typedef __attribute__((ext_vector_type(4))) unsigned short u16x4;

// RNE f32 -> bf16 (finite inputs)
__device__ __forceinline__ ushort f2b(float f) {
    uint x = __float_as_uint(f);
    return (ushort)((x + 0x7fff + ((x >> 16) & 1)) >> 16);
}
__device__ __forceinline__ float b2f(uint u) {
    return __uint_as_float(u << 16);
}

// ---------------------------------------------------------------- encode (f32)
__global__ void k_encode(const float* __restrict__ x, const float* __restrict__ Wenc,
                         const float* __restrict__ benc, float* __restrict__ h) {
    int bn = blockIdx.x;
    int b = bn >> 10;
    const float* xb = x + (long)b * C_ * N_ + (bn & 1023);
    for (int c0 = threadIdx.x; c0 < HID; c0 += blockDim.x) {
        float acc = benc[c0];
        for (int c = 0; c < C_; ++c)
            acc += xb[c * N_] * Wenc[c * HID + c0];
        h[(long)bn * HID + c0] = acc;
    }
}

// ---------------------------------------------------------------- row normalize (f32)
__global__ void k_normalize(const float* __restrict__ h, float* __restrict__ nh) {
    int bn = blockIdx.x;
    __shared__ float red[128];
    int tid = threadIdx.x;
    float ss = 0.f;
    for (int c = tid; c < HID; c += 128) { float v = h[(long)bn*HID+c]; ss += v*v; }
    red[tid] = ss; __syncthreads();
    for (int s = 64; s > 0; s >>= 1) { if (tid < s) red[tid] += red[tid+s]; __syncthreads(); }
    float inv = 1.0f / sqrtf(red[0]);
    for (int c = tid; c < HID; c += 128) nh[(long)bn*HID+c] = h[(long)bn*HID+c] * inv;
}

// ---------------------------------------------------------------- f32 GEMM (sim only, NT)
template<bool BT, bool RELU>
__global__ __launch_bounds__(256) void k_gemm(
        const float* __restrict__ A, const float* __restrict__ Bm,
        const float* __restrict__ bias, const float* __restrict__ resid,
        float* __restrict__ C, int M, int N, int K,
        long strideA, long strideB, long strideC) {
    __shared__ float As[16][68];
    __shared__ float Bs[16][68];
    int bz = blockIdx.z;
    A  += (long)bz * strideA;
    Bm += (long)bz * strideB;
    C  += (long)bz * strideC;
    int bm = blockIdx.y * 64, bn = blockIdx.x * 64;
    int tid = threadIdx.x;
    int ty = tid >> 4, tx = tid & 15;
    int lm = tid >> 2, lq = tid & 3;
    float acc[4][4] = {};
    for (int k0 = 0; k0 < K; k0 += 16) {
        {
            float4 av = *(const float4*)&A[(long)(bm + lm) * K + k0 + lq * 4];
            As[lq*4+0][lm] = av.x; As[lq*4+1][lm] = av.y;
            As[lq*4+2][lm] = av.z; As[lq*4+3][lm] = av.w;
        }
        if (BT) {
            float4 bv = *(const float4*)&Bm[(long)(bn + lm) * K + k0 + lq * 4];
            Bs[lq*4+0][lm] = bv.x; Bs[lq*4+1][lm] = bv.y;
            Bs[lq*4+2][lm] = bv.z; Bs[lq*4+3][lm] = bv.w;
        } else {
            int kk = tid >> 4, nq = tid & 15;
            float4 bv = *(const float4*)&Bm[(long)(k0 + kk) * N + bn + nq * 4];
            Bs[kk][nq*4+0] = bv.x; Bs[kk][nq*4+1] = bv.y;
            Bs[kk][nq*4+2] = bv.z; Bs[kk][nq*4+3] = bv.w;
        }
        __syncthreads();
        #pragma unroll
        for (int kk = 0; kk < 16; ++kk) {
            float4 a = *(const float4*)&As[kk][ty * 4];
            float4 b = *(const float4*)&Bs[kk][tx * 4];
            acc[0][0] += a.x*b.x; acc[0][1] += a.x*b.y; acc[0][2] += a.x*b.z; acc[0][3] += a.x*b.w;
            acc[1][0] += a.y*b.x; acc[1][1] += a.y*b.y; acc[1][2] += a.y*b.z; acc[1][3] += a.y*b.w;
            acc[2][0] += a.z*b.x; acc[2][1] += a.z*b.y; acc[2][2] += a.z*b.z; acc[2][3] += a.z*b.w;
            acc[3][0] += a.w*b.x; acc[3][1] += a.w*b.y; acc[3][2] += a.w*b.z; acc[3][3] += a.w*b.w;
        }
        __syncthreads();
    }
    #pragma unroll
    for (int i = 0; i < 4; ++i) {
        int row = bm + ty * 4 + i;
        #pragma unroll
        for (int j = 0; j < 4; ++j) {
            int col = bn + tx * 4 + j;
            float c = acc[i][j];
            if (bias)  c += bias[col];
            if (resid) c += resid[(long)row * N + col];
            if (RELU)  c = fmaxf(c, 0.f);
            C[(long)row * N + col] = c;
        }
    }
}

// ---------------------------------------------------------------- top-k (k=16) per row (f32, exact)
__global__ __launch_bounds__(256) void k_topk(const float* __restrict__ sim, int* __restrict__ knn) {
    int bn = blockIdx.x; int b = bn >> 10, n = bn & 1023;
    __shared__ float sv[1024];
    __shared__ float rv[256];
    __shared__ int   ri[256];
    int tid = threadIdx.x;
    const float* row = sim + (long)b * N_ * N_ + (long)n * N_;
    for (int m = tid; m < N_; m += 256)
        sv[m] = row[m] - (m == n ? 2.0f : 0.0f);
    __syncthreads();
    for (int j = 0; j < KNN; ++j) {
        float best = -1e30f; int bi = 0;
        for (int m = tid; m < N_; m += 256) {
            float v = sv[m];
            if (v > best) { best = v; bi = m; }
        }
        rv[tid] = best; ri[tid] = bi; __syncthreads();
        for (int s = 128; s > 0; s >>= 1) {
            if (tid < s) {
                if (rv[tid+s] > rv[tid] || (rv[tid+s] == rv[tid] && ri[tid+s] < ri[tid])) {
                    rv[tid] = rv[tid+s]; ri[tid] = ri[tid+s];
                }
            }
            __syncthreads();
        }
        if (tid == 0) { knn[(long)bn * KNN + j] = ri[0]; sv[ri[0]] = -1e30f; }
        __syncthreads();
    }
}

// ---------------------------------------------------------------- weight cast+transpose
// 15 square weights [384][384] f32 -> bf16 [384][384] transposed
__global__ void k_cast15(const float* __restrict__ g, const float* __restrict__ q,
                         const float* __restrict__ k, const float* __restrict__ v,
                         const float* __restrict__ o, ushort* __restrict__ out) {
    int z = blockIdx.z; int type = z / 3, l = z % 3;
    const float* in = (type == 0 ? g : type == 1 ? q : type == 2 ? k : type == 3 ? v : o)
                      + (long)l * HID * HID;
    ushort* op = out + (long)z * HID * HID;
    __shared__ float t[32][33];
    int c0 = blockIdx.x * 32, r0 = blockIdx.y * 32;
    int tid = threadIdx.x; int i = tid & 31, j4 = tid >> 5;
    #pragma unroll
    for (int rr = 0; rr < 4; ++rr) {
        int r = j4 * 4 + rr;
        t[r][i] = in[(long)(r0 + r) * HID + c0 + i];
    }
    __syncthreads();
    #pragma unroll
    for (int rr = 0; rr < 4; ++rr) {
        int c = j4 * 4 + rr;
        op[(long)(c0 + c) * HID + r0 + i] = f2b(t[i][c]);
    }
}

// generic: in f32 [R][C] -> out bf16 [C][R]; z batches whole matrices
__global__ void k_castT(const float* __restrict__ in_, ushort* __restrict__ out_,
                        int R, int C) {
    long mz = (long)blockIdx.z * R * C;
    const float* in = in_ + mz;
    ushort* op = out_ + mz;
    __shared__ float t[32][33];
    int c0 = blockIdx.x * 32, r0 = blockIdx.y * 32;
    int tid = threadIdx.x; int i = tid & 31, j4 = tid >> 5;
    #pragma unroll
    for (int rr = 0; rr < 4; ++rr) {
        int r = j4 * 4 + rr;
        t[r][i] = in[(long)(r0 + r) * C + c0 + i];
    }
    __syncthreads();
    #pragma unroll
    for (int rr = 0; rr < 4; ++rr) {
        int c = j4 * 4 + rr;
        op[(long)(c0 + c) * R + r0 + i] = f2b(t[i][c]);
    }
}

// ---------------------------------------------------------------- MFMA GEMM
// C[M,N] = A[M,K] @ Wt[N,K]^T + bias (+resid) (+relu)
// OUTMODE: 0 = f32 [M][N], 1 = bf16 [M][N], 2 = bf16 transposed [N][ldcT]
template<int OUTMODE, bool RELU, bool ABF16>
__global__ __launch_bounds__(256) void k_mgemm(
        const void* __restrict__ Ap, const ushort* __restrict__ Wt,
        const float* __restrict__ bias, const float* __restrict__ resid,
        void* __restrict__ Cout, int M, int N, int K, long ldcT) {
    __shared__ ushort Al[64][40];   // stride 80B (odd multiple of 16B)
    __shared__ ushort Bl[64][40];
    int bm = blockIdx.y * 64, bnn = blockIdx.x * 64;
    int tid = threadIdx.x;
    int w = tid >> 6, l = tid & 63;
    int sr = tid >> 2, skq = (tid & 3) * 8;
    f32x4 zero = {0.f, 0.f, 0.f, 0.f};
    f32x4 acc[4] = {zero, zero, zero, zero};
    for (int k0 = 0; k0 < K; k0 += 32) {
        if (ABF16) {
            const ushort* As = (const ushort*)Ap + (long)(bm + sr) * K + k0 + skq;
            *(u16x8*)&Al[sr][skq] = *(const u16x8*)As;
        } else {
            const float* As = (const float*)Ap + (long)(bm + sr) * K + k0 + skq;
            float4 a0 = *(const float4*)As;
            float4 a1 = *(const float4*)(As + 4);
            u16x8 v;
            v[0]=f2b(a0.x); v[1]=f2b(a0.y); v[2]=f2b(a0.z); v[3]=f2b(a0.w);
            v[4]=f2b(a1.x); v[5]=f2b(a1.y); v[6]=f2b(a1.z); v[7]=f2b(a1.w);
            *(u16x8*)&Al[sr][skq] = v;
        }
        {
            const ushort* Ws = Wt + (long)(bnn + sr) * K + k0 + skq;
            *(u16x8*)&Bl[sr][skq] = *(const u16x8*)Ws;
        }
        __syncthreads();
        s16x8 af = *(const s16x8*)&Al[w * 16 + (l & 15)][(l >> 4) * 8];
        #pragma unroll
        for (int cb = 0; cb < 4; ++cb) {
            s16x8 bf = *(const s16x8*)&Bl[cb * 16 + (l & 15)][(l >> 4) * 8];
            acc[cb] = __builtin_amdgcn_mfma_f32_16x16x32_bf16(af, bf, acc[cb], 0, 0, 0);
        }
        __syncthreads();
    }
    #pragma unroll
    for (int cb = 0; cb < 4; ++cb) {
        int coln = bnn + cb * 16 + (l & 15);
        float bv = bias[coln];
        if (OUTMODE == 2) {
            int tok0 = bm + w * 16 + (l >> 4) * 4;
            u16x4 pk;
            #pragma unroll
            for (int reg = 0; reg < 4; ++reg)
                pk[reg] = f2b(acc[cb][reg] + bv);
            *(u16x4*)((ushort*)Cout + (long)coln * ldcT + tok0) = pk;
        } else {
            #pragma unroll
            for (int reg = 0; reg < 4; ++reg) {
                int rowg = bm + w * 16 + (l >> 4) * 4 + reg;
                float v = acc[cb][reg] + bv;
                if (resid) v += resid[(long)rowg * N + coln];
                if (RELU)  v = fmaxf(v, 0.f);
                if (OUTMODE == 0) ((float*)Cout)[(long)rowg * N + coln] = v;
                else              ((ushort*)Cout)[(long)rowg * N + coln] = f2b(v);
            }
        }
    }
}

// ---------------------------------------------------------------- GCN gather + residual + LN (f32)
__global__ void k_gcn_ln(const float* __restrict__ h, const float* __restrict__ xw,
                         const int* __restrict__ knn,
                         const float* __restrict__ lns, const float* __restrict__ lnb,
                         float* __restrict__ hlocal) {
    int bn = blockIdx.x; int b = bn >> 10;
    __shared__ int nb[KNN];
    __shared__ float red[128];
    int tid = threadIdx.x;
    if (tid < KNN) nb[tid] = knn[(long)bn * KNN + tid];
    __syncthreads();
    float val[3]; float sum = 0.f, ssq = 0.f;
    #pragma unroll
    for (int i = 0; i < 3; ++i) {
        int c = tid + i * 128;
        float acc = xw[(long)bn * HID + c];
        #pragma unroll
        for (int j = 0; j < KNN; ++j)
            acc += xw[((long)(b << 10) + nb[j]) * HID + c];
        float v = h[(long)bn * HID + c] + acc * (1.0f / 17.0f);
        val[i] = v; sum += v; ssq += v * v;
    }
    red[tid] = sum; __syncthreads();
    for (int s = 64; s > 0; s >>= 1) { if (tid < s) red[tid] += red[tid+s]; __syncthreads(); }
    sum = red[0]; __syncthreads();
    red[tid] = ssq; __syncthreads();
    for (int s = 64; s > 0; s >>= 1) { if (tid < s) red[tid] += red[tid+s]; __syncthreads(); }
    ssq = red[0];
    float mu = sum / HID;
    float var = ssq / HID - mu * mu;
    float inv = rsqrtf(var + 1e-5f);
    #pragma unroll
    for (int i = 0; i < 3; ++i) {
        int c = tid + i * 128;
        hlocal[(long)bn * HID + c] = (val[i] - mu) * inv * lns[c] + lnb[c];
    }
}

// ---------------------------------------------------------------- (a[+badd]) -> LN -> (+post) (f32)
__global__ void k_addln(const float* __restrict__ a, const float* __restrict__ badd,
                        const float* __restrict__ post,
                        const float* __restrict__ lns, const float* __restrict__ lnb,
                        float* __restrict__ outp) {
    int bn = blockIdx.x;
    __shared__ float red[128];
    int tid = threadIdx.x;
    float val[3]; float sum = 0.f, ssq = 0.f;
    #pragma unroll
    for (int i = 0; i < 3; ++i) {
        int c = tid + i * 128;
        float v = a[(long)bn * HID + c];
        if (badd) v += badd[(long)bn * HID + c];
        val[i] = v; sum += v; ssq += v * v;
    }
    red[tid] = sum; __syncthreads();
    for (int s = 64; s > 0; s >>= 1) { if (tid < s) red[tid] += red[tid+s]; __syncthreads(); }
    sum = red[0]; __syncthreads();
    red[tid] = ssq; __syncthreads();
    for (int s = 64; s > 0; s >>= 1) { if (tid < s) red[tid] += red[tid+s]; __syncthreads(); }
    ssq = red[0];
    float mu = sum / HID;
    float var = ssq / HID - mu * mu;
    float inv = rsqrtf(var + 1e-5f);
    #pragma unroll
    for (int i = 0; i < 3; ++i) {
        int c = tid + i * 128;
        float o = (val[i] - mu) * inv * lns[c] + lnb[c];
        if (post) o += post[(long)bn * HID + c];
        outp[(long)bn * HID + c] = o;
    }
}

// ---------------------------------------------------------------- MFMA attention
__global__ __launch_bounds__(256) void k_attn(const ushort* __restrict__ qb,
                                              const ushort* __restrict__ kb,
                                              const ushort* __restrict__ vt,
                                              float* __restrict__ o) {
    int b = blockIdx.z, hh = blockIdx.y, r0 = blockIdx.x * 16;
    __shared__ ushort sc[16][1032];     // bf16 scores/probs; stride 2064B (odd x 16B)
    __shared__ ushort kvt[9216];        // union: Kt[64][136] | VtT[128][72]
    __shared__ float rowinv[16];
    int tid = threadIdx.x;
    int w = tid >> 6, l = tid & 63;
    s16x8 aq[4];
    const ushort* qrow = qb + ((long)(b * N_) + r0 + (l & 15)) * HID + hh * DH + (l >> 4) * 8;
    #pragma unroll
    for (int ks = 0; ks < 4; ++ks) aq[ks] = *(const s16x8*)(qrow + ks * 32);
    const float scale = 0.08838834764831845f;   // 1/sqrt(128)
    // ---------- S = Q K^T
    for (int m0 = 0; m0 < N_; m0 += 64) {
        {
            int key = tid >> 2, seg = tid & 3;
            const ushort* src = kb + ((long)(b * N_) + m0 + key) * HID + hh * DH + seg * 32;
            ushort* dst = &kvt[key * 136 + seg * 32];
            #pragma unroll
            for (int i = 0; i < 4; ++i)
                *(u16x8*)(dst + i * 8) = *(const u16x8*)(src + i * 8);
        }
        __syncthreads();
        f32x4 acc = {0.f, 0.f, 0.f, 0.f};
        #pragma unroll
        for (int ks = 0; ks < 4; ++ks) {
            s16x8 bk = *(const s16x8*)&kvt[(w * 16 + (l & 15)) * 136 + ks * 32 + (l >> 4) * 8];
            acc = __builtin_amdgcn_mfma_f32_16x16x32_bf16(aq[ks], bk, acc, 0, 0, 0);
        }
        int key = m0 + w * 16 + (l & 15);
        #pragma unroll
        for (int reg = 0; reg < 4; ++reg)
            sc[(l >> 4) * 4 + reg][key] = f2b(acc[reg] * scale);
        __syncthreads();
    }
    // ---------- softmax
    {
        int g = tid >> 5, l2 = tid & 31;
        #pragma unroll
        for (int rr = 0; rr < 2; ++rr) {
            int row = g + rr * 8;
            float v[32];
            #pragma unroll
            for (int i = 0; i < 16; ++i) {
                uint u = *(const uint*)&sc[row][l2 * 2 + i * 64];
                v[2*i]   = b2f(u & 0xffffu);
                v[2*i+1] = b2f(u >> 16);
            }
            float mx = v[0];
            #pragma unroll
            for (int i = 1; i < 32; ++i) mx = fmaxf(mx, v[i]);
            #pragma unroll
            for (int m = 16; m >= 1; m >>= 1) mx = fmaxf(mx, __shfl_xor(mx, m));
            float sm = 0.f;
            #pragma unroll
            for (int i = 0; i < 16; ++i) {
                float e0 = __expf(v[2*i]   - mx);
                float e1 = __expf(v[2*i+1] - mx);
                sm += e0 + e1;
                *(uint*)&sc[row][l2 * 2 + i * 64] = (uint)f2b(e0) | ((uint)f2b(e1) << 16);
            }
            #pragma unroll
            for (int m = 16; m >= 1; m >>= 1) sm += __shfl_xor(sm, m);
            if (l2 == 0) rowinv[row] = 1.0f / sm;
        }
    }
    __syncthreads();
    // ---------- O = P V
    f32x4 zero = {0.f, 0.f, 0.f, 0.f};
    f32x4 oacc[2] = {zero, zero};
    for (int m0 = 0; m0 < N_; m0 += 64) {
        {
            int dim = tid >> 1, half = tid & 1;
            const ushort* src = vt + ((long)(hh * DH + dim)) * (B_ * N_) + b * N_ + m0 + half * 32;
            ushort* dst = &kvt[dim * 72 + half * 32];
            #pragma unroll
            for (int i = 0; i < 4; ++i)
                *(u16x8*)(dst + i * 8) = *(const u16x8*)(src + i * 8);
        }
        __syncthreads();
        #pragma unroll
        for (int ks = 0; ks < 2; ++ks) {
            s16x8 pf = *(const s16x8*)&sc[l & 15][m0 + ks * 32 + (l >> 4) * 8];
            #pragma unroll
            for (int d = 0; d < 2; ++d) {
                s16x8 vf = *(const s16x8*)&kvt[((w * 2 + d) * 16 + (l & 15)) * 72 + ks * 32 + (l >> 4) * 8];
                oacc[d] = __builtin_amdgcn_mfma_f32_16x16x32_bf16(pf, vf, oacc[d], 0, 0, 0);
            }
        }
        __syncthreads();
    }
    #pragma unroll
    for (int d = 0; d < 2; ++d) {
        int dim = (w * 2 + d) * 16 + (l & 15);
        #pragma unroll
        for (int reg = 0; reg < 4; ++reg) {
            int row = (l >> 4) * 4 + reg;
            o[((long)(b * N_) + r0 + row) * HID + hh * DH + dim] = oacc[d][reg] * rowinv[row];
        }
    }
}

// ---------------------------------------------------------------- mean pool, two-stage
// stage 1: block (seg s, graph b): sum rows [s*32, s*32+32) -> partial[(b*32+s)][c]
__global__ __launch_bounds__(384) void k_pool1(const float* __restrict__ h,
                                               float* __restrict__ partial) {
    int s = blockIdx.x, b = blockIdx.y;
    int c = threadIdx.x;
    const float* hp = h + ((long)(b * N_) + s * 32) * HID + c;
    float acc = 0.f;
    #pragma unroll
    for (int n = 0; n < 32; ++n) acc += hp[(long)n * HID];
    partial[((long)(b * 32) + s) * HID + c] = acc;
}
// stage 2: block b: sum 32 partials, * 1/N
__global__ __launch_bounds__(384) void k_pool2(const float* __restrict__ partial,
                                               float* __restrict__ pooled) {
    int b = blockIdx.x;
    int c = threadIdx.x;
    const float* pp = partial + (long)(b * 32) * HID + c;
    float acc = 0.f;
    #pragma unroll
    for (int s = 0; s < 32; ++s) acc += pp[(long)s * HID];
    pooled[b * HID + c] = acc * (1.0f / N_);
}

// ---------------------------------------------------------------- head (f32)
__global__ void k_head(const float* __restrict__ pooled,
                       const float* __restrict__ w1, const float* __restrict__ b1,
                       const float* __restrict__ w2, const float* __restrict__ b2,
                       float* __restrict__ out) {
    int b = blockIdx.x; int tid = threadIdx.x;   // 384 threads
    __shared__ float z[HID];
    float acc = b1[tid];
    for (int c = 0; c < HID; ++c) acc += pooled[b * HID + c] * w1[c * HID + tid];
    z[tid] = fmaxf(acc, 0.f);
    __syncthreads();
    if (tid < OUTD) {
        float a2 = b2[tid];
        for (int j = 0; j < HID; ++j) a2 += z[j] * w2[j * OUTD + tid];
        out[b * OUTD + tid] = a2;
    }
}

// ================================================================ launch
extern "C" void kernel_launch(void* const* d_in, const int* in_sizes, int n_in,
                              void* d_out, int out_size, void* d_ws, size_t ws_size,
                              hipStream_t stream) {
    const float* x       = (const float*)d_in[0];
    const float* W_enc   = (const float*)d_in[1];
    const float* b_enc   = (const float*)d_in[2];
    const float* gcn_W   = (const float*)d_in[3];
    const float* gcn_b   = (const float*)d_in[4];
    const float* Wq      = (const float*)d_in[5];
    const float* bq      = (const float*)d_in[6];
    const float* Wk      = (const float*)d_in[7];
    const float* bk      = (const float*)d_in[8];
    const float* Wv      = (const float*)d_in[9];
    const float* bv      = (const float*)d_in[10];
    const float* Wo      = (const float*)d_in[11];
    const float* bo      = (const float*)d_in[12];
    const float* ln_s    = (const float*)d_in[13];
    const float* ln_b    = (const float*)d_in[14];
    const float* mlp_W1  = (const float*)d_in[15];
    const float* mlp_b1  = (const float*)d_in[16];
    const float* mlp_W2  = (const float*)d_in[17];
    const float* mlp_b2  = (const float*)d_in[18];
    const float* lin1_W  = (const float*)d_in[19];
    const float* lin1_b  = (const float*)d_in[20];
    const float* lin2_W  = (const float*)d_in[21];
    const float* lin2_b  = (const float*)d_in[22];

    const long S = (long)B_ * N_ * HID;            // 3,145,728
    char* base = (char*)d_ws;
    float* h      = (float*)(base);
    float* tmp1   = (float*)(base + (size_t)S * 4);       // xw / o / u / pool-partial
    float* hlocal = (float*)(base + (size_t)S * 8);
    float* outb   = (float*)(base + (size_t)S * 12);
    char*  tzone  = base + (size_t)S * 16;                // 2S f32 region (multi-use)
    float* proj   = (float*)(base + (size_t)S * 24);
    float*  sim = (float*)tzone;
    ushort* qbf = (ushort*)tzone;
    ushort* kbf = (ushort*)(tzone + (size_t)S * 2);
    ushort* vbT = (ushort*)(tzone + (size_t)S * 4);
    ushort* tb  = (ushort*)tzone;
    int*    knn    = (int*)(base + (size_t)S * 28);
    float*  pooled = (float*)(base + (size_t)S * 28 + 524288);
    ushort* wts    = (ushort*)(base + (size_t)S * 28 + 524288 + 16384);
    const long SQ = (long)HID * HID;
    ushort* w1T = wts + 15 * SQ;
    ushort* w2T = w1T + 3 * (long)HID * 2 * HID;
    float* partial = tmp1;    // pool stage-1 partials (tmp1 is dead at pool time)

    // ---- weight cast+transpose (bf16 [N][K])
    k_cast15<<<dim3(12, 12, 15), 256, 0, stream>>>(gcn_W, Wq, Wk, Wv, Wo, wts);
    k_castT<<<dim3(24, 12, 3), 256, 0, stream>>>(mlp_W1, w1T, HID, 2 * HID);
    k_castT<<<dim3(12, 24, 3), 256, 0, stream>>>(mlp_W2, w2T, 2 * HID, HID);

    // ---- encode + normalize + sim (f32 exact) + topk
    k_encode<<<B_ * N_, 128, 0, stream>>>(x, W_enc, b_enc, h);
    k_normalize<<<B_ * N_, 128, 0, stream>>>(h, tmp1);
    k_gemm<true, false><<<dim3(16, 16, B_), 256, 0, stream>>>(
        tmp1, tmp1, nullptr, nullptr, sim, N_, N_, HID,
        (long)N_ * HID, (long)N_ * HID, (long)N_ * N_);
    k_topk<<<B_ * N_, 256, 0, stream>>>(sim, knn);

    const int M = B_ * N_;   // 8192
    for (int l = 0; l < L_; ++l) {
        const ushort* gWt = wts + (long)(0 + l) * SQ;
        const ushort* wqT = wts + (long)(3 + l) * SQ;
        const ushort* wkT = wts + (long)(6 + l) * SQ;
        const ushort* wvT = wts + (long)(9 + l) * SQ;
        const ushort* woT = wts + (long)(12 + l) * SQ;
        const ushort* w1Tl = w1T + (long)l * HID * 2 * HID;
        const ushort* w2Tl = w2T + (long)l * HID * 2 * HID;
        const float* gB  = gcn_b + (long)l * HID;
        const float* bql = bq + (long)l * HID;
        const float* bkl = bk + (long)l * HID;
        const float* bvl = bv + (long)l * HID;
        const float* bol = bo + (long)l * HID;
        const float* b1l = mlp_b1 + (long)l * 2 * HID;
        const float* b2l = mlp_b2 + (long)l * HID;
        const float* ls0 = ln_s + (long)(l * 3 + 0) * HID; const float* lb0 = ln_b + (long)(l * 3 + 0) * HID;
        const float* ls1 = ln_s + (long)(l * 3 + 1) * HID; const float* lb1 = ln_b + (long)(l * 3 + 1) * HID;
        const float* ls2 = ln_s + (long)(l * 3 + 2) * HID; const float* lb2 = ln_b + (long)(l * 3 + 2) * HID;

        k_mgemm<0, false, false><<<dim3(HID / 64, M / 64), 256, 0, stream>>>(
            h, gWt, gB, nullptr, tmp1, M, HID, HID, 0);
        k_gcn_ln<<<B_ * N_, 128, 0, stream>>>(h, tmp1, knn, ls0, lb0, hlocal);
        k_mgemm<1, false, false><<<dim3(HID / 64, M / 64), 256, 0, stream>>>(
            h, wqT, bql, nullptr, qbf, M, HID, HID, 0);
        k_mgemm<1, false, false><<<dim3(HID / 64, M / 64), 256, 0, stream>>>(
            h, wkT, bkl, nullptr, kbf, M, HID, HID, 0);
        k_mgemm<2, false, false><<<dim3(HID / 64, M / 64), 256, 0, stream>>>(
            h, wvT, bvl, nullptr, vbT, M, HID, HID, (long)M);
        k_attn<<<dim3(N_ / 16, NHEADS, B_), 256, 0, stream>>>(qbf, kbf, vbT, tmp1);
        k_mgemm<0, false, false><<<dim3(HID / 64, M / 64), 256, 0, stream>>>(
            tmp1, woT, bol, nullptr, proj, M, HID, HID, 0);
        k_addln<<<B_ * N_, 128, 0, stream>>>(h, proj, hlocal, ls1, lb1, outb);
        k_mgemm<1, true, false><<<dim3(2 * HID / 64, M / 64), 256, 0, stream>>>(
            outb, w1Tl, b1l, nullptr, tb, M, 2 * HID, HID, 0);
        k_mgemm<0, false, true><<<dim3(HID / 64, M / 64), 256, 0, stream>>>(
            tb, w2Tl, b2l, outb, tmp1, M, HID, 2 * HID, 0);
        k_addln<<<B_ * N_, 128, 0, stream>>>(tmp1, nullptr, nullptr, ls2, lb2, h);
    }

    // two-stage mean pool (partial -> tmp1 region, dead here)
    k_pool1<<<dim3(32, B_), 384, 0, stream>>>(h, partial);
    k_pool2<<<B_, 384, 0, stream>>>(partial, pooled);
    k_head<<<B_, HID, 0, stream>>>(pooled, lin1_W, lin1_b, lin2_W, lin2_b,
                                   (float*)d_out);
}

// Round 7
// 1057.371 us; speedup vs baseline: 3.3382x; 1.0538x over previous
//
#include <hip/hip_runtime.h>
#include <hip/hip_bf16.h>

#define B_    8
#define C_    64
#define N_    1024
#define HID   384
#define OUTD  128
#define L_    3
#define KNN   16
#define NHEADS 3
#define DH    128

typedef __attribute__((ext_vector_type(8))) short    s16x8;   // MFMA A/B frag: 8 bf16
typedef __attribute__((ext_vector_type(4))) float    f32x4;   // MFMA C/D frag
typedef __attribute__((ext_vector_type(8))) unsigned short u16x8;
typedef __attribute__((ext_vector_type(4))) unsigned short u16x4;

// RNE f32 -> bf16 (finite inputs)
__device__ __forceinline__ ushort f2b(float f) {
    uint x = __float_as_uint(f);
    return (ushort)((x + 0x7fff + ((x >> 16) & 1)) >> 16);
}
__device__ __forceinline__ float b2f(uint u) {
    return __uint_as_float(u << 16);
}

// ---------------------------------------------------------------- encode (f32)
__global__ void k_encode(const float* __restrict__ x, const float* __restrict__ Wenc,
                         const float* __restrict__ benc, float* __restrict__ h) {
    int bn = blockIdx.x;
    int b = bn >> 10;
    const float* xb = x + (long)b * C_ * N_ + (bn & 1023);
    for (int c0 = threadIdx.x; c0 < HID; c0 += blockDim.x) {
        float acc = benc[c0];
        for (int c = 0; c < C_; ++c)
            acc += xb[c * N_] * Wenc[c * HID + c0];
        h[(long)bn * HID + c0] = acc;
    }
}

// ---------------------------------------------------------------- row normalize (f32)
__global__ void k_normalize(const float* __restrict__ h, float* __restrict__ nh) {
    int bn = blockIdx.x;
    __shared__ float red[128];
    int tid = threadIdx.x;
    float ss = 0.f;
    for (int c = tid; c < HID; c += 128) { float v = h[(long)bn*HID+c]; ss += v*v; }
    red[tid] = ss; __syncthreads();
    for (int s = 64; s > 0; s >>= 1) { if (tid < s) red[tid] += red[tid+s]; __syncthreads(); }
    float inv = 1.0f / sqrtf(red[0]);
    for (int c = tid; c < HID; c += 128) nh[(long)bn*HID+c] = h[(long)bn*HID+c] * inv;
}

// ---------------------------------------------------------------- f32 GEMM (sim only, NT)
template<bool BT, bool RELU>
__global__ __launch_bounds__(256) void k_gemm(
        const float* __restrict__ A, const float* __restrict__ Bm,
        const float* __restrict__ bias, const float* __restrict__ resid,
        float* __restrict__ C, int M, int N, int K,
        long strideA, long strideB, long strideC) {
    __shared__ float As[16][68];
    __shared__ float Bs[16][68];
    int bz = blockIdx.z;
    A  += (long)bz * strideA;
    Bm += (long)bz * strideB;
    C  += (long)bz * strideC;
    int bm = blockIdx.y * 64, bn = blockIdx.x * 64;
    int tid = threadIdx.x;
    int ty = tid >> 4, tx = tid & 15;
    int lm = tid >> 2, lq = tid & 3;
    float acc[4][4] = {};
    for (int k0 = 0; k0 < K; k0 += 16) {
        {
            float4 av = *(const float4*)&A[(long)(bm + lm) * K + k0 + lq * 4];
            As[lq*4+0][lm] = av.x; As[lq*4+1][lm] = av.y;
            As[lq*4+2][lm] = av.z; As[lq*4+3][lm] = av.w;
        }
        if (BT) {
            float4 bv = *(const float4*)&Bm[(long)(bn + lm) * K + k0 + lq * 4];
            Bs[lq*4+0][lm] = bv.x; Bs[lq*4+1][lm] = bv.y;
            Bs[lq*4+2][lm] = bv.z; Bs[lq*4+3][lm] = bv.w;
        } else {
            int kk = tid >> 4, nq = tid & 15;
            float4 bv = *(const float4*)&Bm[(long)(k0 + kk) * N + bn + nq * 4];
            Bs[kk][nq*4+0] = bv.x; Bs[kk][nq*4+1] = bv.y;
            Bs[kk][nq*4+2] = bv.z; Bs[kk][nq*4+3] = bv.w;
        }
        __syncthreads();
        #pragma unroll
        for (int kk = 0; kk < 16; ++kk) {
            float4 a = *(const float4*)&As[kk][ty * 4];
            float4 b = *(const float4*)&Bs[kk][tx * 4];
            acc[0][0] += a.x*b.x; acc[0][1] += a.x*b.y; acc[0][2] += a.x*b.z; acc[0][3] += a.x*b.w;
            acc[1][0] += a.y*b.x; acc[1][1] += a.y*b.y; acc[1][2] += a.y*b.z; acc[1][3] += a.y*b.w;
            acc[2][0] += a.z*b.x; acc[2][1] += a.z*b.y; acc[2][2] += a.z*b.z; acc[2][3] += a.z*b.w;
            acc[3][0] += a.w*b.x; acc[3][1] += a.w*b.y; acc[3][2] += a.w*b.z; acc[3][3] += a.w*b.w;
        }
        __syncthreads();
    }
    #pragma unroll
    for (int i = 0; i < 4; ++i) {
        int row = bm + ty * 4 + i;
        #pragma unroll
        for (int j = 0; j < 4; ++j) {
            int col = bn + tx * 4 + j;
            float c = acc[i][j];
            if (bias)  c += bias[col];
            if (resid) c += resid[(long)row * N + col];
            if (RELU)  c = fmaxf(c, 0.f);
            C[(long)row * N + col] = c;
        }
    }
}

// ---------------------------------------------------------------- top-k (k=16), register+shfl
__global__ __launch_bounds__(256) void k_topk(const float* __restrict__ sim, int* __restrict__ knn) {
    int bn = blockIdx.x; int b = bn >> 10, n = bn & 1023;
    const float* row = sim + (long)b * N_ * N_ + (long)n * N_;
    int tid = threadIdx.x;
    float v[4];
    #pragma unroll
    for (int j = 0; j < 4; ++j) {
        int m = tid + j * 256;
        v[j] = row[m] - (m == n ? 2.0f : 0.0f);
    }
    __shared__ float wv[4];
    __shared__ int   wi[4];
    int wave = tid >> 6;
    for (int it = 0; it < KNN; ++it) {
        // local best among 4 (ascending m, strict > keeps lowest index on ties)
        float bv = v[0]; int bi = tid;
        #pragma unroll
        for (int j = 1; j < 4; ++j) {
            int m = tid + j * 256;
            if (v[j] > bv) { bv = v[j]; bi = m; }
        }
        // 64-lane butterfly, tie-break lower index
        #pragma unroll
        for (int mask = 1; mask < 64; mask <<= 1) {
            float ov = __shfl_xor(bv, mask);
            int   oi = __shfl_xor(bi, mask);
            if (ov > bv || (ov == bv && oi < bi)) { bv = ov; bi = oi; }
        }
        if ((tid & 63) == 0) { wv[wave] = bv; wi[wave] = bi; }
        __syncthreads();
        float fv = wv[0]; int fi = wi[0];
        #pragma unroll
        for (int q = 1; q < 4; ++q)
            if (wv[q] > fv || (wv[q] == fv && wi[q] < fi)) { fv = wv[q]; fi = wi[q]; }
        if (tid == 0) knn[(long)bn * KNN + it] = fi;
        if ((fi & 255) == tid) v[fi >> 8] = -1e30f;
        __syncthreads();
    }
}

// ---------------------------------------------------------------- weight cast+transpose
__global__ void k_cast15(const float* __restrict__ g, const float* __restrict__ q,
                         const float* __restrict__ k, const float* __restrict__ v,
                         const float* __restrict__ o, ushort* __restrict__ out) {
    int z = blockIdx.z; int type = z / 3, l = z % 3;
    const float* in = (type == 0 ? g : type == 1 ? q : type == 2 ? k : type == 3 ? v : o)
                      + (long)l * HID * HID;
    ushort* op = out + (long)z * HID * HID;
    __shared__ float t[32][33];
    int c0 = blockIdx.x * 32, r0 = blockIdx.y * 32;
    int tid = threadIdx.x; int i = tid & 31, j4 = tid >> 5;
    #pragma unroll
    for (int rr = 0; rr < 4; ++rr) {
        int r = j4 * 4 + rr;
        t[r][i] = in[(long)(r0 + r) * HID + c0 + i];
    }
    __syncthreads();
    #pragma unroll
    for (int rr = 0; rr < 4; ++rr) {
        int c = j4 * 4 + rr;
        op[(long)(c0 + c) * HID + r0 + i] = f2b(t[i][c]);
    }
}

__global__ void k_castT(const float* __restrict__ in_, ushort* __restrict__ out_,
                        int R, int C) {
    long mz = (long)blockIdx.z * R * C;
    const float* in = in_ + mz;
    ushort* op = out_ + mz;
    __shared__ float t[32][33];
    int c0 = blockIdx.x * 32, r0 = blockIdx.y * 32;
    int tid = threadIdx.x; int i = tid & 31, j4 = tid >> 5;
    #pragma unroll
    for (int rr = 0; rr < 4; ++rr) {
        int r = j4 * 4 + rr;
        t[r][i] = in[(long)(r0 + r) * C + c0 + i];
    }
    __syncthreads();
    #pragma unroll
    for (int rr = 0; rr < 4; ++rr) {
        int c = j4 * 4 + rr;
        op[(long)(c0 + c) * R + r0 + i] = f2b(t[i][c]);
    }
}

// flat f32 -> bf16 (8 elems/thread)
__global__ __launch_bounds__(256) void k_castb(const float* __restrict__ in,
                                               ushort* __restrict__ out) {
    long i0 = ((long)blockIdx.x * 256 + threadIdx.x) * 8;
    float4 a0 = *(const float4*)&in[i0];
    float4 a1 = *(const float4*)&in[i0 + 4];
    u16x8 v;
    v[0]=f2b(a0.x); v[1]=f2b(a0.y); v[2]=f2b(a0.z); v[3]=f2b(a0.w);
    v[4]=f2b(a1.x); v[5]=f2b(a1.y); v[6]=f2b(a1.z); v[7]=f2b(a1.w);
    *(u16x8*)&out[i0] = v;
}

// ---------------------------------------------------------------- MFMA GEMM v2 (128x128 tile)
// C[M,N] = A[M,K](bf16) @ Wt[N,K]^T(bf16) + bias (+resid) (+relu)
// OUTMODE: 0 = f32 [M][N], 1 = bf16 [M][N], 2 = bf16 transposed [N][ldcT]
// 4 waves; wave (wm=w>>1, wn=w&1) owns 64x64 quadrant: 4x4 16x16 frags.
template<int OUTMODE, bool RELU>
__global__ __launch_bounds__(256) void k_mgemm(
        const ushort* __restrict__ A, const ushort* __restrict__ Wt,
        const float* __restrict__ bias, const float* __restrict__ resid,
        void* __restrict__ Cout, int M, int N, int K, long ldcT) {
    __shared__ ushort Al[128][40];   // row stride 80B
    __shared__ ushort Bl[128][40];
    int bm = blockIdx.y * 128, bnn = blockIdx.x * 128;
    int tid = threadIdx.x;
    int w = tid >> 6, l = tid & 63;
    int wm = w >> 1, wn = w & 1;
    int sr = tid >> 2, skq = (tid & 3) * 8;     // staging: rows sr, sr+64; k-chunk skq
    f32x4 acc[4][4] = {};
    for (int k0 = 0; k0 < K; k0 += 32) {
        *(u16x8*)&Al[sr][skq]      = *(const u16x8*)&A [(long)(bm + sr) * K + k0 + skq];
        *(u16x8*)&Al[sr + 64][skq] = *(const u16x8*)&A [(long)(bm + sr + 64) * K + k0 + skq];
        *(u16x8*)&Bl[sr][skq]      = *(const u16x8*)&Wt[(long)(bnn + sr) * K + k0 + skq];
        *(u16x8*)&Bl[sr + 64][skq] = *(const u16x8*)&Wt[(long)(bnn + sr + 64) * K + k0 + skq];
        __syncthreads();
        s16x8 af[4], bf[4];
        #pragma unroll
        for (int mi = 0; mi < 4; ++mi)
            af[mi] = *(const s16x8*)&Al[wm * 64 + mi * 16 + (l & 15)][(l >> 4) * 8];
        #pragma unroll
        for (int ni = 0; ni < 4; ++ni)
            bf[ni] = *(const s16x8*)&Bl[wn * 64 + ni * 16 + (l & 15)][(l >> 4) * 8];
        #pragma unroll
        for (int mi = 0; mi < 4; ++mi)
            #pragma unroll
            for (int ni = 0; ni < 4; ++ni)
                acc[mi][ni] = __builtin_amdgcn_mfma_f32_16x16x32_bf16(af[mi], bf[ni], acc[mi][ni], 0, 0, 0);
        __syncthreads();
    }
    // epilogue
    #pragma unroll
    for (int mi = 0; mi < 4; ++mi) {
        int row0 = bm + wm * 64 + mi * 16 + (l >> 4) * 4;
        #pragma unroll
        for (int ni = 0; ni < 4; ++ni) {
            int coln = bnn + wn * 64 + ni * 16 + (l & 15);
            float bv = bias[coln];
            if (OUTMODE == 2) {
                u16x4 pk;
                #pragma unroll
                for (int reg = 0; reg < 4; ++reg)
                    pk[reg] = f2b(acc[mi][ni][reg] + bv);
                *(u16x4*)((ushort*)Cout + (long)coln * ldcT + row0) = pk;
            } else {
                #pragma unroll
                for (int reg = 0; reg < 4; ++reg) {
                    int rowg = row0 + reg;
                    float v = acc[mi][ni][reg] + bv;
                    if (resid) v += resid[(long)rowg * N + coln];
                    if (RELU)  v = fmaxf(v, 0.f);
                    if (OUTMODE == 0) ((float*)Cout)[(long)rowg * N + coln] = v;
                    else              ((ushort*)Cout)[(long)rowg * N + coln] = f2b(v);
                }
            }
        }
    }
}

// ---------------------------------------------------------------- GCN gather + residual + LN (f32)
__global__ void k_gcn_ln(const float* __restrict__ h, const float* __restrict__ xw,
                         const int* __restrict__ knn,
                         const float* __restrict__ lns, const float* __restrict__ lnb,
                         float* __restrict__ hlocal) {
    int bn = blockIdx.x; int b = bn >> 10;
    __shared__ int nb[KNN];
    __shared__ float red[128];
    int tid = threadIdx.x;
    if (tid < KNN) nb[tid] = knn[(long)bn * KNN + tid];
    __syncthreads();
    float val[3]; float sum = 0.f, ssq = 0.f;
    #pragma unroll
    for (int i = 0; i < 3; ++i) {
        int c = tid + i * 128;
        float acc = xw[(long)bn * HID + c];
        #pragma unroll
        for (int j = 0; j < KNN; ++j)
            acc += xw[((long)(b << 10) + nb[j]) * HID + c];
        float v = h[(long)bn * HID + c] + acc * (1.0f / 17.0f);
        val[i] = v; sum += v; ssq += v * v;
    }
    red[tid] = sum; __syncthreads();
    for (int s = 64; s > 0; s >>= 1) { if (tid < s) red[tid] += red[tid+s]; __syncthreads(); }
    sum = red[0]; __syncthreads();
    red[tid] = ssq; __syncthreads();
    for (int s = 64; s > 0; s >>= 1) { if (tid < s) red[tid] += red[tid+s]; __syncthreads(); }
    ssq = red[0];
    float mu = sum / HID;
    float var = ssq / HID - mu * mu;
    float inv = rsqrtf(var + 1e-5f);
    #pragma unroll
    for (int i = 0; i < 3; ++i) {
        int c = tid + i * 128;
        hlocal[(long)bn * HID + c] = (val[i] - mu) * inv * lns[c] + lnb[c];
    }
}

// ---------------------------------------------------------------- (a[+badd]) -> LN -> (+post), + bf16 mirror
__global__ void k_addln(const float* __restrict__ a, const float* __restrict__ badd,
                        const float* __restrict__ post,
                        const float* __restrict__ lns, const float* __restrict__ lnb,
                        float* __restrict__ outp, ushort* __restrict__ bfout) {
    int bn = blockIdx.x;
    __shared__ float red[128];
    int tid = threadIdx.x;
    float val[3]; float sum = 0.f, ssq = 0.f;
    #pragma unroll
    for (int i = 0; i < 3; ++i) {
        int c = tid + i * 128;
        float v = a[(long)bn * HID + c];
        if (badd) v += badd[(long)bn * HID + c];
        val[i] = v; sum += v; ssq += v * v;
    }
    red[tid] = sum; __syncthreads();
    for (int s = 64; s > 0; s >>= 1) { if (tid < s) red[tid] += red[tid+s]; __syncthreads(); }
    sum = red[0]; __syncthreads();
    red[tid] = ssq; __syncthreads();
    for (int s = 64; s > 0; s >>= 1) { if (tid < s) red[tid] += red[tid+s]; __syncthreads(); }
    ssq = red[0];
    float mu = sum / HID;
    float var = ssq / HID - mu * mu;
    float inv = rsqrtf(var + 1e-5f);
    #pragma unroll
    for (int i = 0; i < 3; ++i) {
        int c = tid + i * 128;
        float o = (val[i] - mu) * inv * lns[c] + lnb[c];
        if (post) o += post[(long)bn * HID + c];
        outp[(long)bn * HID + c] = o;
        if (bfout) bfout[(long)bn * HID + c] = f2b(o);
    }
}

// ---------------------------------------------------------------- MFMA attention (bf16 out)
__global__ __launch_bounds__(256) void k_attn(const ushort* __restrict__ qb,
                                              const ushort* __restrict__ kb,
                                              const ushort* __restrict__ vt,
                                              ushort* __restrict__ o) {
    int b = blockIdx.z, hh = blockIdx.y, r0 = blockIdx.x * 16;
    __shared__ ushort sc[16][1032];     // bf16 scores/probs; stride 2064B
    __shared__ ushort kvt[9216];        // union: Kt[64][136] | VtT[128][72]
    __shared__ float rowinv[16];
    int tid = threadIdx.x;
    int w = tid >> 6, l = tid & 63;
    s16x8 aq[4];
    const ushort* qrow = qb + ((long)(b * N_) + r0 + (l & 15)) * HID + hh * DH + (l >> 4) * 8;
    #pragma unroll
    for (int ks = 0; ks < 4; ++ks) aq[ks] = *(const s16x8*)(qrow + ks * 32);
    const float scale = 0.08838834764831845f;   // 1/sqrt(128)
    // ---------- S = Q K^T
    for (int m0 = 0; m0 < N_; m0 += 64) {
        {
            int key = tid >> 2, seg = tid & 3;
            const ushort* src = kb + ((long)(b * N_) + m0 + key) * HID + hh * DH + seg * 32;
            ushort* dst = &kvt[key * 136 + seg * 32];
            #pragma unroll
            for (int i = 0; i < 4; ++i)
                *(u16x8*)(dst + i * 8) = *(const u16x8*)(src + i * 8);
        }
        __syncthreads();
        f32x4 acc = {0.f, 0.f, 0.f, 0.f};
        #pragma unroll
        for (int ks = 0; ks < 4; ++ks) {
            s16x8 bk = *(const s16x8*)&kvt[(w * 16 + (l & 15)) * 136 + ks * 32 + (l >> 4) * 8];
            acc = __builtin_amdgcn_mfma_f32_16x16x32_bf16(aq[ks], bk, acc, 0, 0, 0);
        }
        int key = m0 + w * 16 + (l & 15);
        #pragma unroll
        for (int reg = 0; reg < 4; ++reg)
            sc[(l >> 4) * 4 + reg][key] = f2b(acc[reg] * scale);
        __syncthreads();
    }
    // ---------- softmax
    {
        int g = tid >> 5, l2 = tid & 31;
        #pragma unroll
        for (int rr = 0; rr < 2; ++rr) {
            int row = g + rr * 8;
            float v[32];
            #pragma unroll
            for (int i = 0; i < 16; ++i) {
                uint u = *(const uint*)&sc[row][l2 * 2 + i * 64];
                v[2*i]   = b2f(u & 0xffffu);
                v[2*i+1] = b2f(u >> 16);
            }
            float mx = v[0];
            #pragma unroll
            for (int i = 1; i < 32; ++i) mx = fmaxf(mx, v[i]);
            #pragma unroll
            for (int m = 16; m >= 1; m >>= 1) mx = fmaxf(mx, __shfl_xor(mx, m));
            float sm = 0.f;
            #pragma unroll
            for (int i = 0; i < 16; ++i) {
                float e0 = __expf(v[2*i]   - mx);
                float e1 = __expf(v[2*i+1] - mx);
                sm += e0 + e1;
                *(uint*)&sc[row][l2 * 2 + i * 64] = (uint)f2b(e0) | ((uint)f2b(e1) << 16);
            }
            #pragma unroll
            for (int m = 16; m >= 1; m >>= 1) sm += __shfl_xor(sm, m);
            if (l2 == 0) rowinv[row] = 1.0f / sm;
        }
    }
    __syncthreads();
    // ---------- O = P V
    f32x4 zero = {0.f, 0.f, 0.f, 0.f};
    f32x4 oacc[2] = {zero, zero};
    for (int m0 = 0; m0 < N_; m0 += 64) {
        {
            int dim = tid >> 1, half = tid & 1;
            const ushort* src = vt + ((long)(hh * DH + dim)) * (B_ * N_) + b * N_ + m0 + half * 32;
            ushort* dst = &kvt[dim * 72 + half * 32];
            #pragma unroll
            for (int i = 0; i < 4; ++i)
                *(u16x8*)(dst + i * 8) = *(const u16x8*)(src + i * 8);
        }
        __syncthreads();
        #pragma unroll
        for (int ks = 0; ks < 2; ++ks) {
            s16x8 pf = *(const s16x8*)&sc[l & 15][m0 + ks * 32 + (l >> 4) * 8];
            #pragma unroll
            for (int d = 0; d < 2; ++d) {
                s16x8 vf = *(const s16x8*)&kvt[((w * 2 + d) * 16 + (l & 15)) * 72 + ks * 32 + (l >> 4) * 8];
                oacc[d] = __builtin_amdgcn_mfma_f32_16x16x32_bf16(pf, vf, oacc[d], 0, 0, 0);
            }
        }
        __syncthreads();
    }
    #pragma unroll
    for (int d = 0; d < 2; ++d) {
        int dim = (w * 2 + d) * 16 + (l & 15);
        #pragma unroll
        for (int reg = 0; reg < 4; ++reg) {
            int row = (l >> 4) * 4 + reg;
            o[((long)(b * N_) + r0 + row) * HID + hh * DH + dim] = f2b(oacc[d][reg] * rowinv[row]);
        }
    }
}

// ---------------------------------------------------------------- mean pool, two-stage
__global__ __launch_bounds__(384) void k_pool1(const float* __restrict__ h,
                                               float* __restrict__ partial) {
    int s = blockIdx.x, b = blockIdx.y;
    int c = threadIdx.x;
    const float* hp = h + ((long)(b * N_) + s * 32) * HID + c;
    float acc = 0.f;
    #pragma unroll
    for (int n = 0; n < 32; ++n) acc += hp[(long)n * HID];
    partial[((long)(b * 32) + s) * HID + c] = acc;
}
__global__ __launch_bounds__(384) void k_pool2(const float* __restrict__ partial,
                                               float* __restrict__ pooled) {
    int b = blockIdx.x;
    int c = threadIdx.x;
    const float* pp = partial + (long)(b * 32) * HID + c;
    float acc = 0.f;
    #pragma unroll
    for (int s = 0; s < 32; ++s) acc += pp[(long)s * HID];
    pooled[b * HID + c] = acc * (1.0f / N_);
}

// ---------------------------------------------------------------- head (f32)
__global__ void k_head(const float* __restrict__ pooled,
                       const float* __restrict__ w1, const float* __restrict__ b1,
                       const float* __restrict__ w2, const float* __restrict__ b2,
                       float* __restrict__ out) {
    int b = blockIdx.x; int tid = threadIdx.x;   // 384 threads
    __shared__ float z[HID];
    float acc = b1[tid];
    for (int c = 0; c < HID; ++c) acc += pooled[b * HID + c] * w1[c * HID + tid];
    z[tid] = fmaxf(acc, 0.f);
    __syncthreads();
    if (tid < OUTD) {
        float a2 = b2[tid];
        for (int j = 0; j < HID; ++j) a2 += z[j] * w2[j * OUTD + tid];
        out[b * OUTD + tid] = a2;
    }
}

// ================================================================ launch
extern "C" void kernel_launch(void* const* d_in, const int* in_sizes, int n_in,
                              void* d_out, int out_size, void* d_ws, size_t ws_size,
                              hipStream_t stream) {
    const float* x       = (const float*)d_in[0];
    const float* W_enc   = (const float*)d_in[1];
    const float* b_enc   = (const float*)d_in[2];
    const float* gcn_W   = (const float*)d_in[3];
    const float* gcn_b   = (const float*)d_in[4];
    const float* Wq      = (const float*)d_in[5];
    const float* bq      = (const float*)d_in[6];
    const float* Wk      = (const float*)d_in[7];
    const float* bk      = (const float*)d_in[8];
    const float* Wv      = (const float*)d_in[9];
    const float* bv      = (const float*)d_in[10];
    const float* Wo      = (const float*)d_in[11];
    const float* bo      = (const float*)d_in[12];
    const float* ln_s    = (const float*)d_in[13];
    const float* ln_b    = (const float*)d_in[14];
    const float* mlp_W1  = (const float*)d_in[15];
    const float* mlp_b1  = (const float*)d_in[16];
    const float* mlp_W2  = (const float*)d_in[17];
    const float* mlp_b2  = (const float*)d_in[18];
    const float* lin1_W  = (const float*)d_in[19];
    const float* lin1_b  = (const float*)d_in[20];
    const float* lin2_W  = (const float*)d_in[21];
    const float* lin2_b  = (const float*)d_in[22];

    const long S = (long)B_ * N_ * HID;            // 3,145,728
    char* base = (char*)d_ws;
    float* h      = (float*)(base);
    float* tmp1   = (float*)(base + (size_t)S * 4);       // xw / attn-out(bf16) / u / pool-partial
    float* hlocal = (float*)(base + (size_t)S * 8);
    float* outb   = (float*)(base + (size_t)S * 12);
    char*  tzone  = base + (size_t)S * 16;                // 8S-byte multi-use region
    float* proj   = (float*)(base + (size_t)S * 24);
    float*  sim = (float*)tzone;                          // phase-1 (spills into proj)
    ushort* qbf = (ushort*)tzone;                         // [0,2S)
    ushort* kbf = (ushort*)(tzone + (size_t)S * 2);       // [2S,4S)
    ushort* vbT = (ushort*)(tzone + (size_t)S * 4);       // [4S,6S)
    ushort* outb_bf = (ushort*)(tzone + (size_t)S * 6);   // [6S,8S) - free all layer
    ushort* tb  = (ushort*)tzone;                         // [0,4S) after attn
    int*    knn    = (int*)(base + (size_t)S * 28);
    float*  pooled = (float*)(base + (size_t)S * 28 + 524288);
    ushort* wts    = (ushort*)(base + (size_t)S * 28 + 524288 + 16384);
    const long SQ = (long)HID * HID;
    ushort* w1T = wts + 15 * SQ;
    ushort* w2T = w1T + 3 * (long)HID * 2 * HID;
    ushort* hb  = (ushort*)(base + (size_t)S * 28 + 524288 + 16384 + 7962624);
    float* partial = tmp1;
    ushort* obf = (ushort*)tmp1;                          // attn bf16 out (tmp1 dead)

    // ---- weight cast+transpose (bf16 [N][K])
    k_cast15<<<dim3(12, 12, 15), 256, 0, stream>>>(gcn_W, Wq, Wk, Wv, Wo, wts);
    k_castT<<<dim3(24, 12, 3), 256, 0, stream>>>(mlp_W1, w1T, HID, 2 * HID);
    k_castT<<<dim3(12, 24, 3), 256, 0, stream>>>(mlp_W2, w2T, 2 * HID, HID);

    // ---- encode + normalize + sim (f32 exact) + topk
    k_encode<<<B_ * N_, 128, 0, stream>>>(x, W_enc, b_enc, h);
    k_normalize<<<B_ * N_, 128, 0, stream>>>(h, tmp1);
    k_gemm<true, false><<<dim3(16, 16, B_), 256, 0, stream>>>(
        tmp1, tmp1, nullptr, nullptr, sim, N_, N_, HID,
        (long)N_ * HID, (long)N_ * HID, (long)N_ * N_);
    k_topk<<<B_ * N_, 256, 0, stream>>>(sim, knn);
    k_castb<<<(int)(S / 2048), 256, 0, stream>>>(h, hb);   // h -> bf16 mirror

    const int M = B_ * N_;   // 8192
    for (int l = 0; l < L_; ++l) {
        const ushort* gWt = wts + (long)(0 + l) * SQ;
        const ushort* wqT = wts + (long)(3 + l) * SQ;
        const ushort* wkT = wts + (long)(6 + l) * SQ;
        const ushort* wvT = wts + (long)(9 + l) * SQ;
        const ushort* woT = wts + (long)(12 + l) * SQ;
        const ushort* w1Tl = w1T + (long)l * HID * 2 * HID;
        const ushort* w2Tl = w2T + (long)l * HID * 2 * HID;
        const float* gB  = gcn_b + (long)l * HID;
        const float* bql = bq + (long)l * HID;
        const float* bkl = bk + (long)l * HID;
        const float* bvl = bv + (long)l * HID;
        const float* bol = bo + (long)l * HID;
        const float* b1l = mlp_b1 + (long)l * 2 * HID;
        const float* b2l = mlp_b2 + (long)l * HID;
        const float* ls0 = ln_s + (long)(l * 3 + 0) * HID; const float* lb0 = ln_b + (long)(l * 3 + 0) * HID;
        const float* ls1 = ln_s + (long)(l * 3 + 1) * HID; const float* lb1 = ln_b + (long)(l * 3 + 1) * HID;
        const float* ls2 = ln_s + (long)(l * 3 + 2) * HID; const float* lb2 = ln_b + (long)(l * 3 + 2) * HID;

        // xw = h @ gcn_W + gcn_b  (f32)
        k_mgemm<0, false><<<dim3(HID / 128, M / 128), 256, 0, stream>>>(
            hb, gWt, gB, nullptr, tmp1, M, HID, HID, 0);
        k_gcn_ln<<<B_ * N_, 128, 0, stream>>>(h, tmp1, knn, ls0, lb0, hlocal);
        // q, k (bf16), v (bf16 transposed)
        k_mgemm<1, false><<<dim3(HID / 128, M / 128), 256, 0, stream>>>(
            hb, wqT, bql, nullptr, qbf, M, HID, HID, 0);
        k_mgemm<1, false><<<dim3(HID / 128, M / 128), 256, 0, stream>>>(
            hb, wkT, bkl, nullptr, kbf, M, HID, HID, 0);
        k_mgemm<2, false><<<dim3(HID / 128, M / 128), 256, 0, stream>>>(
            hb, wvT, bvl, nullptr, vbT, M, HID, HID, (long)M);
        // attention -> obf (bf16)
        k_attn<<<dim3(N_ / 16, NHEADS, B_), 256, 0, stream>>>(qbf, kbf, vbT, obf);
        // proj = o @ Wo + bo (f32)
        k_mgemm<0, false><<<dim3(HID / 128, M / 128), 256, 0, stream>>>(
            obf, woT, bol, nullptr, proj, M, HID, HID, 0);
        // out = hlocal + LN(h + proj) -> outb (+bf16 mirror)
        k_addln<<<B_ * N_, 128, 0, stream>>>(h, proj, hlocal, ls1, lb1, outb, outb_bf);
        // t = relu(out @ W1 + b1) -> bf16 tb
        k_mgemm<1, true><<<dim3(2 * HID / 128, M / 128), 256, 0, stream>>>(
            outb_bf, w1Tl, b1l, nullptr, tb, M, 2 * HID, HID, 0);
        // u = out + t @ W2 + b2 -> tmp1 (f32)
        k_mgemm<0, false><<<dim3(HID / 128, M / 128), 256, 0, stream>>>(
            tb, w2Tl, b2l, outb, tmp1, M, HID, 2 * HID, 0);
        // h = LN(u) (+hb mirror)
        k_addln<<<B_ * N_, 128, 0, stream>>>(tmp1, nullptr, nullptr, ls2, lb2, h, hb);
    }

    k_pool1<<<dim3(32, B_), 384, 0, stream>>>(h, partial);
    k_pool2<<<B_, 384, 0, stream>>>(partial, pooled);
    k_head<<<B_, HID, 0, stream>>>(pooled, lin1_W, lin1_b, lin2_W, lin2_b,
                                   (float*)d_out);
}

// Round 9
// 996.811 us; speedup vs baseline: 3.5410x; 1.0608x over previous
//
#include <hip/hip_runtime.h>
#include <hip/hip_bf16.h>

#define B_    8
#define C_    64
#define N_    1024
#define HID   384
#define OUTD  128
#define L_    3
#define KNN   16
#define NHEADS 3
#define DH    128

typedef __attribute__((ext_vector_type(8))) short    s16x8;   // MFMA A/B frag: 8 bf16
typedef __attribute__((ext_vector_type(4))) float    f32x4;   // MFMA C/D frag
typedef __attribute__((ext_vector_type(8))) unsigned short u16x8;
typedef __attribute__((ext_vector_type(4))) unsigned short u16x4;

// RNE f32 -> bf16 (finite inputs)
__device__ __forceinline__ ushort f2b(float f) {
    uint x = __float_as_uint(f);
    return (ushort)((x + 0x7fff + ((x >> 16) & 1)) >> 16);
}
__device__ __forceinline__ float b2f(uint u) {
    return __uint_as_float(u << 16);
}

// ---------------------------------------------------------------- encode + row-normalize (fused, f32)
// h[b,n,:] = x[b,:,n] @ W_enc + b_enc ;  nh = h / ||h||
__global__ void k_encode(const float* __restrict__ x, const float* __restrict__ Wenc,
                         const float* __restrict__ benc, float* __restrict__ h,
                         float* __restrict__ nh) {
    int bn = blockIdx.x;
    int b = bn >> 10;
    const float* xb = x + (long)b * C_ * N_ + (bn & 1023);
    int tid = threadIdx.x;
    __shared__ float red[128];
    float val[3];
    #pragma unroll
    for (int i = 0; i < 3; ++i) {
        int c0 = tid + i * 128;
        float acc = benc[c0];
        for (int c = 0; c < C_; ++c)
            acc += xb[c * N_] * Wenc[c * HID + c0];
        h[(long)bn * HID + c0] = acc;
        val[i] = acc;
    }
    float ss = 0.f;
    #pragma unroll
    for (int i = 0; i < 3; ++i) ss += val[i] * val[i];
    red[tid] = ss; __syncthreads();
    for (int s = 64; s > 0; s >>= 1) { if (tid < s) red[tid] += red[tid+s]; __syncthreads(); }
    float inv = 1.0f / sqrtf(red[0]);
    #pragma unroll
    for (int i = 0; i < 3; ++i)
        nh[(long)bn * HID + tid + i * 128] = val[i] * inv;
}

// ---------------------------------------------------------------- f32 GEMM (sim only, NT)
template<bool BT, bool RELU>
__global__ __launch_bounds__(256) void k_gemm(
        const float* __restrict__ A, const float* __restrict__ Bm,
        const float* __restrict__ bias, const float* __restrict__ resid,
        float* __restrict__ C, int M, int N, int K,
        long strideA, long strideB, long strideC) {
    __shared__ float As[16][68];
    __shared__ float Bs[16][68];
    int bz = blockIdx.z;
    A  += (long)bz * strideA;
    Bm += (long)bz * strideB;
    C  += (long)bz * strideC;
    int bm = blockIdx.y * 64, bn = blockIdx.x * 64;
    int tid = threadIdx.x;
    int ty = tid >> 4, tx = tid & 15;
    int lm = tid >> 2, lq = tid & 3;
    float acc[4][4] = {};
    for (int k0 = 0; k0 < K; k0 += 16) {
        {
            float4 av = *(const float4*)&A[(long)(bm + lm) * K + k0 + lq * 4];
            As[lq*4+0][lm] = av.x; As[lq*4+1][lm] = av.y;
            As[lq*4+2][lm] = av.z; As[lq*4+3][lm] = av.w;
        }
        if (BT) {
            float4 bv = *(const float4*)&Bm[(long)(bn + lm) * K + k0 + lq * 4];
            Bs[lq*4+0][lm] = bv.x; Bs[lq*4+1][lm] = bv.y;
            Bs[lq*4+2][lm] = bv.z; Bs[lq*4+3][lm] = bv.w;
        } else {
            int kk = tid >> 4, nq = tid & 15;
            float4 bv = *(const float4*)&Bm[(long)(k0 + kk) * N + bn + nq * 4];
            Bs[kk][nq*4+0] = bv.x; Bs[kk][nq*4+1] = bv.y;
            Bs[kk][nq*4+2] = bv.z; Bs[kk][nq*4+3] = bv.w;
        }
        __syncthreads();
        #pragma unroll
        for (int kk = 0; kk < 16; ++kk) {
            float4 a = *(const float4*)&As[kk][ty * 4];
            float4 b = *(const float4*)&Bs[kk][tx * 4];
            acc[0][0] += a.x*b.x; acc[0][1] += a.x*b.y; acc[0][2] += a.x*b.z; acc[0][3] += a.x*b.w;
            acc[1][0] += a.y*b.x; acc[1][1] += a.y*b.y; acc[1][2] += a.y*b.z; acc[1][3] += a.y*b.w;
            acc[2][0] += a.z*b.x; acc[2][1] += a.z*b.y; acc[2][2] += a.z*b.z; acc[2][3] += a.z*b.w;
            acc[3][0] += a.w*b.x; acc[3][1] += a.w*b.y; acc[3][2] += a.w*b.z; acc[3][3] += a.w*b.w;
        }
        __syncthreads();
    }
    #pragma unroll
    for (int i = 0; i < 4; ++i) {
        int row = bm + ty * 4 + i;
        #pragma unroll
        for (int j = 0; j < 4; ++j) {
            int col = bn + tx * 4 + j;
            float c = acc[i][j];
            if (bias)  c += bias[col];
            if (resid) c += resid[(long)row * N + col];
            if (RELU)  c = fmaxf(c, 0.f);
            C[(long)row * N + col] = c;
        }
    }
}

// ---------------------------------------------------------------- top-k (k=16), one wave per row
// 64 lanes x 16 vals in registers; 16 iterations of 64-lane shfl butterfly
// (tie-break lower index); zero barriers, zero LDS.
__global__ __launch_bounds__(256) void k_topk(const float* __restrict__ sim, int* __restrict__ knn) {
    int tid = threadIdx.x;
    int wave = tid >> 6, ll = tid & 63;
    int bn = blockIdx.x * 4 + wave;
    int b = bn >> 10, n = bn & 1023;
    const float* row = sim + (long)b * N_ * N_ + (long)n * N_;
    float v[16];
    #pragma unroll
    for (int j = 0; j < 16; ++j) {
        int m = ll + j * 64;
        v[j] = row[m] - (m == n ? 2.0f : 0.0f);
    }
    int* kout = knn + (long)bn * KNN;
    for (int it = 0; it < KNN; ++it) {
        // local argmax over 16 (ascending index, strict > keeps lowest m on ties)
        float bv = v[0]; int bi = ll;
        #pragma unroll
        for (int j = 1; j < 16; ++j)
            if (v[j] > bv) { bv = v[j]; bi = ll + j * 64; }
        // 64-lane butterfly, tie-break lower index
        #pragma unroll
        for (int mask = 1; mask < 64; mask <<= 1) {
            float ov = __shfl_xor(bv, mask);
            int   oi = __shfl_xor(bi, mask);
            if (ov > bv || (ov == bv && oi < bi)) { bv = ov; bi = oi; }
        }
        if (ll == 0) kout[it] = bi;
        if ((bi & 63) == ll) v[bi >> 6] = -1e30f;   // owner invalidates
    }
}

// ---------------------------------------------------------------- weight cast+transpose
__global__ void k_cast15(const float* __restrict__ g, const float* __restrict__ q,
                         const float* __restrict__ k, const float* __restrict__ v,
                         const float* __restrict__ o, ushort* __restrict__ out) {
    int z = blockIdx.z; int type = z / 3, l = z % 3;
    const float* in = (type == 0 ? g : type == 1 ? q : type == 2 ? k : type == 3 ? v : o)
                      + (long)l * HID * HID;
    ushort* op = out + (long)z * HID * HID;
    __shared__ float t[32][33];
    int c0 = blockIdx.x * 32, r0 = blockIdx.y * 32;
    int tid = threadIdx.x; int i = tid & 31, j4 = tid >> 5;
    #pragma unroll
    for (int rr = 0; rr < 4; ++rr) {
        int r = j4 * 4 + rr;
        t[r][i] = in[(long)(r0 + r) * HID + c0 + i];
    }
    __syncthreads();
    #pragma unroll
    for (int rr = 0; rr < 4; ++rr) {
        int c = j4 * 4 + rr;
        op[(long)(c0 + c) * HID + r0 + i] = f2b(t[i][c]);
    }
}

__global__ void k_castT(const float* __restrict__ in_, ushort* __restrict__ out_,
                        int R, int C) {
    long mz = (long)blockIdx.z * R * C;
    const float* in = in_ + mz;
    ushort* op = out_ + mz;
    __shared__ float t[32][33];
    int c0 = blockIdx.x * 32, r0 = blockIdx.y * 32;
    int tid = threadIdx.x; int i = tid & 31, j4 = tid >> 5;
    #pragma unroll
    for (int rr = 0; rr < 4; ++rr) {
        int r = j4 * 4 + rr;
        t[r][i] = in[(long)(r0 + r) * C + c0 + i];
    }
    __syncthreads();
    #pragma unroll
    for (int rr = 0; rr < 4; ++rr) {
        int c = j4 * 4 + rr;
        op[(long)(c0 + c) * R + r0 + i] = f2b(t[i][c]);
    }
}

// flat f32 -> bf16 (8 elems/thread)
__global__ __launch_bounds__(256) void k_castb(const float* __restrict__ in,
                                               ushort* __restrict__ out) {
    long i0 = ((long)blockIdx.x * 256 + threadIdx.x) * 8;
    float4 a0 = *(const float4*)&in[i0];
    float4 a1 = *(const float4*)&in[i0 + 4];
    u16x8 v;
    v[0]=f2b(a0.x); v[1]=f2b(a0.y); v[2]=f2b(a0.z); v[3]=f2b(a0.w);
    v[4]=f2b(a1.x); v[5]=f2b(a1.y); v[6]=f2b(a1.z); v[7]=f2b(a1.w);
    *(u16x8*)&out[i0] = v;
}

// ---------------------------------------------------------------- MFMA GEMM v2 (128x128 tile)
// C[M,N] = A[M,K](bf16) @ Wt[N,K]^T(bf16) + bias (+resid) (+relu)
// OUTMODE: 0 = f32 [M][N], 1 = bf16 [M][N], 2 = bf16 transposed [N][ldcT]
template<int OUTMODE, bool RELU>
__global__ __launch_bounds__(256) void k_mgemm(
        const ushort* __restrict__ A, const ushort* __restrict__ Wt,
        const float* __restrict__ bias, const float* __restrict__ resid,
        void* __restrict__ Cout, int M, int N, int K, long ldcT) {
    __shared__ ushort Al[128][40];   // row stride 80B
    __shared__ ushort Bl[128][40];
    int bm = blockIdx.y * 128, bnn = blockIdx.x * 128;
    int tid = threadIdx.x;
    int w = tid >> 6, l = tid & 63;
    int wm = w >> 1, wn = w & 1;
    int sr = tid >> 2, skq = (tid & 3) * 8;
    f32x4 acc[4][4] = {};
    for (int k0 = 0; k0 < K; k0 += 32) {
        *(u16x8*)&Al[sr][skq]      = *(const u16x8*)&A [(long)(bm + sr) * K + k0 + skq];
        *(u16x8*)&Al[sr + 64][skq] = *(const u16x8*)&A [(long)(bm + sr + 64) * K + k0 + skq];
        *(u16x8*)&Bl[sr][skq]      = *(const u16x8*)&Wt[(long)(bnn + sr) * K + k0 + skq];
        *(u16x8*)&Bl[sr + 64][skq] = *(const u16x8*)&Wt[(long)(bnn + sr + 64) * K + k0 + skq];
        __syncthreads();
        s16x8 af[4], bf[4];
        #pragma unroll
        for (int mi = 0; mi < 4; ++mi)
            af[mi] = *(const s16x8*)&Al[wm * 64 + mi * 16 + (l & 15)][(l >> 4) * 8];
        #pragma unroll
        for (int ni = 0; ni < 4; ++ni)
            bf[ni] = *(const s16x8*)&Bl[wn * 64 + ni * 16 + (l & 15)][(l >> 4) * 8];
        #pragma unroll
        for (int mi = 0; mi < 4; ++mi)
            #pragma unroll
            for (int ni = 0; ni < 4; ++ni)
                acc[mi][ni] = __builtin_amdgcn_mfma_f32_16x16x32_bf16(af[mi], bf[ni], acc[mi][ni], 0, 0, 0);
        __syncthreads();
    }
    #pragma unroll
    for (int mi = 0; mi < 4; ++mi) {
        int row0 = bm + wm * 64 + mi * 16 + (l >> 4) * 4;
        #pragma unroll
        for (int ni = 0; ni < 4; ++ni) {
            int coln = bnn + wn * 64 + ni * 16 + (l & 15);
            float bv = bias[coln];
            if (OUTMODE == 2) {
                u16x4 pk;
                #pragma unroll
                for (int reg = 0; reg < 4; ++reg)
                    pk[reg] = f2b(acc[mi][ni][reg] + bv);
                *(u16x4*)((ushort*)Cout + (long)coln * ldcT + row0) = pk;
            } else {
                #pragma unroll
                for (int reg = 0; reg < 4; ++reg) {
                    int rowg = row0 + reg;
                    float v = acc[mi][ni][reg] + bv;
                    if (resid) v += resid[(long)rowg * N + coln];
                    if (RELU)  v = fmaxf(v, 0.f);
                    if (OUTMODE == 0) ((float*)Cout)[(long)rowg * N + coln] = v;
                    else              ((ushort*)Cout)[(long)rowg * N + coln] = f2b(v);
                }
            }
        }
    }
}

// ---------------------------------------------------------------- GCN gather + residual + LN (f32)
__global__ void k_gcn_ln(const float* __restrict__ h, const float* __restrict__ xw,
                         const int* __restrict__ knn,
                         const float* __restrict__ lns, const float* __restrict__ lnb,
                         float* __restrict__ hlocal) {
    int bn = blockIdx.x; int b = bn >> 10;
    __shared__ int nb[KNN];
    __shared__ float red[128];
    int tid = threadIdx.x;
    if (tid < KNN) nb[tid] = knn[(long)bn * KNN + tid];
    __syncthreads();
    float val[3]; float sum = 0.f, ssq = 0.f;
    #pragma unroll
    for (int i = 0; i < 3; ++i) {
        int c = tid + i * 128;
        float acc = xw[(long)bn * HID + c];
        #pragma unroll
        for (int j = 0; j < KNN; ++j)
            acc += xw[((long)(b << 10) + nb[j]) * HID + c];
        float v = h[(long)bn * HID + c] + acc * (1.0f / 17.0f);
        val[i] = v; sum += v; ssq += v * v;
    }
    red[tid] = sum; __syncthreads();
    for (int s = 64; s > 0; s >>= 1) { if (tid < s) red[tid] += red[tid+s]; __syncthreads(); }
    sum = red[0]; __syncthreads();
    red[tid] = ssq; __syncthreads();
    for (int s = 64; s > 0; s >>= 1) { if (tid < s) red[tid] += red[tid+s]; __syncthreads(); }
    ssq = red[0];
    float mu = sum / HID;
    float var = ssq / HID - mu * mu;
    float inv = rsqrtf(var + 1e-5f);
    #pragma unroll
    for (int i = 0; i < 3; ++i) {
        int c = tid + i * 128;
        hlocal[(long)bn * HID + c] = (val[i] - mu) * inv * lns[c] + lnb[c];
    }
}

// ---------------------------------------------------------------- (a[+badd]) -> LN -> (+post), + bf16 mirror
__global__ void k_addln(const float* __restrict__ a, const float* __restrict__ badd,
                        const float* __restrict__ post,
                        const float* __restrict__ lns, const float* __restrict__ lnb,
                        float* __restrict__ outp, ushort* __restrict__ bfout) {
    int bn = blockIdx.x;
    __shared__ float red[128];
    int tid = threadIdx.x;
    float val[3]; float sum = 0.f, ssq = 0.f;
    #pragma unroll
    for (int i = 0; i < 3; ++i) {
        int c = tid + i * 128;
        float v = a[(long)bn * HID + c];
        if (badd) v += badd[(long)bn * HID + c];
        val[i] = v; sum += v; ssq += v * v;
    }
    red[tid] = sum; __syncthreads();
    for (int s = 64; s > 0; s >>= 1) { if (tid < s) red[tid] += red[tid+s]; __syncthreads(); }
    sum = red[0]; __syncthreads();
    red[tid] = ssq; __syncthreads();
    for (int s = 64; s > 0; s >>= 1) { if (tid < s) red[tid] += red[tid+s]; __syncthreads(); }
    ssq = red[0];
    float mu = sum / HID;
    float var = ssq / HID - mu * mu;
    float inv = rsqrtf(var + 1e-5f);
    #pragma unroll
    for (int i = 0; i < 3; ++i) {
        int c = tid + i * 128;
        float o = (val[i] - mu) * inv * lns[c] + lnb[c];
        if (post) o += post[(long)bn * HID + c];
        outp[(long)bn * HID + c] = o;
        if (bfout) bfout[(long)bn * HID + c] = f2b(o);
    }
}

// ---------------------------------------------------------------- MFMA attention (bf16 out)
__global__ __launch_bounds__(256) void k_attn(const ushort* __restrict__ qb,
                                              const ushort* __restrict__ kb,
                                              const ushort* __restrict__ vt,
                                              ushort* __restrict__ o) {
    int b = blockIdx.z, hh = blockIdx.y, r0 = blockIdx.x * 16;
    __shared__ ushort sc[16][1032];     // bf16 scores/probs; stride 2064B
    __shared__ ushort kvt[9216];        // union: Kt[64][136] | VtT[128][72]
    __shared__ float rowinv[16];
    int tid = threadIdx.x;
    int w = tid >> 6, l = tid & 63;
    s16x8 aq[4];
    const ushort* qrow = qb + ((long)(b * N_) + r0 + (l & 15)) * HID + hh * DH + (l >> 4) * 8;
    #pragma unroll
    for (int ks = 0; ks < 4; ++ks) aq[ks] = *(const s16x8*)(qrow + ks * 32);
    const float scale = 0.08838834764831845f;   // 1/sqrt(128)
    // ---------- S = Q K^T
    for (int m0 = 0; m0 < N_; m0 += 64) {
        {
            int key = tid >> 2, seg = tid & 3;
            const ushort* src = kb + ((long)(b * N_) + m0 + key) * HID + hh * DH + seg * 32;
            ushort* dst = &kvt[key * 136 + seg * 32];
            #pragma unroll
            for (int i = 0; i < 4; ++i)
                *(u16x8*)(dst + i * 8) = *(const u16x8*)(src + i * 8);
        }
        __syncthreads();
        f32x4 acc = {0.f, 0.f, 0.f, 0.f};
        #pragma unroll
        for (int ks = 0; ks < 4; ++ks) {
            s16x8 bk = *(const s16x8*)&kvt[(w * 16 + (l & 15)) * 136 + ks * 32 + (l >> 4) * 8];
            acc = __builtin_amdgcn_mfma_f32_16x16x32_bf16(aq[ks], bk, acc, 0, 0, 0);
        }
        int key = m0 + w * 16 + (l & 15);
        #pragma unroll
        for (int reg = 0; reg < 4; ++reg)
            sc[(l >> 4) * 4 + reg][key] = f2b(acc[reg] * scale);
        __syncthreads();
    }
    // ---------- softmax
    {
        int g = tid >> 5, l2 = tid & 31;
        #pragma unroll
        for (int rr = 0; rr < 2; ++rr) {
            int row = g + rr * 8;
            float v[32];
            #pragma unroll
            for (int i = 0; i < 16; ++i) {
                uint u = *(const uint*)&sc[row][l2 * 2 + i * 64];
                v[2*i]   = b2f(u & 0xffffu);
                v[2*i+1] = b2f(u >> 16);
            }
            float mx = v[0];
            #pragma unroll
            for (int i = 1; i < 32; ++i) mx = fmaxf(mx, v[i]);
            #pragma unroll
            for (int m = 16; m >= 1; m >>= 1) mx = fmaxf(mx, __shfl_xor(mx, m));
            float sm = 0.f;
            #pragma unroll
            for (int i = 0; i < 16; ++i) {
                float e0 = __expf(v[2*i]   - mx);
                float e1 = __expf(v[2*i+1] - mx);
                sm += e0 + e1;
                *(uint*)&sc[row][l2 * 2 + i * 64] = (uint)f2b(e0) | ((uint)f2b(e1) << 16);
            }
            #pragma unroll
            for (int m = 16; m >= 1; m >>= 1) sm += __shfl_xor(sm, m);
            if (l2 == 0) rowinv[row] = 1.0f / sm;
        }
    }
    __syncthreads();
    // ---------- O = P V
    f32x4 zero = {0.f, 0.f, 0.f, 0.f};
    f32x4 oacc[2] = {zero, zero};
    for (int m0 = 0; m0 < N_; m0 += 64) {
        {
            int dim = tid >> 1, half = tid & 1;
            const ushort* src = vt + ((long)(hh * DH + dim)) * (B_ * N_) + b * N_ + m0 + half * 32;
            ushort* dst = &kvt[dim * 72 + half * 32];
            #pragma unroll
            for (int i = 0; i < 4; ++i)
                *(u16x8*)(dst + i * 8) = *(const u16x8*)(src + i * 8);
        }
        __syncthreads();
        #pragma unroll
        for (int ks = 0; ks < 2; ++ks) {
            s16x8 pf = *(const s16x8*)&sc[l & 15][m0 + ks * 32 + (l >> 4) * 8];
            #pragma unroll
            for (int d = 0; d < 2; ++d) {
                s16x8 vf = *(const s16x8*)&kvt[((w * 2 + d) * 16 + (l & 15)) * 72 + ks * 32 + (l >> 4) * 8];
                oacc[d] = __builtin_amdgcn_mfma_f32_16x16x32_bf16(pf, vf, oacc[d], 0, 0, 0);
            }
        }
        __syncthreads();
    }
    #pragma unroll
    for (int d = 0; d < 2; ++d) {
        int dim = (w * 2 + d) * 16 + (l & 15);
        #pragma unroll
        for (int reg = 0; reg < 4; ++reg) {
            int row = (l >> 4) * 4 + reg;
            o[((long)(b * N_) + r0 + row) * HID + hh * DH + dim] = f2b(oacc[d][reg] * rowinv[row]);
        }
    }
}

// ---------------------------------------------------------------- mean pool, two-stage
__global__ __launch_bounds__(384) void k_pool1(const float* __restrict__ h,
                                               float* __restrict__ partial) {
    int s = blockIdx.x, b = blockIdx.y;
    int c = threadIdx.x;
    const float* hp = h + ((long)(b * N_) + s * 32) * HID + c;
    float acc = 0.f;
    #pragma unroll
    for (int n = 0; n < 32; ++n) acc += hp[(long)n * HID];
    partial[((long)(b * 32) + s) * HID + c] = acc;
}
__global__ __launch_bounds__(384) void k_pool2(const float* __restrict__ partial,
                                               float* __restrict__ pooled) {
    int b = blockIdx.x;
    int c = threadIdx.x;
    const float* pp = partial + (long)(b * 32) * HID + c;
    float acc = 0.f;
    #pragma unroll
    for (int s = 0; s < 32; ++s) acc += pp[(long)s * HID];
    pooled[b * HID + c] = acc * (1.0f / N_);
}

// ---------------------------------------------------------------- head (f32)
__global__ void k_head(const float* __restrict__ pooled,
                       const float* __restrict__ w1, const float* __restrict__ b1,
                       const float* __restrict__ w2, const float* __restrict__ b2,
                       float* __restrict__ out) {
    int b = blockIdx.x; int tid = threadIdx.x;   // 384 threads
    __shared__ float z[HID];
    float acc = b1[tid];
    for (int c = 0; c < HID; ++c) acc += pooled[b * HID + c] * w1[c * HID + tid];
    z[tid] = fmaxf(acc, 0.f);
    __syncthreads();
    if (tid < OUTD) {
        float a2 = b2[tid];
        for (int j = 0; j < HID; ++j) a2 += z[j] * w2[j * OUTD + tid];
        out[b * OUTD + tid] = a2;
    }
}

// ================================================================ launch
extern "C" void kernel_launch(void* const* d_in, const int* in_sizes, int n_in,
                              void* d_out, int out_size, void* d_ws, size_t ws_size,
                              hipStream_t stream) {
    const float* x       = (const float*)d_in[0];
    const float* W_enc   = (const float*)d_in[1];
    const float* b_enc   = (const float*)d_in[2];
    const float* gcn_W   = (const float*)d_in[3];
    const float* gcn_b   = (const float*)d_in[4];
    const float* Wq      = (const float*)d_in[5];
    const float* bq      = (const float*)d_in[6];
    const float* Wk      = (const float*)d_in[7];
    const float* bk      = (const float*)d_in[8];
    const float* Wv      = (const float*)d_in[9];
    const float* bv      = (const float*)d_in[10];
    const float* Wo      = (const float*)d_in[11];
    const float* bo      = (const float*)d_in[12];
    const float* ln_s    = (const float*)d_in[13];
    const float* ln_b    = (const float*)d_in[14];
    const float* mlp_W1  = (const float*)d_in[15];
    const float* mlp_b1  = (const float*)d_in[16];
    const float* mlp_W2  = (const float*)d_in[17];
    const float* mlp_b2  = (const float*)d_in[18];
    const float* lin1_W  = (const float*)d_in[19];
    const float* lin1_b  = (const float*)d_in[20];
    const float* lin2_W  = (const float*)d_in[21];
    const float* lin2_b  = (const float*)d_in[22];

    const long S = (long)B_ * N_ * HID;            // 3,145,728
    char* base = (char*)d_ws;
    float* h      = (float*)(base);
    float* tmp1   = (float*)(base + (size_t)S * 4);       // xw / attn-out(bf16) / u / pool-partial
    float* hlocal = (float*)(base + (size_t)S * 8);
    float* outb   = (float*)(base + (size_t)S * 12);
    char*  tzone  = base + (size_t)S * 16;                // 8S-byte multi-use region
    float* proj   = (float*)(base + (size_t)S * 24);
    float*  sim = (float*)tzone;                          // phase-1 (spills into proj)
    ushort* qbf = (ushort*)tzone;                         // [0,2S)
    ushort* kbf = (ushort*)(tzone + (size_t)S * 2);       // [2S,4S)
    ushort* vbT = (ushort*)(tzone + (size_t)S * 4);       // [4S,6S)
    ushort* outb_bf = (ushort*)(tzone + (size_t)S * 6);   // [6S,8S)
    ushort* tb  = (ushort*)tzone;                         // [0,4S) after attn
    int*    knn    = (int*)(base + (size_t)S * 28);
    float*  pooled = (float*)(base + (size_t)S * 28 + 524288);
    ushort* wts    = (ushort*)(base + (size_t)S * 28 + 524288 + 16384);
    const long SQ = (long)HID * HID;
    ushort* w1T = wts + 15 * SQ;
    ushort* w2T = w1T + 3 * (long)HID * 2 * HID;
    ushort* hb  = (ushort*)(base + (size_t)S * 28 + 524288 + 16384 + 7962624);
    float* partial = tmp1;
    ushort* obf = (ushort*)tmp1;                          // attn bf16 out (tmp1 dead)

    // ---- weight cast+transpose (bf16 [N][K])
    k_cast15<<<dim3(12, 12, 15), 256, 0, stream>>>(gcn_W, Wq, Wk, Wv, Wo, wts);
    k_castT<<<dim3(24, 12, 3), 256, 0, stream>>>(mlp_W1, w1T, HID, 2 * HID);
    k_castT<<<dim3(12, 24, 3), 256, 0, stream>>>(mlp_W2, w2T, 2 * HID, HID);

    // ---- encode(+normalize) + sim (f32 exact) + topk
    k_encode<<<B_ * N_, 128, 0, stream>>>(x, W_enc, b_enc, h, tmp1);
    k_gemm<true, false><<<dim3(16, 16, B_), 256, 0, stream>>>(
        tmp1, tmp1, nullptr, nullptr, sim, N_, N_, HID,
        (long)N_ * HID, (long)N_ * HID, (long)N_ * N_);
    k_topk<<<B_ * N_ / 4, 256, 0, stream>>>(sim, knn);
    k_castb<<<(int)(S / 2048), 256, 0, stream>>>(h, hb);   // h -> bf16 mirror

    const int M = B_ * N_;   // 8192
    for (int l = 0; l < L_; ++l) {
        const ushort* gWt = wts + (long)(0 + l) * SQ;
        const ushort* wqT = wts + (long)(3 + l) * SQ;
        const ushort* wkT = wts + (long)(6 + l) * SQ;
        const ushort* wvT = wts + (long)(9 + l) * SQ;
        const ushort* woT = wts + (long)(12 + l) * SQ;
        const ushort* w1Tl = w1T + (long)l * HID * 2 * HID;
        const ushort* w2Tl = w2T + (long)l * HID * 2 * HID;
        const float* gB  = gcn_b + (long)l * HID;
        const float* bql = bq + (long)l * HID;
        const float* bkl = bk + (long)l * HID;
        const float* bvl = bv + (long)l * HID;
        const float* bol = bo + (long)l * HID;
        const float* b1l = mlp_b1 + (long)l * 2 * HID;
        const float* b2l = mlp_b2 + (long)l * HID;
        const float* ls0 = ln_s + (long)(l * 3 + 0) * HID; const float* lb0 = ln_b + (long)(l * 3 + 0) * HID;
        const float* ls1 = ln_s + (long)(l * 3 + 1) * HID; const float* lb1 = ln_b + (long)(l * 3 + 1) * HID;
        const float* ls2 = ln_s + (long)(l * 3 + 2) * HID; const float* lb2 = ln_b + (long)(l * 3 + 2) * HID;

        // xw = h @ gcn_W + gcn_b  (f32)
        k_mgemm<0, false><<<dim3(HID / 128, M / 128), 256, 0, stream>>>(
            hb, gWt, gB, nullptr, tmp1, M, HID, HID, 0);
        k_gcn_ln<<<B_ * N_, 128, 0, stream>>>(h, tmp1, knn, ls0, lb0, hlocal);
        // q, k (bf16), v (bf16 transposed)
        k_mgemm<1, false><<<dim3(HID / 128, M / 128), 256, 0, stream>>>(
            hb, wqT, bql, nullptr, qbf, M, HID, HID, 0);
        k_mgemm<1, false><<<dim3(HID / 128, M / 128), 256, 0, stream>>>(
            hb, wkT, bkl, nullptr, kbf, M, HID, HID, 0);
        k_mgemm<2, false><<<dim3(HID / 128, M / 128), 256, 0, stream>>>(
            hb, wvT, bvl, nullptr, vbT, M, HID, HID, (long)M);
        // attention -> obf (bf16)
        k_attn<<<dim3(N_ / 16, NHEADS, B_), 256, 0, stream>>>(qbf, kbf, vbT, obf);
        // proj = o @ Wo + bo (f32)
        k_mgemm<0, false><<<dim3(HID / 128, M / 128), 256, 0, stream>>>(
            obf, woT, bol, nullptr, proj, M, HID, HID, 0);
        // out = hlocal + LN(h + proj) -> outb (+bf16 mirror)
        k_addln<<<B_ * N_, 128, 0, stream>>>(h, proj, hlocal, ls1, lb1, outb, outb_bf);
        // t = relu(out @ W1 + b1) -> bf16 tb
        k_mgemm<1, true><<<dim3(2 * HID / 128, M / 128), 256, 0, stream>>>(
            outb_bf, w1Tl, b1l, nullptr, tb, M, 2 * HID, HID, 0);
        // u = out + t @ W2 + b2 -> tmp1 (f32)
        k_mgemm<0, false><<<dim3(HID / 128, M / 128), 256, 0, stream>>>(
            tb, w2Tl, b2l, outb, tmp1, M, HID, 2 * HID, 0);
        // h = LN(u) (+hb mirror)
        k_addln<<<B_ * N_, 128, 0, stream>>>(tmp1, nullptr, nullptr, ls2, lb2, h, hb);
    }

    k_pool1<<<dim3(32, B_), 384, 0, stream>>>(h, partial);
    k_pool2<<<B_, 384, 0, stream>>>(partial, pooled);
    k_head<<<B_, HID, 0, stream>>>(pooled, lin1_W, lin1_b, lin2_W, lin2_b,
                                   (float*)d_out);
}

// Round 10
// 874.977 us; speedup vs baseline: 4.0341x; 1.1392x over previous
//
#include <hip/hip_runtime.h>
#include <hip/hip_bf16.h>

#define B_    8
#define C_    64
#define N_    1024
#define HID   384
#define OUTD  128
#define L_    3
#define KNN   16
#define NHEADS 3
#define DH    128

typedef __attribute__((ext_vector_type(8))) short    s16x8;   // MFMA A/B frag: 8 bf16
typedef __attribute__((ext_vector_type(4))) float    f32x4;   // MFMA C/D frag
typedef __attribute__((ext_vector_type(8))) unsigned short u16x8;
typedef __attribute__((ext_vector_type(4))) unsigned short u16x4;

// RNE f32 -> bf16 (finite inputs)
__device__ __forceinline__ ushort f2b(float f) {
    uint x = __float_as_uint(f);
    return (ushort)((x + 0x7fff + ((x >> 16) & 1)) >> 16);
}
__device__ __forceinline__ float b2f(uint u) {
    return __uint_as_float(u << 16);
}

// ---------------------------------------------------------------- encode (+normalize +bf16 mirrors)
// h = x_pix @ W_enc + b_enc ; hb = bf16(h) ; nh = h/||h|| split into hi+lo bf16
__global__ void k_encode(const float* __restrict__ x, const float* __restrict__ Wenc,
                         const float* __restrict__ benc, float* __restrict__ h,
                         ushort* __restrict__ hb,
                         ushort* __restrict__ nhh, ushort* __restrict__ nhl) {
    int bn = blockIdx.x;
    int b = bn >> 10;
    const float* xb = x + (long)b * C_ * N_ + (bn & 1023);
    int tid = threadIdx.x;
    __shared__ float red[128];
    float val[3];
    #pragma unroll
    for (int i = 0; i < 3; ++i) {
        int c0 = tid + i * 128;
        float acc = benc[c0];
        for (int c = 0; c < C_; ++c)
            acc += xb[c * N_] * Wenc[c * HID + c0];
        h[(long)bn * HID + c0] = acc;
        hb[(long)bn * HID + c0] = f2b(acc);
        val[i] = acc;
    }
    float ss = 0.f;
    #pragma unroll
    for (int i = 0; i < 3; ++i) ss += val[i] * val[i];
    red[tid] = ss; __syncthreads();
    for (int s = 64; s > 0; s >>= 1) { if (tid < s) red[tid] += red[tid+s]; __syncthreads(); }
    float inv = 1.0f / sqrtf(red[0]);
    #pragma unroll
    for (int i = 0; i < 3; ++i) {
        int c0 = tid + i * 128;
        float fv = val[i] * inv;
        ushort hu = f2b(fv);
        float lo = fv - b2f((uint)hu);
        nhh[(long)bn * HID + c0] = hu;
        nhl[(long)bn * HID + c0] = f2b(lo);
    }
}

// ---------------------------------------------------------------- sim = nh @ nh^T via hi/lo split MFMA
// sim ~= hi.hi^T + hi.lo^T + lo.hi^T  (error ~1e-6, comparable to f32 GEMM rounding)
__global__ __launch_bounds__(256) void k_sim(const ushort* __restrict__ nhh,
                                             const ushort* __restrict__ nhl,
                                             float* __restrict__ sim) {
    __shared__ ushort Ah[128][40], Alo[128][40], Bh[128][40], Blo[128][40];
    int bz = blockIdx.z;
    int bm = blockIdx.y * 128, bn = blockIdx.x * 128;
    const ushort* baseh = nhh + (long)bz * N_ * HID;
    const ushort* basel = nhl + (long)bz * N_ * HID;
    int tid = threadIdx.x;
    int w = tid >> 6, l = tid & 63;
    int wm = w >> 1, wn = w & 1;
    int sr = tid >> 2, skq = (tid & 3) * 8;
    f32x4 acc[4][4] = {};
    for (int k0 = 0; k0 < HID; k0 += 32) {
        *(u16x8*)&Ah [sr][skq]      = *(const u16x8*)&baseh[(long)(bm + sr) * HID + k0 + skq];
        *(u16x8*)&Ah [sr + 64][skq] = *(const u16x8*)&baseh[(long)(bm + sr + 64) * HID + k0 + skq];
        *(u16x8*)&Alo[sr][skq]      = *(const u16x8*)&basel[(long)(bm + sr) * HID + k0 + skq];
        *(u16x8*)&Alo[sr + 64][skq] = *(const u16x8*)&basel[(long)(bm + sr + 64) * HID + k0 + skq];
        *(u16x8*)&Bh [sr][skq]      = *(const u16x8*)&baseh[(long)(bn + sr) * HID + k0 + skq];
        *(u16x8*)&Bh [sr + 64][skq] = *(const u16x8*)&baseh[(long)(bn + sr + 64) * HID + k0 + skq];
        *(u16x8*)&Blo[sr][skq]      = *(const u16x8*)&basel[(long)(bn + sr) * HID + k0 + skq];
        *(u16x8*)&Blo[sr + 64][skq] = *(const u16x8*)&basel[(long)(bn + sr + 64) * HID + k0 + skq];
        __syncthreads();
        s16x8 ah[4], al[4], bh[4], bl[4];
        #pragma unroll
        for (int mi = 0; mi < 4; ++mi) {
            ah[mi] = *(const s16x8*)&Ah [wm * 64 + mi * 16 + (l & 15)][(l >> 4) * 8];
            al[mi] = *(const s16x8*)&Alo[wm * 64 + mi * 16 + (l & 15)][(l >> 4) * 8];
        }
        #pragma unroll
        for (int ni = 0; ni < 4; ++ni) {
            bh[ni] = *(const s16x8*)&Bh [wn * 64 + ni * 16 + (l & 15)][(l >> 4) * 8];
            bl[ni] = *(const s16x8*)&Blo[wn * 64 + ni * 16 + (l & 15)][(l >> 4) * 8];
        }
        #pragma unroll
        for (int mi = 0; mi < 4; ++mi)
            #pragma unroll
            for (int ni = 0; ni < 4; ++ni) {
                acc[mi][ni] = __builtin_amdgcn_mfma_f32_16x16x32_bf16(ah[mi], bh[ni], acc[mi][ni], 0, 0, 0);
                acc[mi][ni] = __builtin_amdgcn_mfma_f32_16x16x32_bf16(ah[mi], bl[ni], acc[mi][ni], 0, 0, 0);
                acc[mi][ni] = __builtin_amdgcn_mfma_f32_16x16x32_bf16(al[mi], bh[ni], acc[mi][ni], 0, 0, 0);
            }
        __syncthreads();
    }
    float* so = sim + (long)bz * N_ * N_;
    #pragma unroll
    for (int mi = 0; mi < 4; ++mi) {
        int row0 = bm + wm * 64 + mi * 16 + (l >> 4) * 4;
        #pragma unroll
        for (int ni = 0; ni < 4; ++ni) {
            int coln = bn + wn * 64 + ni * 16 + (l & 15);
            #pragma unroll
            for (int reg = 0; reg < 4; ++reg)
                so[(long)(row0 + reg) * N_ + coln] = acc[mi][ni][reg];
        }
    }
}

// ---------------------------------------------------------------- top-k (k=16), one wave per row
__global__ __launch_bounds__(256) void k_topk(const float* __restrict__ sim, int* __restrict__ knn) {
    int tid = threadIdx.x;
    int wave = tid >> 6, ll = tid & 63;
    int bn = blockIdx.x * 4 + wave;
    int b = bn >> 10, n = bn & 1023;
    const float* row = sim + (long)b * N_ * N_ + (long)n * N_;
    float v[16];
    #pragma unroll
    for (int j = 0; j < 16; ++j) {
        int m = ll + j * 64;
        v[j] = row[m] - (m == n ? 2.0f : 0.0f);
    }
    int* kout = knn + (long)bn * KNN;
    for (int it = 0; it < KNN; ++it) {
        float bv = v[0]; int bi = ll;
        #pragma unroll
        for (int j = 1; j < 16; ++j)
            if (v[j] > bv) { bv = v[j]; bi = ll + j * 64; }
        #pragma unroll
        for (int mask = 1; mask < 64; mask <<= 1) {
            float ov = __shfl_xor(bv, mask);
            int   oi = __shfl_xor(bi, mask);
            if (ov > bv || (ov == bv && oi < bi)) { bv = ov; bi = oi; }
        }
        if (ll == 0) kout[it] = bi;
        if ((bi & 63) == ll) v[bi >> 6] = -1e30f;
    }
}

// ---------------------------------------------------------------- weight cast+transpose
// slots: gcn -> l ; q/k/v -> 3 + l*3 + {0,1,2} (per-layer contiguous) ; o -> 12 + l
__global__ void k_cast15(const float* __restrict__ g, const float* __restrict__ q,
                         const float* __restrict__ k, const float* __restrict__ v,
                         const float* __restrict__ o, ushort* __restrict__ out) {
    int z = blockIdx.z; int type = z / 3, l = z % 3;
    const float* in = (type == 0 ? g : type == 1 ? q : type == 2 ? k : type == 3 ? v : o)
                      + (long)l * HID * HID;
    int slot = (type == 0) ? l : (type == 4) ? 12 + l : 3 + l * 3 + (type - 1);
    ushort* op = out + (long)slot * HID * HID;
    __shared__ float t[32][33];
    int c0 = blockIdx.x * 32, r0 = blockIdx.y * 32;
    int tid = threadIdx.x; int i = tid & 31, j4 = tid >> 5;
    #pragma unroll
    for (int rr = 0; rr < 4; ++rr) {
        int r = j4 * 4 + rr;
        t[r][i] = in[(long)(r0 + r) * HID + c0 + i];
    }
    __syncthreads();
    #pragma unroll
    for (int rr = 0; rr < 4; ++rr) {
        int c = j4 * 4 + rr;
        op[(long)(c0 + c) * HID + r0 + i] = f2b(t[i][c]);
    }
}

__global__ void k_castT(const float* __restrict__ in_, ushort* __restrict__ out_,
                        int R, int C) {
    long mz = (long)blockIdx.z * R * C;
    const float* in = in_ + mz;
    ushort* op = out_ + mz;
    __shared__ float t[32][33];
    int c0 = blockIdx.x * 32, r0 = blockIdx.y * 32;
    int tid = threadIdx.x; int i = tid & 31, j4 = tid >> 5;
    #pragma unroll
    for (int rr = 0; rr < 4; ++rr) {
        int r = j4 * 4 + rr;
        t[r][i] = in[(long)(r0 + r) * C + c0 + i];
    }
    __syncthreads();
    #pragma unroll
    for (int rr = 0; rr < 4; ++rr) {
        int c = j4 * 4 + rr;
        op[(long)(c0 + c) * R + r0 + i] = f2b(t[i][c]);
    }
}

// concat qkv biases: qkvb[l][0:384)=bq, [384:768)=bk, [768:1152)=bv
__global__ void k_biasqkv(const float* __restrict__ bq, const float* __restrict__ bk,
                          const float* __restrict__ bv, float* __restrict__ qkvb) {
    int l = blockIdx.x, t = threadIdx.x;
    qkvb[l * 1152 + t]       = bq[l * HID + t];
    qkvb[l * 1152 + 384 + t] = bk[l * HID + t];
    qkvb[l * 1152 + 768 + t] = bv[l * HID + t];
}

// ---------------------------------------------------------------- MFMA GEMM v2 (128x128 tile)
// C[M,N] = A[M,K](bf16) @ Wt[N,K]^T(bf16) + bias (+resid) (+relu)
// OUTMODE: 0 = f32 [M][N], 1 = bf16 [M][N], 2 = bf16 transposed [N][ldcT],
//          3 = fused qkv: coln<768 -> bf16 rows stride 768 (Cout); coln>=768 -> transposed (CoutT)
template<int OUTMODE, bool RELU>
__global__ __launch_bounds__(256) void k_mgemm(
        const ushort* __restrict__ A, const ushort* __restrict__ Wt,
        const float* __restrict__ bias, const float* __restrict__ resid,
        void* __restrict__ Cout, void* __restrict__ CoutT,
        int M, int N, int K, long ldcT) {
    __shared__ ushort Al[128][40];   // row stride 80B
    __shared__ ushort Bl[128][40];
    int bm = blockIdx.y * 128, bnn = blockIdx.x * 128;
    int tid = threadIdx.x;
    int w = tid >> 6, l = tid & 63;
    int wm = w >> 1, wn = w & 1;
    int sr = tid >> 2, skq = (tid & 3) * 8;
    f32x4 acc[4][4] = {};
    for (int k0 = 0; k0 < K; k0 += 32) {
        *(u16x8*)&Al[sr][skq]      = *(const u16x8*)&A [(long)(bm + sr) * K + k0 + skq];
        *(u16x8*)&Al[sr + 64][skq] = *(const u16x8*)&A [(long)(bm + sr + 64) * K + k0 + skq];
        *(u16x8*)&Bl[sr][skq]      = *(const u16x8*)&Wt[(long)(bnn + sr) * K + k0 + skq];
        *(u16x8*)&Bl[sr + 64][skq] = *(const u16x8*)&Wt[(long)(bnn + sr + 64) * K + k0 + skq];
        __syncthreads();
        s16x8 af[4], bf[4];
        #pragma unroll
        for (int mi = 0; mi < 4; ++mi)
            af[mi] = *(const s16x8*)&Al[wm * 64 + mi * 16 + (l & 15)][(l >> 4) * 8];
        #pragma unroll
        for (int ni = 0; ni < 4; ++ni)
            bf[ni] = *(const s16x8*)&Bl[wn * 64 + ni * 16 + (l & 15)][(l >> 4) * 8];
        #pragma unroll
        for (int mi = 0; mi < 4; ++mi)
            #pragma unroll
            for (int ni = 0; ni < 4; ++ni)
                acc[mi][ni] = __builtin_amdgcn_mfma_f32_16x16x32_bf16(af[mi], bf[ni], acc[mi][ni], 0, 0, 0);
        __syncthreads();
    }
    #pragma unroll
    for (int mi = 0; mi < 4; ++mi) {
        int row0 = bm + wm * 64 + mi * 16 + (l >> 4) * 4;
        #pragma unroll
        for (int ni = 0; ni < 4; ++ni) {
            int coln = bnn + wn * 64 + ni * 16 + (l & 15);
            float bv = bias[coln];
            if (OUTMODE == 2) {
                u16x4 pk;
                #pragma unroll
                for (int reg = 0; reg < 4; ++reg)
                    pk[reg] = f2b(acc[mi][ni][reg] + bv);
                *(u16x4*)((ushort*)Cout + (long)coln * ldcT + row0) = pk;
            } else if (OUTMODE == 3) {
                if (coln < 768) {
                    #pragma unroll
                    for (int reg = 0; reg < 4; ++reg)
                        ((ushort*)Cout)[(long)(row0 + reg) * 768 + coln] = f2b(acc[mi][ni][reg] + bv);
                } else {
                    u16x4 pk;
                    #pragma unroll
                    for (int reg = 0; reg < 4; ++reg)
                        pk[reg] = f2b(acc[mi][ni][reg] + bv);
                    *(u16x4*)((ushort*)CoutT + (long)(coln - 768) * ldcT + row0) = pk;
                }
            } else {
                #pragma unroll
                for (int reg = 0; reg < 4; ++reg) {
                    int rowg = row0 + reg;
                    float v = acc[mi][ni][reg] + bv;
                    if (resid) v += resid[(long)rowg * N + coln];
                    if (RELU)  v = fmaxf(v, 0.f);
                    if (OUTMODE == 0) ((float*)Cout)[(long)rowg * N + coln] = v;
                    else              ((ushort*)Cout)[(long)rowg * N + coln] = f2b(v);
                }
            }
        }
    }
}

// ---------------------------------------------------------------- GCN gather + residual + LN (f32)
__global__ void k_gcn_ln(const float* __restrict__ h, const float* __restrict__ xw,
                         const int* __restrict__ knn,
                         const float* __restrict__ lns, const float* __restrict__ lnb,
                         float* __restrict__ hlocal) {
    int bn = blockIdx.x; int b = bn >> 10;
    __shared__ int nb[KNN];
    __shared__ float red[128];
    int tid = threadIdx.x;
    if (tid < KNN) nb[tid] = knn[(long)bn * KNN + tid];
    __syncthreads();
    float val[3]; float sum = 0.f, ssq = 0.f;
    #pragma unroll
    for (int i = 0; i < 3; ++i) {
        int c = tid + i * 128;
        float acc = xw[(long)bn * HID + c];
        #pragma unroll
        for (int j = 0; j < KNN; ++j)
            acc += xw[((long)(b << 10) + nb[j]) * HID + c];
        float v = h[(long)bn * HID + c] + acc * (1.0f / 17.0f);
        val[i] = v; sum += v; ssq += v * v;
    }
    red[tid] = sum; __syncthreads();
    for (int s = 64; s > 0; s >>= 1) { if (tid < s) red[tid] += red[tid+s]; __syncthreads(); }
    sum = red[0]; __syncthreads();
    red[tid] = ssq; __syncthreads();
    for (int s = 64; s > 0; s >>= 1) { if (tid < s) red[tid] += red[tid+s]; __syncthreads(); }
    ssq = red[0];
    float mu = sum / HID;
    float var = ssq / HID - mu * mu;
    float inv = rsqrtf(var + 1e-5f);
    #pragma unroll
    for (int i = 0; i < 3; ++i) {
        int c = tid + i * 128;
        hlocal[(long)bn * HID + c] = (val[i] - mu) * inv * lns[c] + lnb[c];
    }
}

// ---------------------------------------------------------------- (a[+badd]) -> LN -> (+post), + bf16 mirror
__global__ void k_addln(const float* __restrict__ a, const float* __restrict__ badd,
                        const float* __restrict__ post,
                        const float* __restrict__ lns, const float* __restrict__ lnb,
                        float* __restrict__ outp, ushort* __restrict__ bfout) {
    int bn = blockIdx.x;
    __shared__ float red[128];
    int tid = threadIdx.x;
    float val[3]; float sum = 0.f, ssq = 0.f;
    #pragma unroll
    for (int i = 0; i < 3; ++i) {
        int c = tid + i * 128;
        float v = a[(long)bn * HID + c];
        if (badd) v += badd[(long)bn * HID + c];
        val[i] = v; sum += v; ssq += v * v;
    }
    red[tid] = sum; __syncthreads();
    for (int s = 64; s > 0; s >>= 1) { if (tid < s) red[tid] += red[tid+s]; __syncthreads(); }
    sum = red[0]; __syncthreads();
    red[tid] = ssq; __syncthreads();
    for (int s = 64; s > 0; s >>= 1) { if (tid < s) red[tid] += red[tid+s]; __syncthreads(); }
    ssq = red[0];
    float mu = sum / HID;
    float var = ssq / HID - mu * mu;
    float inv = rsqrtf(var + 1e-5f);
    #pragma unroll
    for (int i = 0; i < 3; ++i) {
        int c = tid + i * 128;
        float o = (val[i] - mu) * inv * lns[c] + lnb[c];
        if (post) o += post[(long)bn * HID + c];
        outp[(long)bn * HID + c] = o;
        if (bfout) bfout[(long)bn * HID + c] = f2b(o);
    }
}

// ---------------------------------------------------------------- MFMA attention (qk fused buffer, bf16 out)
__global__ __launch_bounds__(256) void k_attn(const ushort* __restrict__ qk,
                                              const ushort* __restrict__ vt,
                                              ushort* __restrict__ o) {
    int b = blockIdx.z, hh = blockIdx.y, r0 = blockIdx.x * 16;
    __shared__ ushort sc[16][1032];     // bf16 scores/probs; stride 2064B
    __shared__ ushort kvt[9216];        // union: Kt[64][136] | VtT[128][72]
    __shared__ float rowinv[16];
    int tid = threadIdx.x;
    int w = tid >> 6, l = tid & 63;
    s16x8 aq[4];
    const ushort* qrow = qk + ((long)(b * N_) + r0 + (l & 15)) * 768 + hh * DH + (l >> 4) * 8;
    #pragma unroll
    for (int ks = 0; ks < 4; ++ks) aq[ks] = *(const s16x8*)(qrow + ks * 32);
    const float scale = 0.08838834764831845f;   // 1/sqrt(128)
    // ---------- S = Q K^T
    for (int m0 = 0; m0 < N_; m0 += 64) {
        {
            int key = tid >> 2, seg = tid & 3;
            const ushort* src = qk + ((long)(b * N_) + m0 + key) * 768 + 384 + hh * DH + seg * 32;
            ushort* dst = &kvt[key * 136 + seg * 32];
            #pragma unroll
            for (int i = 0; i < 4; ++i)
                *(u16x8*)(dst + i * 8) = *(const u16x8*)(src + i * 8);
        }
        __syncthreads();
        f32x4 acc = {0.f, 0.f, 0.f, 0.f};
        #pragma unroll
        for (int ks = 0; ks < 4; ++ks) {
            s16x8 bk = *(const s16x8*)&kvt[(w * 16 + (l & 15)) * 136 + ks * 32 + (l >> 4) * 8];
            acc = __builtin_amdgcn_mfma_f32_16x16x32_bf16(aq[ks], bk, acc, 0, 0, 0);
        }
        int key = m0 + w * 16 + (l & 15);
        #pragma unroll
        for (int reg = 0; reg < 4; ++reg)
            sc[(l >> 4) * 4 + reg][key] = f2b(acc[reg] * scale);
        __syncthreads();
    }
    // ---------- softmax
    {
        int g = tid >> 5, l2 = tid & 31;
        #pragma unroll
        for (int rr = 0; rr < 2; ++rr) {
            int row = g + rr * 8;
            float v[32];
            #pragma unroll
            for (int i = 0; i < 16; ++i) {
                uint u = *(const uint*)&sc[row][l2 * 2 + i * 64];
                v[2*i]   = b2f(u & 0xffffu);
                v[2*i+1] = b2f(u >> 16);
            }
            float mx = v[0];
            #pragma unroll
            for (int i = 1; i < 32; ++i) mx = fmaxf(mx, v[i]);
            #pragma unroll
            for (int m = 16; m >= 1; m >>= 1) mx = fmaxf(mx, __shfl_xor(mx, m));
            float sm = 0.f;
            #pragma unroll
            for (int i = 0; i < 16; ++i) {
                float e0 = __expf(v[2*i]   - mx);
                float e1 = __expf(v[2*i+1] - mx);
                sm += e0 + e1;
                *(uint*)&sc[row][l2 * 2 + i * 64] = (uint)f2b(e0) | ((uint)f2b(e1) << 16);
            }
            #pragma unroll
            for (int m = 16; m >= 1; m >>= 1) sm += __shfl_xor(sm, m);
            if (l2 == 0) rowinv[row] = 1.0f / sm;
        }
    }
    __syncthreads();
    // ---------- O = P V
    f32x4 zero = {0.f, 0.f, 0.f, 0.f};
    f32x4 oacc[2] = {zero, zero};
    for (int m0 = 0; m0 < N_; m0 += 64) {
        {
            int dim = tid >> 1, half = tid & 1;
            const ushort* src = vt + ((long)(hh * DH + dim)) * (B_ * N_) + b * N_ + m0 + half * 32;
            ushort* dst = &kvt[dim * 72 + half * 32];
            #pragma unroll
            for (int i = 0; i < 4; ++i)
                *(u16x8*)(dst + i * 8) = *(const u16x8*)(src + i * 8);
        }
        __syncthreads();
        #pragma unroll
        for (int ks = 0; ks < 2; ++ks) {
            s16x8 pf = *(const s16x8*)&sc[l & 15][m0 + ks * 32 + (l >> 4) * 8];
            #pragma unroll
            for (int d = 0; d < 2; ++d) {
                s16x8 vf = *(const s16x8*)&kvt[((w * 2 + d) * 16 + (l & 15)) * 72 + ks * 32 + (l >> 4) * 8];
                oacc[d] = __builtin_amdgcn_mfma_f32_16x16x32_bf16(pf, vf, oacc[d], 0, 0, 0);
            }
        }
        __syncthreads();
    }
    #pragma unroll
    for (int d = 0; d < 2; ++d) {
        int dim = (w * 2 + d) * 16 + (l & 15);
        #pragma unroll
        for (int reg = 0; reg < 4; ++reg) {
            int row = (l >> 4) * 4 + reg;
            o[((long)(b * N_) + r0 + row) * HID + hh * DH + dim] = f2b(oacc[d][reg] * rowinv[row]);
        }
    }
}

// ---------------------------------------------------------------- mean pool, two-stage
__global__ __launch_bounds__(384) void k_pool1(const float* __restrict__ h,
                                               float* __restrict__ partial) {
    int s = blockIdx.x, b = blockIdx.y;
    int c = threadIdx.x;
    const float* hp = h + ((long)(b * N_) + s * 32) * HID + c;
    float acc = 0.f;
    #pragma unroll
    for (int n = 0; n < 32; ++n) acc += hp[(long)n * HID];
    partial[((long)(b * 32) + s) * HID + c] = acc;
}
__global__ __launch_bounds__(384) void k_pool2(const float* __restrict__ partial,
                                               float* __restrict__ pooled) {
    int b = blockIdx.x;
    int c = threadIdx.x;
    const float* pp = partial + (long)(b * 32) * HID + c;
    float acc = 0.f;
    #pragma unroll
    for (int s = 0; s < 32; ++s) acc += pp[(long)s * HID];
    pooled[b * HID + c] = acc * (1.0f / N_);
}

// ---------------------------------------------------------------- head (f32)
__global__ void k_head(const float* __restrict__ pooled,
                       const float* __restrict__ w1, const float* __restrict__ b1,
                       const float* __restrict__ w2, const float* __restrict__ b2,
                       float* __restrict__ out) {
    int b = blockIdx.x; int tid = threadIdx.x;   // 384 threads
    __shared__ float z[HID];
    float acc = b1[tid];
    for (int c = 0; c < HID; ++c) acc += pooled[b * HID + c] * w1[c * HID + tid];
    z[tid] = fmaxf(acc, 0.f);
    __syncthreads();
    if (tid < OUTD) {
        float a2 = b2[tid];
        for (int j = 0; j < HID; ++j) a2 += z[j] * w2[j * OUTD + tid];
        out[b * OUTD + tid] = a2;
    }
}

// ================================================================ launch
extern "C" void kernel_launch(void* const* d_in, const int* in_sizes, int n_in,
                              void* d_out, int out_size, void* d_ws, size_t ws_size,
                              hipStream_t stream) {
    const float* x       = (const float*)d_in[0];
    const float* W_enc   = (const float*)d_in[1];
    const float* b_enc   = (const float*)d_in[2];
    const float* gcn_W   = (const float*)d_in[3];
    const float* gcn_b   = (const float*)d_in[4];
    const float* Wq      = (const float*)d_in[5];
    const float* bq      = (const float*)d_in[6];
    const float* Wk      = (const float*)d_in[7];
    const float* bk      = (const float*)d_in[8];
    const float* Wv      = (const float*)d_in[9];
    const float* bv      = (const float*)d_in[10];
    const float* Wo      = (const float*)d_in[11];
    const float* bo      = (const float*)d_in[12];
    const float* ln_s    = (const float*)d_in[13];
    const float* ln_b    = (const float*)d_in[14];
    const float* mlp_W1  = (const float*)d_in[15];
    const float* mlp_b1  = (const float*)d_in[16];
    const float* mlp_W2  = (const float*)d_in[17];
    const float* mlp_b2  = (const float*)d_in[18];
    const float* lin1_W  = (const float*)d_in[19];
    const float* lin1_b  = (const float*)d_in[20];
    const float* lin2_W  = (const float*)d_in[21];
    const float* lin2_b  = (const float*)d_in[22];

    const long S = (long)B_ * N_ * HID;            // 3,145,728
    char* base = (char*)d_ws;
    float* h      = (float*)(base);
    float* tmp1   = (float*)(base + (size_t)S * 4);       // xw / attn-out(bf16) / u / pool-partial / nhh+nhl
    float* hlocal = (float*)(base + (size_t)S * 8);
    float* outb   = (float*)(base + (size_t)S * 12);
    char*  tzone  = base + (size_t)S * 16;                // 8S-byte multi-use region
    float* proj   = (float*)(base + (size_t)S * 24);
    float*  sim = (float*)tzone;                          // phase-1 (spills into proj)
    ushort* qkbf = (ushort*)tzone;                        // [0,4S): fused q|k rows stride 768
    ushort* vbT  = (ushort*)(tzone + (size_t)S * 4);      // [4S,6S)
    ushort* outb_bf = (ushort*)(tzone + (size_t)S * 6);   // [6S,8S)
    ushort* tb  = (ushort*)tzone;                         // [0,4S) after attn (mlp hidden)
    ushort* nhh = (ushort*)(base + (size_t)S * 4);        // phase-1 overlay of tmp1
    ushort* nhl = (ushort*)(base + (size_t)S * 6);
    int*    knn    = (int*)(base + (size_t)S * 28);
    float*  pooled = (float*)(base + (size_t)S * 28 + 524288);
    ushort* wts    = (ushort*)(base + (size_t)S * 28 + 524288 + 16384);
    const long SQ = (long)HID * HID;
    ushort* w1T = wts + 15 * SQ;
    ushort* w2T = w1T + 3 * (long)HID * 2 * HID;
    ushort* hb  = (ushort*)(base + (size_t)S * 28 + 524288 + 16384 + 7962624);
    float* qkvb = (float*)(base + (size_t)S * 28 + 524288 + 16384 + 7962624 + (size_t)S * 2);
    float* partial = tmp1;
    ushort* obf = (ushort*)tmp1;                          // attn bf16 out (tmp1 dead)

    // ---- weight cast+transpose (bf16 [N][K]) + qkv bias concat
    k_cast15<<<dim3(12, 12, 15), 256, 0, stream>>>(gcn_W, Wq, Wk, Wv, Wo, wts);
    k_castT<<<dim3(24, 12, 3), 256, 0, stream>>>(mlp_W1, w1T, HID, 2 * HID);
    k_castT<<<dim3(12, 24, 3), 256, 0, stream>>>(mlp_W2, w2T, 2 * HID, HID);
    k_biasqkv<<<3, 384, 0, stream>>>(bq, bk, bv, qkvb);

    // ---- encode(+normalize+mirrors) + sim (hi/lo MFMA) + topk
    k_encode<<<B_ * N_, 128, 0, stream>>>(x, W_enc, b_enc, h, hb, nhh, nhl);
    k_sim<<<dim3(8, 8, 8), 256, 0, stream>>>(nhh, nhl, sim);
    k_topk<<<B_ * N_ / 4, 256, 0, stream>>>(sim, knn);

    const int M = B_ * N_;   // 8192
    for (int l = 0; l < L_; ++l) {
        const ushort* gWt  = wts + (long)l * SQ;
        const ushort* qkvW = wts + (long)(3 + l * 3) * SQ;    // q,k,v rows contiguous [1152][384]
        const ushort* woT  = wts + (long)(12 + l) * SQ;
        const ushort* w1Tl = w1T + (long)l * HID * 2 * HID;
        const ushort* w2Tl = w2T + (long)l * HID * 2 * HID;
        const float* gB  = gcn_b + (long)l * HID;
        const float* bol = bo + (long)l * HID;
        const float* b1l = mlp_b1 + (long)l * 2 * HID;
        const float* b2l = mlp_b2 + (long)l * HID;
        const float* ls0 = ln_s + (long)(l * 3 + 0) * HID; const float* lb0 = ln_b + (long)(l * 3 + 0) * HID;
        const float* ls1 = ln_s + (long)(l * 3 + 1) * HID; const float* lb1 = ln_b + (long)(l * 3 + 1) * HID;
        const float* ls2 = ln_s + (long)(l * 3 + 2) * HID; const float* lb2 = ln_b + (long)(l * 3 + 2) * HID;

        // xw = h @ gcn_W + gcn_b  (f32)
        k_mgemm<0, false><<<dim3(HID / 128, M / 128), 256, 0, stream>>>(
            hb, gWt, gB, nullptr, tmp1, nullptr, M, HID, HID, 0);
        k_gcn_ln<<<B_ * N_, 128, 0, stream>>>(h, tmp1, knn, ls0, lb0, hlocal);
        // fused q|k|v: one GEMM, N=1152; q/k rows stride 768, v transposed
        k_mgemm<3, false><<<dim3(1152 / 128, M / 128), 256, 0, stream>>>(
            hb, qkvW, qkvb + l * 1152, nullptr, qkbf, vbT, M, 1152, HID, (long)M);
        // attention -> obf (bf16)
        k_attn<<<dim3(N_ / 16, NHEADS, B_), 256, 0, stream>>>(qkbf, vbT, obf);
        // proj = o @ Wo + bo (f32)
        k_mgemm<0, false><<<dim3(HID / 128, M / 128), 256, 0, stream>>>(
            obf, woT, bol, nullptr, proj, nullptr, M, HID, HID, 0);
        // out = hlocal + LN(h + proj) -> outb (+bf16 mirror)
        k_addln<<<B_ * N_, 128, 0, stream>>>(h, proj, hlocal, ls1, lb1, outb, outb_bf);
        // t = relu(out @ W1 + b1) -> bf16 tb
        k_mgemm<1, true><<<dim3(2 * HID / 128, M / 128), 256, 0, stream>>>(
            outb_bf, w1Tl, b1l, nullptr, tb, nullptr, M, 2 * HID, HID, 0);
        // u = out + t @ W2 + b2 -> tmp1 (f32)
        k_mgemm<0, false><<<dim3(HID / 128, M / 128), 256, 0, stream>>>(
            tb, w2Tl, b2l, outb, tmp1, nullptr, M, HID, 2 * HID, 0);
        // h = LN(u) (+hb mirror)
        k_addln<<<B_ * N_, 128, 0, stream>>>(tmp1, nullptr, nullptr, ls2, lb2, h, hb);
    }

    k_pool1<<<dim3(32, B_), 384, 0, stream>>>(h, partial);
    k_pool2<<<B_, 384, 0, stream>>>(partial, pooled);
    k_head<<<B_, HID, 0, stream>>>(pooled, lin1_W, lin1_b, lin2_W, lin2_b,
                                   (float*)d_out);
}